// Round 1
// baseline (3429.969 us; speedup 1.0000x reference)
//
#include <hip/hip_runtime.h>
#include <hip/hip_bf16.h>
#include <math.h>

#define Sdim 2048
#define Bdim 2
#define Ddim 768
#define Hdim 12
#define DHdim 64
#define Ldim 2
#define Cdim 128
#define NCdim 16
#define FFdim 3072
#define Gdim 17
#define NSEPd 16
#define HIDd 100
#define NCLSd 7
#define SEPID 2
#define MROWS (Bdim*Sdim)

// ---------------- sep finding ----------------
__global__ void k_findsep(const int* __restrict__ ids, int* __restrict__ glob,
                          int* __restrict__ isg) {
    __shared__ int flag[Sdim];
    __shared__ int gl[Gdim];
    int t = threadIdx.x;
    for (int s = t; s < Sdim; s += blockDim.x) flag[s] = (ids[s] == SEPID) ? 1 : 0;
    __syncthreads();
    if (t == 0) {
        int cnt = 0;
        gl[0] = 0;
        for (int s = 0; s < Sdim && cnt < NSEPd; ++s) if (flag[s]) gl[++cnt] = s;
        while (cnt < NSEPd) gl[++cnt] = 0;
    }
    __syncthreads();
    for (int s = t; s < Sdim; s += blockDim.x) isg[s] = 0;
    if (t < Gdim) glob[t] = gl[t];
    __syncthreads();
    if (t < Gdim) isg[gl[t]] = 1;
}

// ---------------- embedding + LN ----------------
__global__ __launch_bounds__(256) void k_embed(const int* __restrict__ ids,
        const float* __restrict__ tok, const float* __restrict__ pos,
        const float* __restrict__ g, const float* __restrict__ b,
        float* __restrict__ x) {
    int row = blockIdx.x;
    int s = row & (Sdim - 1);
    long id = ids[row];
    const float* te = tok + id * (long)Ddim;
    const float* pe = pos + (long)s * Ddim;
    __shared__ float buf[Ddim];
    __shared__ float ra[4], rb[4];
    float ls = 0.f, lq = 0.f;
    for (int d = threadIdx.x; d < Ddim; d += 256) {
        float v = te[d] + pe[d];
        buf[d] = v; ls += v; lq += v * v;
    }
    #pragma unroll
    for (int o = 32; o; o >>= 1) { ls += __shfl_xor(ls, o, 64); lq += __shfl_xor(lq, o, 64); }
    int w = threadIdx.x >> 6;
    if ((threadIdx.x & 63) == 0) { ra[w] = ls; rb[w] = lq; }
    __syncthreads();
    float sum = ra[0] + ra[1] + ra[2] + ra[3];
    float sq  = rb[0] + rb[1] + rb[2] + rb[3];
    float mu = sum / Ddim;
    float var = sq / Ddim - mu * mu;
    float rs = rsqrtf(var + 1e-5f);
    float* xr = x + (long)row * Ddim;
    for (int d = threadIdx.x; d < Ddim; d += 256)
        xr[d] = (buf[d] - mu) * rs * g[d] + b[d];
}

// ---------------- residual add + LN (x = LN(x + a)) ----------------
__global__ __launch_bounds__(256) void k_ln_res(float* __restrict__ x,
        const float* __restrict__ a, const float* __restrict__ g,
        const float* __restrict__ b) {
    long row = blockIdx.x;
    __shared__ float buf[Ddim];
    __shared__ float ra[4], rb[4];
    float ls = 0.f, lq = 0.f;
    const float* xr = x + row * Ddim;
    const float* ar = a + row * Ddim;
    for (int d = threadIdx.x; d < Ddim; d += 256) {
        float v = xr[d] + ar[d];
        buf[d] = v; ls += v; lq += v * v;
    }
    #pragma unroll
    for (int o = 32; o; o >>= 1) { ls += __shfl_xor(ls, o, 64); lq += __shfl_xor(lq, o, 64); }
    int w = threadIdx.x >> 6;
    if ((threadIdx.x & 63) == 0) { ra[w] = ls; rb[w] = lq; }
    __syncthreads();
    float sum = ra[0] + ra[1] + ra[2] + ra[3];
    float sq  = rb[0] + rb[1] + rb[2] + rb[3];
    float mu = sum / Ddim;
    float var = sq / Ddim - mu * mu;
    float rs = rsqrtf(var + 1e-5f);
    float* xw = x + row * Ddim;
    for (int d = threadIdx.x; d < Ddim; d += 256)
        xw[d] = (buf[d] - mu) * rs * g[d] + b[d];
}

// ---------------- generic f32 GEMM: C = A[MxK] @ W[KxN] + bias, opt gelu ----------------
#define BM 64
#define BN 64
#define BKK 16
__global__ __launch_bounds__(256) void k_gemm(const float* __restrict__ A,
        const float* __restrict__ W, const float* __restrict__ bias,
        float* __restrict__ Cmat, int M, int N, int K, int act) {
    __shared__ float As[BKK][BM + 1];
    __shared__ float Ws[BKK][BN + 1];
    int bm = blockIdx.y * BM;
    int bn = blockIdx.x * BN;
    int t = threadIdx.x;
    int tx = t & 15, ty = t >> 4;
    float acc[4][4] = {};
    for (int k0 = 0; k0 < K; k0 += BKK) {
        #pragma unroll
        for (int i = 0; i < 4; ++i) {
            int idx = t * 4 + i;
            int m = idx >> 4, kk = idx & 15;
            As[kk][m] = A[(long)(bm + m) * K + k0 + kk];
        }
        #pragma unroll
        for (int i = 0; i < 4; ++i) {
            int idx = t + 256 * i;
            int kk = idx >> 6, n = idx & 63;
            Ws[kk][n] = W[(long)(k0 + kk) * N + bn + n];
        }
        __syncthreads();
        #pragma unroll
        for (int kk = 0; kk < BKK; ++kk) {
            float a0[4], b0[4];
            #pragma unroll
            for (int i = 0; i < 4; ++i) a0[i] = As[kk][ty * 4 + i];
            #pragma unroll
            for (int j = 0; j < 4; ++j) b0[j] = Ws[kk][tx * 4 + j];
            #pragma unroll
            for (int i = 0; i < 4; ++i)
                #pragma unroll
                for (int j = 0; j < 4; ++j) acc[i][j] += a0[i] * b0[j];
        }
        __syncthreads();
    }
    #pragma unroll
    for (int i = 0; i < 4; ++i) {
        int m = bm + ty * 4 + i;
        #pragma unroll
        for (int j = 0; j < 4; ++j) {
            int n = bn + tx * 4 + j;
            float v = acc[i][j] + bias[n];
            if (act == 1) {
                float u = v;
                v = 0.5f * u * (1.f + tanhf(0.7978845608f * (u + 0.044715f * u * u * u)));
            }
            Cmat[(long)m * N + n] = v;
        }
    }
}

// ---------------- local (banded) attention + global keys, online softmax ----------------
// grid (NC, H, B), block 128; thread c handles query row n*C+c
__global__ __launch_bounds__(128) void k_attn_local(const float* __restrict__ q,
        const float* __restrict__ k, const float* __restrict__ v,
        const int* __restrict__ isg, const int* __restrict__ glob,
        const int* __restrict__ amask, float* __restrict__ ao) {
    int n = blockIdx.x, h = blockIdx.y, b = blockIdx.z;
    int c = threadIdx.x;
    int r = n * Cdim + c;
    const long base = (long)b * Sdim * Ddim + h * DHdim;
    float qreg[DHdim];
    #pragma unroll
    for (int d = 0; d < DHdim; ++d) qreg[d] = q[base + (long)r * Ddim + d];
    float m = -1e30f, l = 0.f;
    float acc[DHdim];
    #pragma unroll
    for (int d = 0; d < DHdim; ++d) acc[d] = 0.f;

    __shared__ float kb[32][DHdim];
    __shared__ float vb[32][DHdim];
    __shared__ int kvalid[3 * Cdim];
    __shared__ int gpos[Gdim];
    __shared__ int gok[Gdim];

    for (int j = threadIdx.x; j < 3 * Cdim; j += 128) {
        int p = n * Cdim + j - Cdim;
        int ok = (p >= 0 && p < Sdim);
        if (ok) ok = (amask[b * Sdim + p] != 0) && (isg[p] == 0);
        kvalid[j] = ok;
    }
    if (threadIdx.x < Gdim) {
        int p = glob[threadIdx.x];
        gpos[threadIdx.x] = p;
        gok[threadIdx.x] = (amask[b * Sdim + p] != 0);
    }
    __syncthreads();

    for (int ch = 0; ch < 12; ++ch) {
        for (int i = threadIdx.x; i < 32 * DHdim; i += 128) {
            int jj = i >> 6, d = i & 63;
            int p = n * Cdim + ch * 32 + jj - Cdim;
            float kvv = 0.f, vvv = 0.f;
            if (p >= 0 && p < Sdim) {
                kvv = k[base + (long)p * Ddim + d];
                vvv = v[base + (long)p * Ddim + d];
            }
            kb[jj][d] = kvv; vb[jj][d] = vvv;
        }
        __syncthreads();
        for (int jj = 0; jj < 32; ++jj) {
            int j = ch * 32 + jj;
            if (j < c || j > c + 256 || !kvalid[j]) continue;
            float s = 0.f;
            #pragma unroll
            for (int d = 0; d < DHdim; ++d) s += qreg[d] * kb[jj][d];
            s *= 0.125f;
            if (s > m) {
                float corr = __expf(m - s);
                l *= corr;
                #pragma unroll
                for (int d = 0; d < DHdim; ++d) acc[d] *= corr;
                m = s;
            }
            float p = __expf(s - m);
            l += p;
            #pragma unroll
            for (int d = 0; d < DHdim; ++d) acc[d] += p * vb[jj][d];
        }
        __syncthreads();
    }
    // global keys
    for (int i = threadIdx.x; i < Gdim * DHdim; i += 128) {
        int g = i >> 6, d = i & 63;
        int p = gpos[g];
        kb[g][d] = k[base + (long)p * Ddim + d];
        vb[g][d] = v[base + (long)p * Ddim + d];
    }
    __syncthreads();
    for (int g = 0; g < Gdim; ++g) {
        if (!gok[g]) continue;
        float s = 0.f;
        #pragma unroll
        for (int d = 0; d < DHdim; ++d) s += qreg[d] * kb[g][d];
        s *= 0.125f;
        if (s > m) {
            float corr = __expf(m - s);
            l *= corr;
            #pragma unroll
            for (int d = 0; d < DHdim; ++d) acc[d] *= corr;
            m = s;
        }
        float p = __expf(s - m);
        l += p;
        #pragma unroll
        for (int d = 0; d < DHdim; ++d) acc[d] += p * vb[g][d];
    }
    float inv = 1.f / l;
    #pragma unroll
    for (int d = 0; d < DHdim; ++d) ao[base + (long)r * Ddim + d] = acc[d] * inv;
}

// ---------------- global token rows attend to all S keys ----------------
// grid (G, H, B), block 256
__global__ __launch_bounds__(256) void k_attn_glob(const float* __restrict__ q,
        const float* __restrict__ k, const float* __restrict__ v,
        const int* __restrict__ glob, const int* __restrict__ amask,
        float* __restrict__ ao) {
    int g = blockIdx.x, h = blockIdx.y, b = blockIdx.z;
    __shared__ float sc[Sdim];
    __shared__ float qs[DHdim];
    __shared__ float redm[4], reds[4];
    __shared__ float part[4][DHdim];
    int t = threadIdx.x;
    int qr = glob[g];
    const long base = (long)b * Sdim * Ddim + h * DHdim;
    if (t < DHdim) qs[t] = q[base + (long)qr * Ddim + t] * 0.125f;
    __syncthreads();
    float lm = -1e30f;
    for (int s0 = t; s0 < Sdim; s0 += 256) {
        float s = 0.f;
        const float* kr = k + base + (long)s0 * Ddim;
        #pragma unroll
        for (int d = 0; d < DHdim; ++d) s += qs[d] * kr[d];
        if (amask[b * Sdim + s0] == 0) s = -1e30f;
        sc[s0] = s;
        lm = fmaxf(lm, s);
    }
    #pragma unroll
    for (int o = 32; o; o >>= 1) lm = fmaxf(lm, __shfl_xor(lm, o, 64));
    if ((t & 63) == 0) redm[t >> 6] = lm;
    __syncthreads();
    float mx = fmaxf(fmaxf(redm[0], redm[1]), fmaxf(redm[2], redm[3]));
    float lsum = 0.f;
    for (int s0 = t; s0 < Sdim; s0 += 256) {
        float p = __expf(sc[s0] - mx);
        sc[s0] = p; lsum += p;
    }
    #pragma unroll
    for (int o = 32; o; o >>= 1) lsum += __shfl_xor(lsum, o, 64);
    if ((t & 63) == 0) reds[t >> 6] = lsum;
    __syncthreads();
    float l = reds[0] + reds[1] + reds[2] + reds[3];
    int d = t & 63, chunk = t >> 6;
    float a = 0.f;
    for (int s0 = chunk * 512; s0 < (chunk + 1) * 512; ++s0)
        a += sc[s0] * v[base + (long)s0 * Ddim + d];
    part[chunk][d] = a;
    __syncthreads();
    if (t < DHdim) {
        float o = (part[0][t] + part[1][t] + part[2][t] + part[3][t]) / l;
        ao[base + (long)qr * Ddim + t] = o;
    }
}

// ---------------- classification head ----------------
// grid B*(NSEP-2)=28, block 128
__global__ __launch_bounds__(128) void k_head(const float* __restrict__ x,
        const int* __restrict__ glob, const float* __restrict__ Wh,
        const float* __restrict__ bh, const float* __restrict__ Wout,
        const float* __restrict__ bout, float* __restrict__ out) {
    int i = blockIdx.x;
    int b = i / 14, j = i % 14;
    __shared__ float emb[2 * Ddim];
    __shared__ float hid[HIDd];
    int t = threadIdx.x;
    int p = glob[j + 2];
    for (int d = t; d < Ddim; d += 128) {
        emb[d] = x[(long)b * Sdim * Ddim + d];
        emb[Ddim + d] = x[((long)b * Sdim + p) * Ddim + d];
    }
    __syncthreads();
    if (t < HIDd) {
        float s = bh[t];
        for (int k1 = 0; k1 < 2 * Ddim; ++k1) s += emb[k1] * Wh[k1 * HIDd + t];
        hid[t] = fmaxf(s, 0.f);
    }
    __syncthreads();
    if (t < NCLSd) {
        float s = bout[t];
        for (int o = 0; o < HIDd; ++o) s += hid[o] * Wout[o * NCLSd + t];
        out[i * NCLSd + t] = s;
    }
}

extern "C" void kernel_launch(void* const* d_in, const int* in_sizes, int n_in,
                              void* d_out, int out_size, void* d_ws, size_t ws_size,
                              hipStream_t stream) {
    const int*   ids   = (const int*)d_in[0];
    const int*   am    = (const int*)d_in[1];
    const float* tok   = (const float*)d_in[2];
    const float* pos   = (const float*)d_in[3];
    const float* lneg  = (const float*)d_in[4];
    const float* lneb  = (const float*)d_in[5];
    const float* Wq    = (const float*)d_in[6];
    const float* bq    = (const float*)d_in[7];
    const float* Wk    = (const float*)d_in[8];
    const float* bk    = (const float*)d_in[9];
    const float* Wv    = (const float*)d_in[10];
    const float* bv    = (const float*)d_in[11];
    const float* Wo    = (const float*)d_in[12];
    const float* bo    = (const float*)d_in[13];
    const float* ln1g  = (const float*)d_in[14];
    const float* ln1b  = (const float*)d_in[15];
    const float* W1    = (const float*)d_in[16];
    const float* b1    = (const float*)d_in[17];
    const float* W2    = (const float*)d_in[18];
    const float* b2    = (const float*)d_in[19];
    const float* ln2g  = (const float*)d_in[20];
    const float* ln2b  = (const float*)d_in[21];
    const float* Wh    = (const float*)d_in[22];
    const float* bh    = (const float*)d_in[23];
    const float* Wout  = (const float*)d_in[24];
    const float* bout  = (const float*)d_in[25];
    float* out = (float*)d_out;

    char* ws = (char*)d_ws;
    const size_t SZ = (size_t)MROWS * Ddim * sizeof(float);   // 12.58 MB
    float* x  = (float*)(ws);
    float* q  = (float*)(ws + SZ);
    float* kk = (float*)(ws + 2 * SZ);
    float* vv = (float*)(ws + 3 * SZ);
    float* ao = (float*)(ws + 4 * SZ);
    float* pr = (float*)(ws + 5 * SZ);
    float* hh = (float*)(ws + 6 * SZ);                        // 4096x3072 = 4*SZ
    int* glob = (int*)(ws + 10 * SZ);
    int* isg  = (int*)(ws + 10 * SZ + 256);

    k_findsep<<<1, 256, 0, stream>>>(ids, glob, isg);
    k_embed<<<MROWS, 256, 0, stream>>>(ids, tok, pos, lneg, lneb, x);

    dim3 g768(Ddim / BN, MROWS / BM);
    dim3 g3072(FFdim / BN, MROWS / BM);
    dim3 gloc(NCdim, Hdim, Bdim);
    dim3 gglb(Gdim, Hdim, Bdim);

    for (int l = 0; l < Ldim; ++l) {
        k_gemm<<<g768, 256, 0, stream>>>(x, Wq + (size_t)l * Ddim * Ddim, bq + l * Ddim, q, MROWS, Ddim, Ddim, 0);
        k_gemm<<<g768, 256, 0, stream>>>(x, Wk + (size_t)l * Ddim * Ddim, bk + l * Ddim, kk, MROWS, Ddim, Ddim, 0);
        k_gemm<<<g768, 256, 0, stream>>>(x, Wv + (size_t)l * Ddim * Ddim, bv + l * Ddim, vv, MROWS, Ddim, Ddim, 0);
        k_attn_local<<<gloc, 128, 0, stream>>>(q, kk, vv, isg, glob, am, ao);
        k_attn_glob<<<gglb, 256, 0, stream>>>(q, kk, vv, glob, am, ao);
        k_gemm<<<g768, 256, 0, stream>>>(ao, Wo + (size_t)l * Ddim * Ddim, bo + l * Ddim, pr, MROWS, Ddim, Ddim, 0);
        k_ln_res<<<MROWS, 256, 0, stream>>>(x, pr, ln1g + l * Ddim, ln1b + l * Ddim);
        k_gemm<<<g3072, 256, 0, stream>>>(x, W1 + (size_t)l * Ddim * FFdim, b1 + l * FFdim, hh, MROWS, FFdim, Ddim, 1);
        k_gemm<<<g768, 256, 0, stream>>>(hh, W2 + (size_t)l * FFdim * Ddim, b2 + l * Ddim, pr, MROWS, Ddim, FFdim, 0);
        k_ln_res<<<MROWS, 256, 0, stream>>>(x, pr, ln2g + l * Ddim, ln2b + l * Ddim);
    }
    k_head<<<Bdim * (NSEPd - 2), 128, 0, stream>>>(x, glob, Wh, bh, Wout, bout, out);
}

// Round 2
// 1495.408 us; speedup vs baseline: 2.2937x; 2.2937x over previous
//
#include <hip/hip_runtime.h>
#include <hip/hip_bf16.h>
#include <math.h>

#define Sdim 2048
#define Bdim 2
#define Ddim 768
#define Hdim 12
#define DHdim 64
#define Ldim 2
#define Cdim 128
#define NCdim 16
#define FFdim 3072
#define Gdim 17
#define NSEPd 16
#define HIDd 100
#define NCLSd 7
#define SEPID 2
#define MROWS (Bdim*Sdim)

typedef __bf16 bf16_t;
typedef bf16_t bf16x8 __attribute__((ext_vector_type(8)));
typedef float f32x4 __attribute__((ext_vector_type(4)));

__device__ __forceinline__ ushort f2bf(float f) {
    union { float f; unsigned u; } a; a.f = f;
    unsigned u = a.u;
    unsigned r = (u + 0x7fffu + ((u >> 16) & 1u)) >> 16;
    return (ushort)r;
}
__device__ __forceinline__ float bf2f(ushort h) {
    union { unsigned u; float f; } a; a.u = ((unsigned)h) << 16;
    return a.f;
}
__device__ __forceinline__ void gload16(const ushort* g, ushort* l) {
    __builtin_amdgcn_global_load_lds(
        (const __attribute__((address_space(1))) void*)g,
        (__attribute__((address_space(3))) void*)l, 16, 0, 0);
}

// ---------------- sep finding ----------------
__global__ void k_findsep(const int* __restrict__ ids, int* __restrict__ glob,
                          int* __restrict__ isg) {
    __shared__ int flag[Sdim];
    __shared__ int gl[Gdim];
    int t = threadIdx.x;
    for (int s = t; s < Sdim; s += blockDim.x) flag[s] = (ids[s] == SEPID) ? 1 : 0;
    __syncthreads();
    if (t == 0) {
        int cnt = 0;
        gl[0] = 0;
        for (int s = 0; s < Sdim && cnt < NSEPd; ++s) if (flag[s]) gl[++cnt] = s;
        while (cnt < NSEPd) gl[++cnt] = 0;
    }
    __syncthreads();
    for (int s = t; s < Sdim; s += blockDim.x) isg[s] = 0;
    if (t < Gdim) glob[t] = gl[t];
    __syncthreads();
    if (t < Gdim) isg[gl[t]] = 1;
}

// ---------------- weight transpose + bf16 convert: W[KxN] f32 -> Wt[NxK] bf16 ----------------
__global__ __launch_bounds__(256) void k_w2bt(const float* __restrict__ W,
        ushort* __restrict__ Wt, int K, int N) {
    __shared__ float tile[32][33];
    int bn = blockIdx.x * 32;
    int bk = blockIdx.y * 32;
    int tx = threadIdx.x & 31, ty = threadIdx.x >> 5;  // ty 0..7
    #pragma unroll
    for (int i = 0; i < 32; i += 8)
        tile[ty + i][tx] = W[(size_t)(bk + ty + i) * N + bn + tx];
    __syncthreads();
    #pragma unroll
    for (int i = 0; i < 32; i += 8)
        Wt[(size_t)(bn + ty + i) * K + bk + tx] = f2bf(tile[tx][ty + i]);
}

// ---------------- embedding + LN (writes f32 x and bf16 xb) ----------------
__global__ __launch_bounds__(256) void k_embed(const int* __restrict__ ids,
        const float* __restrict__ tok, const float* __restrict__ pos,
        const float* __restrict__ g, const float* __restrict__ b,
        float* __restrict__ x, ushort* __restrict__ xb) {
    int row = blockIdx.x;
    int s = row & (Sdim - 1);
    long id = ids[row];
    const float* te = tok + id * (long)Ddim;
    const float* pe = pos + (long)s * Ddim;
    __shared__ float buf[Ddim];
    __shared__ float ra[4], rb[4];
    float ls = 0.f, lq = 0.f;
    for (int d = threadIdx.x; d < Ddim; d += 256) {
        float v = te[d] + pe[d];
        buf[d] = v; ls += v; lq += v * v;
    }
    #pragma unroll
    for (int o = 32; o; o >>= 1) { ls += __shfl_xor(ls, o, 64); lq += __shfl_xor(lq, o, 64); }
    int w = threadIdx.x >> 6;
    if ((threadIdx.x & 63) == 0) { ra[w] = ls; rb[w] = lq; }
    __syncthreads();
    float sum = ra[0] + ra[1] + ra[2] + ra[3];
    float sq  = rb[0] + rb[1] + rb[2] + rb[3];
    float mu = sum / Ddim;
    float var = sq / Ddim - mu * mu;
    float rs = rsqrtf(var + 1e-5f);
    float* xr = x + (long)row * Ddim;
    ushort* xbr = xb + (long)row * Ddim;
    for (int d = threadIdx.x; d < Ddim; d += 256) {
        float v = (buf[d] - mu) * rs * g[d] + b[d];
        xr[d] = v; xbr[d] = f2bf(v);
    }
}

// ---------------- residual add + LN (x = LN(x + a)), writes f32 + bf16 ----------------
__global__ __launch_bounds__(256) void k_ln_res(float* __restrict__ x,
        const float* __restrict__ a, const float* __restrict__ g,
        const float* __restrict__ b, ushort* __restrict__ xb) {
    long row = blockIdx.x;
    __shared__ float buf[Ddim];
    __shared__ float ra[4], rb[4];
    float ls = 0.f, lq = 0.f;
    const float* xr = x + row * Ddim;
    const float* ar = a + row * Ddim;
    for (int d = threadIdx.x; d < Ddim; d += 256) {
        float v = xr[d] + ar[d];
        buf[d] = v; ls += v; lq += v * v;
    }
    #pragma unroll
    for (int o = 32; o; o >>= 1) { ls += __shfl_xor(ls, o, 64); lq += __shfl_xor(lq, o, 64); }
    int w = threadIdx.x >> 6;
    if ((threadIdx.x & 63) == 0) { ra[w] = ls; rb[w] = lq; }
    __syncthreads();
    float sum = ra[0] + ra[1] + ra[2] + ra[3];
    float sq  = rb[0] + rb[1] + rb[2] + rb[3];
    float mu = sum / Ddim;
    float var = sq / Ddim - mu * mu;
    float rs = rsqrtf(var + 1e-5f);
    float* xw = x + row * Ddim;
    ushort* xbr = xb + row * Ddim;
    for (int d = threadIdx.x; d < Ddim; d += 256) {
        float v = (buf[d] - mu) * rs * g[d] + b[d];
        xw[d] = v; xbr[d] = f2bf(v);
    }
}

// ---------------- bf16 MFMA GEMM (m97 structure): C = A[MxK] @ Wt[NxK]^T + bias ----------------
template<int ACT, int OUTBF16>
__global__ __launch_bounds__(256) void k_gemm_bf16(
        const ushort* __restrict__ A, const ushort* __restrict__ Wt,
        const float* __restrict__ bias, void* __restrict__ Cout,
        int M, int N, int K)
{
    __shared__ ushort As[128 * 32];
    __shared__ ushort Bs[128 * 32];
    const int t = threadIdx.x;
    const int bm = blockIdx.y * 128;
    const int bn = blockIdx.x * 128;
    const int lane = t & 63;
    const int wv = t >> 6;
    const int wm = (wv >> 1) * 64;
    const int wn = (wv & 1) * 64;

    const int srow = t >> 2;
    const int scol = (t & 3) * 8;
    const ushort* gA0 = A + (size_t)(bm + srow) * K + scol;
    const ushort* gA1 = A + (size_t)(bm + 64 + srow) * K + scol;
    const ushort* gB0 = Wt + (size_t)(bn + srow) * K + scol;
    const ushort* gB1 = Wt + (size_t)(bn + 64 + srow) * K + scol;
    ushort* lA0 = As + t * 8;
    ushort* lA1 = As + 2048 + t * 8;
    ushort* lB0 = Bs + t * 8;
    ushort* lB1 = Bs + 2048 + t * 8;

    f32x4 acc[4][4] = {};

    const int frow = lane & 15;
    const int koff = (lane >> 4) * 8;

    for (int k0 = 0; k0 < K; k0 += 32) {
        gload16(gA0 + k0, lA0);
        gload16(gA1 + k0, lA1);
        gload16(gB0 + k0, lB0);
        gload16(gB1 + k0, lB1);
        __syncthreads();
        bf16x8 af[4], bfv[4];
        #pragma unroll
        for (int mi = 0; mi < 4; ++mi)
            af[mi] = *reinterpret_cast<const bf16x8*>(As + (wm + mi * 16 + frow) * 32 + koff);
        #pragma unroll
        for (int ni = 0; ni < 4; ++ni)
            bfv[ni] = *reinterpret_cast<const bf16x8*>(Bs + (wn + ni * 16 + frow) * 32 + koff);
        #pragma unroll
        for (int mi = 0; mi < 4; ++mi)
            #pragma unroll
            for (int ni = 0; ni < 4; ++ni)
                acc[mi][ni] = __builtin_amdgcn_mfma_f32_16x16x32_bf16(af[mi], bfv[ni], acc[mi][ni], 0, 0, 0);
        __syncthreads();
    }
    const int crow0 = (lane >> 4) * 4;
    const int ccol = lane & 15;
    #pragma unroll
    for (int mi = 0; mi < 4; ++mi) {
        #pragma unroll
        for (int ni = 0; ni < 4; ++ni) {
            int gc = bn + wn + ni * 16 + ccol;
            float bv = bias[gc];
            #pragma unroll
            for (int j = 0; j < 4; ++j) {
                int gr = bm + wm + mi * 16 + crow0 + j;
                float v = acc[mi][ni][j] + bv;
                if (ACT == 1) {
                    float u = v;
                    v = 0.5f * u * (1.f + tanhf(0.7978845608f * (u + 0.044715f * u * u * u)));
                }
                if (OUTBF16) ((ushort*)Cout)[(size_t)gr * N + gc] = f2bf(v);
                else         ((float*)Cout)[(size_t)gr * N + gc] = v;
            }
        }
    }
}

// ---------------- local (banded) attention + global keys, online softmax ----------------
__global__ __launch_bounds__(128) void k_attn_local(const ushort* __restrict__ q,
        const ushort* __restrict__ k, const ushort* __restrict__ v,
        const int* __restrict__ isg, const int* __restrict__ glob,
        const int* __restrict__ amask, ushort* __restrict__ ao) {
    int n = blockIdx.x, h = blockIdx.y, b = blockIdx.z;
    int c = threadIdx.x;
    int r = n * Cdim + c;
    const long base = (long)b * Sdim * Ddim + h * DHdim;
    float qreg[DHdim];
    #pragma unroll
    for (int d = 0; d < DHdim; ++d) qreg[d] = bf2f(q[base + (long)r * Ddim + d]);
    float m = -1e30f, l = 0.f;
    float acc[DHdim];
    #pragma unroll
    for (int d = 0; d < DHdim; ++d) acc[d] = 0.f;

    __shared__ float kb[32][DHdim];
    __shared__ float vb[32][DHdim];
    __shared__ int kvalid[3 * Cdim];
    __shared__ int gpos[Gdim];
    __shared__ int gok[Gdim];

    for (int j = threadIdx.x; j < 3 * Cdim; j += 128) {
        int p = n * Cdim + j - Cdim;
        int ok = (p >= 0 && p < Sdim);
        if (ok) ok = (amask[b * Sdim + p] != 0) && (isg[p] == 0);
        kvalid[j] = ok;
    }
    if (threadIdx.x < Gdim) {
        int p = glob[threadIdx.x];
        gpos[threadIdx.x] = p;
        gok[threadIdx.x] = (amask[b * Sdim + p] != 0);
    }
    __syncthreads();

    for (int ch = 0; ch < 12; ++ch) {
        for (int i = threadIdx.x; i < 32 * DHdim; i += 128) {
            int jj = i >> 6, d = i & 63;
            int p = n * Cdim + ch * 32 + jj - Cdim;
            float kvv = 0.f, vvv = 0.f;
            if (p >= 0 && p < Sdim) {
                kvv = bf2f(k[base + (long)p * Ddim + d]);
                vvv = bf2f(v[base + (long)p * Ddim + d]);
            }
            kb[jj][d] = kvv; vb[jj][d] = vvv;
        }
        __syncthreads();
        for (int jj = 0; jj < 32; ++jj) {
            int j = ch * 32 + jj;
            if (j < c || j > c + 256 || !kvalid[j]) continue;
            float s = 0.f;
            #pragma unroll
            for (int d = 0; d < DHdim; ++d) s += qreg[d] * kb[jj][d];
            s *= 0.125f;
            if (s > m) {
                float corr = __expf(m - s);
                l *= corr;
                #pragma unroll
                for (int d = 0; d < DHdim; ++d) acc[d] *= corr;
                m = s;
            }
            float p = __expf(s - m);
            l += p;
            #pragma unroll
            for (int d = 0; d < DHdim; ++d) acc[d] += p * vb[jj][d];
        }
        __syncthreads();
    }
    for (int i = threadIdx.x; i < Gdim * DHdim; i += 128) {
        int g = i >> 6, d = i & 63;
        int p = gpos[g];
        kb[g][d] = bf2f(k[base + (long)p * Ddim + d]);
        vb[g][d] = bf2f(v[base + (long)p * Ddim + d]);
    }
    __syncthreads();
    for (int g = 0; g < Gdim; ++g) {
        if (!gok[g]) continue;
        float s = 0.f;
        #pragma unroll
        for (int d = 0; d < DHdim; ++d) s += qreg[d] * kb[g][d];
        s *= 0.125f;
        if (s > m) {
            float corr = __expf(m - s);
            l *= corr;
            #pragma unroll
            for (int d = 0; d < DHdim; ++d) acc[d] *= corr;
            m = s;
        }
        float p = __expf(s - m);
        l += p;
        #pragma unroll
        for (int d = 0; d < DHdim; ++d) acc[d] += p * vb[g][d];
    }
    float inv = 1.f / l;
    #pragma unroll
    for (int d = 0; d < DHdim; ++d)
        ao[base + (long)r * Ddim + d] = f2bf(acc[d] * inv);
}

// ---------------- global token rows attend to all S keys ----------------
__global__ __launch_bounds__(256) void k_attn_glob(const ushort* __restrict__ q,
        const ushort* __restrict__ k, const ushort* __restrict__ v,
        const int* __restrict__ glob, const int* __restrict__ amask,
        ushort* __restrict__ ao) {
    int g = blockIdx.x, h = blockIdx.y, b = blockIdx.z;
    __shared__ float sc[Sdim];
    __shared__ float qs[DHdim];
    __shared__ float redm[4], reds[4];
    __shared__ float part[4][DHdim];
    int t = threadIdx.x;
    int qr = glob[g];
    const long base = (long)b * Sdim * Ddim + h * DHdim;
    if (t < DHdim) qs[t] = bf2f(q[base + (long)qr * Ddim + t]) * 0.125f;
    __syncthreads();
    float lm = -1e30f;
    for (int s0 = t; s0 < Sdim; s0 += 256) {
        float s = 0.f;
        const ushort* kr = k + base + (long)s0 * Ddim;
        #pragma unroll
        for (int d = 0; d < DHdim; ++d) s += qs[d] * bf2f(kr[d]);
        if (amask[b * Sdim + s0] == 0) s = -1e30f;
        sc[s0] = s;
        lm = fmaxf(lm, s);
    }
    #pragma unroll
    for (int o = 32; o; o >>= 1) lm = fmaxf(lm, __shfl_xor(lm, o, 64));
    if ((t & 63) == 0) redm[t >> 6] = lm;
    __syncthreads();
    float mx = fmaxf(fmaxf(redm[0], redm[1]), fmaxf(redm[2], redm[3]));
    float lsum = 0.f;
    for (int s0 = t; s0 < Sdim; s0 += 256) {
        float p = __expf(sc[s0] - mx);
        sc[s0] = p; lsum += p;
    }
    #pragma unroll
    for (int o = 32; o; o >>= 1) lsum += __shfl_xor(lsum, o, 64);
    if ((t & 63) == 0) reds[t >> 6] = lsum;
    __syncthreads();
    float l = reds[0] + reds[1] + reds[2] + reds[3];
    int d = t & 63, chunk = t >> 6;
    float a = 0.f;
    for (int s0 = chunk * 512; s0 < (chunk + 1) * 512; ++s0)
        a += sc[s0] * bf2f(v[base + (long)s0 * Ddim + d]);
    part[chunk][d] = a;
    __syncthreads();
    if (t < DHdim) {
        float o = (part[0][t] + part[1][t] + part[2][t] + part[3][t]) / l;
        ao[base + (long)qr * Ddim + t] = f2bf(o);
    }
}

// ---------------- classification head ----------------
__global__ __launch_bounds__(128) void k_head(const float* __restrict__ x,
        const int* __restrict__ glob, const float* __restrict__ Wh,
        const float* __restrict__ bh, const float* __restrict__ Wout,
        const float* __restrict__ bout, float* __restrict__ out) {
    int i = blockIdx.x;
    int b = i / 14, j = i % 14;
    __shared__ float emb[2 * Ddim];
    __shared__ float hid[HIDd];
    int t = threadIdx.x;
    int p = glob[j + 2];
    for (int d = t; d < Ddim; d += 128) {
        emb[d] = x[(long)b * Sdim * Ddim + d];
        emb[Ddim + d] = x[((long)b * Sdim + p) * Ddim + d];
    }
    __syncthreads();
    if (t < HIDd) {
        float s = bh[t];
        for (int k1 = 0; k1 < 2 * Ddim; ++k1) s += emb[k1] * Wh[k1 * HIDd + t];
        hid[t] = fmaxf(s, 0.f);
    }
    __syncthreads();
    if (t < NCLSd) {
        float s = bout[t];
        for (int o = 0; o < HIDd; ++o) s += hid[o] * Wout[o * NCLSd + t];
        out[i * NCLSd + t] = s;
    }
}

extern "C" void kernel_launch(void* const* d_in, const int* in_sizes, int n_in,
                              void* d_out, int out_size, void* d_ws, size_t ws_size,
                              hipStream_t stream) {
    const int*   ids   = (const int*)d_in[0];
    const int*   am    = (const int*)d_in[1];
    const float* tok   = (const float*)d_in[2];
    const float* pos   = (const float*)d_in[3];
    const float* lneg  = (const float*)d_in[4];
    const float* lneb  = (const float*)d_in[5];
    const float* Wq    = (const float*)d_in[6];
    const float* bq    = (const float*)d_in[7];
    const float* Wk    = (const float*)d_in[8];
    const float* bk    = (const float*)d_in[9];
    const float* Wv    = (const float*)d_in[10];
    const float* bv    = (const float*)d_in[11];
    const float* Wo    = (const float*)d_in[12];
    const float* bo    = (const float*)d_in[13];
    const float* ln1g  = (const float*)d_in[14];
    const float* ln1b  = (const float*)d_in[15];
    const float* W1    = (const float*)d_in[16];
    const float* b1    = (const float*)d_in[17];
    const float* W2    = (const float*)d_in[18];
    const float* b2    = (const float*)d_in[19];
    const float* ln2g  = (const float*)d_in[20];
    const float* ln2b  = (const float*)d_in[21];
    const float* Wh    = (const float*)d_in[22];
    const float* bh    = (const float*)d_in[23];
    const float* Wout  = (const float*)d_in[24];
    const float* bout  = (const float*)d_in[25];
    float* out = (float*)d_out;

    char* ws = (char*)d_ws;
    const size_t SZ = (size_t)MROWS * Ddim * sizeof(float);    // 12.58 MB
    const size_t HB = SZ / 2;                                   // bf16 shadow
    size_t off = 0;
    float*  x   = (float*)(ws + off);  off += SZ;
    float*  pr  = (float*)(ws + off);  off += SZ;
    ushort* xb  = (ushort*)(ws + off); off += HB;
    ushort* qB  = (ushort*)(ws + off); off += HB;
    ushort* kB  = (ushort*)(ws + off); off += HB;
    ushort* vB  = (ushort*)(ws + off); off += HB;
    ushort* aoB = (ushort*)(ws + off); off += HB;
    ushort* hh  = (ushort*)(ws + off); off += (size_t)MROWS * FFdim * 2;
    const size_t WSMALL = (size_t)Ddim * Ddim;      // 589824 elements
    const size_t WBIG   = (size_t)Ddim * FFdim;     // 2359296 elements
    const size_t WL     = 4 * WSMALL + 2 * WBIG;    // per-layer bf16 weight elems
    ushort* wts = (ushort*)(ws + off); off += WL * Ldim * 2;
    int* glob = (int*)(ws + off); off += 256;
    int* isg  = (int*)(ws + off);

    k_findsep<<<1, 256, 0, stream>>>(ids, glob, isg);

    // weight conversion (transpose to N-major bf16)
    for (int l = 0; l < Ldim; ++l) {
        ushort* base = wts + l * WL;
        ushort* Wqt = base;
        ushort* Wkt = base + WSMALL;
        ushort* Wvt = base + 2 * WSMALL;
        ushort* Wot = base + 3 * WSMALL;
        ushort* W1t = base + 4 * WSMALL;
        ushort* W2t = base + 4 * WSMALL + WBIG;
        dim3 t768(Ddim / 32, Ddim / 32);
        k_w2bt<<<t768, 256, 0, stream>>>(Wq + (size_t)l * WSMALL, Wqt, Ddim, Ddim);
        k_w2bt<<<t768, 256, 0, stream>>>(Wk + (size_t)l * WSMALL, Wkt, Ddim, Ddim);
        k_w2bt<<<t768, 256, 0, stream>>>(Wv + (size_t)l * WSMALL, Wvt, Ddim, Ddim);
        k_w2bt<<<t768, 256, 0, stream>>>(Wo + (size_t)l * WSMALL, Wot, Ddim, Ddim);
        k_w2bt<<<dim3(FFdim / 32, Ddim / 32), 256, 0, stream>>>(W1 + (size_t)l * WBIG, W1t, Ddim, FFdim);
        k_w2bt<<<dim3(Ddim / 32, FFdim / 32), 256, 0, stream>>>(W2 + (size_t)l * WBIG, W2t, FFdim, Ddim);
    }

    k_embed<<<MROWS, 256, 0, stream>>>(ids, tok, pos, lneg, lneb, x, xb);

    dim3 g768(Ddim / 128, MROWS / 128);
    dim3 gFF(FFdim / 128, MROWS / 128);
    dim3 gloc(NCdim, Hdim, Bdim);
    dim3 gglb(Gdim, Hdim, Bdim);

    for (int l = 0; l < Ldim; ++l) {
        ushort* base = wts + l * WL;
        ushort* Wqt = base;
        ushort* Wkt = base + WSMALL;
        ushort* Wvt = base + 2 * WSMALL;
        ushort* Wot = base + 3 * WSMALL;
        ushort* W1t = base + 4 * WSMALL;
        ushort* W2t = base + 4 * WSMALL + WBIG;
        k_gemm_bf16<0,1><<<g768, 256, 0, stream>>>(xb, Wqt, bq + l * Ddim, qB, MROWS, Ddim, Ddim);
        k_gemm_bf16<0,1><<<g768, 256, 0, stream>>>(xb, Wkt, bk + l * Ddim, kB, MROWS, Ddim, Ddim);
        k_gemm_bf16<0,1><<<g768, 256, 0, stream>>>(xb, Wvt, bv + l * Ddim, vB, MROWS, Ddim, Ddim);
        k_attn_local<<<gloc, 128, 0, stream>>>(qB, kB, vB, isg, glob, am, aoB);
        k_attn_glob<<<gglb, 256, 0, stream>>>(qB, kB, vB, glob, am, aoB);
        k_gemm_bf16<0,0><<<g768, 256, 0, stream>>>(aoB, Wot, bo + l * Ddim, pr, MROWS, Ddim, Ddim);
        k_ln_res<<<MROWS, 256, 0, stream>>>(x, pr, ln1g + l * Ddim, ln1b + l * Ddim, xb);
        k_gemm_bf16<1,1><<<gFF, 256, 0, stream>>>(xb, W1t, b1 + l * FFdim, hh, MROWS, FFdim, Ddim);
        k_gemm_bf16<0,0><<<g768, 256, 0, stream>>>(hh, W2t, b2 + l * Ddim, pr, MROWS, Ddim, FFdim);
        k_ln_res<<<MROWS, 256, 0, stream>>>(x, pr, ln2g + l * Ddim, ln2b + l * Ddim, xb);
    }
    k_head<<<Bdim * (NSEPd - 2), 128, 0, stream>>>(x, glob, Wh, bh, Wout, bout, out);
}

// Round 3
// 763.553 us; speedup vs baseline: 4.4921x; 1.9585x over previous
//
#include <hip/hip_runtime.h>
#include <hip/hip_bf16.h>
#include <math.h>

#define Sdim 2048
#define Bdim 2
#define Ddim 768
#define Hdim 12
#define DHdim 64
#define Ldim 2
#define Cdim 128
#define NCdim 16
#define FFdim 3072
#define Gdim 17
#define NSEPd 16
#define HIDd 100
#define NCLSd 7
#define SEPID 2
#define MROWS (Bdim*Sdim)
#define QKVS 2304

typedef __bf16 bf16_t;
typedef bf16_t bf16x8 __attribute__((ext_vector_type(8)));
typedef float f32x4 __attribute__((ext_vector_type(4)));
typedef ushort ushort8v __attribute__((ext_vector_type(8)));

__device__ __forceinline__ ushort f2bf(float f) {
    union { float f; unsigned u; } a; a.f = f;
    unsigned u = a.u;
    unsigned r = (u + 0x7fffu + ((u >> 16) & 1u)) >> 16;
    return (ushort)r;
}
__device__ __forceinline__ float bf2f(ushort h) {
    union { unsigned u; float f; } a; a.u = ((unsigned)h) << 16;
    return a.f;
}
__device__ __forceinline__ void gload16(const ushort* g, ushort* l) {
    __builtin_amdgcn_global_load_lds(
        (const __attribute__((address_space(1))) void*)g,
        (__attribute__((address_space(3))) void*)l, 16, 0, 0);
}

// ---------------- sep finding ----------------
__global__ void k_findsep(const int* __restrict__ ids, int* __restrict__ glob,
                          int* __restrict__ isg) {
    __shared__ int flag[Sdim];
    __shared__ int gl[Gdim];
    int t = threadIdx.x;
    for (int s = t; s < Sdim; s += blockDim.x) flag[s] = (ids[s] == SEPID) ? 1 : 0;
    __syncthreads();
    if (t == 0) {
        int cnt = 0;
        gl[0] = 0;
        for (int s = 0; s < Sdim && cnt < NSEPd; ++s) if (flag[s]) gl[++cnt] = s;
        while (cnt < NSEPd) gl[++cnt] = 0;
    }
    __syncthreads();
    for (int s = t; s < Sdim; s += blockDim.x) isg[s] = 0;
    if (t < Gdim) glob[t] = gl[t];
    __syncthreads();
    if (t < Gdim) isg[gl[t]] = 1;
}

// ---------------- weight transpose + bf16 convert: W[KxN] f32 -> Wt[NxK] bf16 ----------------
__global__ __launch_bounds__(256) void k_w2bt(const float* __restrict__ W,
        ushort* __restrict__ Wt, int K, int N) {
    __shared__ float tile[32][33];
    int bn = blockIdx.x * 32;
    int bk = blockIdx.y * 32;
    int tx = threadIdx.x & 31, ty = threadIdx.x >> 5;
    #pragma unroll
    for (int i = 0; i < 32; i += 8)
        tile[ty + i][tx] = W[(size_t)(bk + ty + i) * N + bn + tx];
    __syncthreads();
    #pragma unroll
    for (int i = 0; i < 32; i += 8)
        Wt[(size_t)(bn + ty + i) * K + bk + tx] = f2bf(tile[tx][ty + i]);
}

// ---------------- concat q/k/v biases -> [L][2304] ----------------
__global__ void k_biascat(const float* __restrict__ bq, const float* __restrict__ bk,
                          const float* __restrict__ bv, float* __restrict__ bqkv) {
    int l = blockIdx.x, t = threadIdx.x;
    for (int i = t; i < QKVS; i += 256) {
        float v = (i < Ddim) ? bq[l * Ddim + i]
                : (i < 2 * Ddim) ? bk[l * Ddim + i - Ddim]
                : bv[l * Ddim + i - 2 * Ddim];
        bqkv[l * QKVS + i] = v;
    }
}

// ---------------- embedding + LN (writes f32 x and bf16 xb) ----------------
__global__ __launch_bounds__(256) void k_embed(const int* __restrict__ ids,
        const float* __restrict__ tok, const float* __restrict__ pos,
        const float* __restrict__ g, const float* __restrict__ b,
        float* __restrict__ x, ushort* __restrict__ xb) {
    int row = blockIdx.x;
    int s = row & (Sdim - 1);
    long id = ids[row];
    const float* te = tok + id * (long)Ddim;
    const float* pe = pos + (long)s * Ddim;
    __shared__ float buf[Ddim];
    __shared__ float ra[4], rb[4];
    float ls = 0.f, lq = 0.f;
    for (int d = threadIdx.x; d < Ddim; d += 256) {
        float v = te[d] + pe[d];
        buf[d] = v; ls += v; lq += v * v;
    }
    #pragma unroll
    for (int o = 32; o; o >>= 1) { ls += __shfl_xor(ls, o, 64); lq += __shfl_xor(lq, o, 64); }
    int w = threadIdx.x >> 6;
    if ((threadIdx.x & 63) == 0) { ra[w] = ls; rb[w] = lq; }
    __syncthreads();
    float sum = ra[0] + ra[1] + ra[2] + ra[3];
    float sq  = rb[0] + rb[1] + rb[2] + rb[3];
    float mu = sum / Ddim;
    float var = sq / Ddim - mu * mu;
    float rs = rsqrtf(var + 1e-5f);
    float* xr = x + (long)row * Ddim;
    ushort* xbr = xb + (long)row * Ddim;
    for (int d = threadIdx.x; d < Ddim; d += 256) {
        float v = (buf[d] - mu) * rs * g[d] + b[d];
        xr[d] = v; xbr[d] = f2bf(v);
    }
}

// ---------------- residual add + LN, writes f32 + bf16 ----------------
__global__ __launch_bounds__(256) void k_ln_res(float* __restrict__ x,
        const float* __restrict__ a, const float* __restrict__ g,
        const float* __restrict__ b, ushort* __restrict__ xb) {
    long row = blockIdx.x;
    __shared__ float buf[Ddim];
    __shared__ float ra[4], rb[4];
    float ls = 0.f, lq = 0.f;
    const float* xr = x + row * Ddim;
    const float* ar = a + row * Ddim;
    for (int d = threadIdx.x; d < Ddim; d += 256) {
        float v = xr[d] + ar[d];
        buf[d] = v; ls += v; lq += v * v;
    }
    #pragma unroll
    for (int o = 32; o; o >>= 1) { ls += __shfl_xor(ls, o, 64); lq += __shfl_xor(lq, o, 64); }
    int w = threadIdx.x >> 6;
    if ((threadIdx.x & 63) == 0) { ra[w] = ls; rb[w] = lq; }
    __syncthreads();
    float sum = ra[0] + ra[1] + ra[2] + ra[3];
    float sq  = rb[0] + rb[1] + rb[2] + rb[3];
    float mu = sum / Ddim;
    float var = sq / Ddim - mu * mu;
    float rs = rsqrtf(var + 1e-5f);
    float* xw = x + row * Ddim;
    ushort* xbr = xb + row * Ddim;
    for (int d = threadIdx.x; d < Ddim; d += 256) {
        float v = (buf[d] - mu) * rs * g[d] + b[d];
        xw[d] = v; xbr[d] = f2bf(v);
    }
}

// ---------------- bf16 MFMA GEMM (m97 structure): C = A[MxK] @ Wt[NxK]^T + bias ----------------
template<int ACT, int OUTBF16>
__global__ __launch_bounds__(256) void k_gemm_bf16(
        const ushort* __restrict__ A, const ushort* __restrict__ Wt,
        const float* __restrict__ bias, void* __restrict__ Cout,
        int M, int N, int K)
{
    __shared__ ushort As[128 * 32];
    __shared__ ushort Bs[128 * 32];
    const int t = threadIdx.x;
    const int bm = blockIdx.y * 128;
    const int bn = blockIdx.x * 128;
    const int lane = t & 63;
    const int wv = t >> 6;
    const int wm = (wv >> 1) * 64;
    const int wn = (wv & 1) * 64;

    const int srow = t >> 2;
    const int scol = (t & 3) * 8;
    const ushort* gA0 = A + (size_t)(bm + srow) * K + scol;
    const ushort* gA1 = A + (size_t)(bm + 64 + srow) * K + scol;
    const ushort* gB0 = Wt + (size_t)(bn + srow) * K + scol;
    const ushort* gB1 = Wt + (size_t)(bn + 64 + srow) * K + scol;
    ushort* lA0 = As + t * 8;
    ushort* lA1 = As + 2048 + t * 8;
    ushort* lB0 = Bs + t * 8;
    ushort* lB1 = Bs + 2048 + t * 8;

    f32x4 acc[4][4] = {};

    const int frow = lane & 15;
    const int koff = (lane >> 4) * 8;

    for (int k0 = 0; k0 < K; k0 += 32) {
        gload16(gA0 + k0, lA0);
        gload16(gA1 + k0, lA1);
        gload16(gB0 + k0, lB0);
        gload16(gB1 + k0, lB1);
        __syncthreads();
        bf16x8 af[4], bfv[4];
        #pragma unroll
        for (int mi = 0; mi < 4; ++mi)
            af[mi] = *reinterpret_cast<const bf16x8*>(As + (wm + mi * 16 + frow) * 32 + koff);
        #pragma unroll
        for (int ni = 0; ni < 4; ++ni)
            bfv[ni] = *reinterpret_cast<const bf16x8*>(Bs + (wn + ni * 16 + frow) * 32 + koff);
        #pragma unroll
        for (int mi = 0; mi < 4; ++mi)
            #pragma unroll
            for (int ni = 0; ni < 4; ++ni)
                acc[mi][ni] = __builtin_amdgcn_mfma_f32_16x16x32_bf16(af[mi], bfv[ni], acc[mi][ni], 0, 0, 0);
        __syncthreads();
    }
    const int crow0 = (lane >> 4) * 4;
    const int ccol = lane & 15;
    #pragma unroll
    for (int mi = 0; mi < 4; ++mi) {
        #pragma unroll
        for (int ni = 0; ni < 4; ++ni) {
            int gc = bn + wn + ni * 16 + ccol;
            float bv = bias[gc];
            #pragma unroll
            for (int j = 0; j < 4; ++j) {
                int gr = bm + wm + mi * 16 + crow0 + j;
                float v = acc[mi][ni][j] + bv;
                if (ACT == 1) {
                    float u = v;
                    v = 0.5f * u * (1.f + tanhf(0.7978845608f * (u + 0.044715f * u * u * u)));
                }
                if (OUTBF16) ((ushort*)Cout)[(size_t)gr * N + gc] = f2bf(v);
                else         ((float*)Cout)[(size_t)gr * N + gc] = v;
            }
        }
    }
}

// ---------------- MFMA flash local attention ----------------
// grid (NC, H, B), block 256 (4 waves, wave wv owns q rows wv*32..+31 of the chunk)
// keys: tiles 0..11 = banded local (pos = n*128 + j - 128), tile 12 = 17 globals + pad
__global__ __launch_bounds__(256) void k_attn_mfma(
        const ushort* __restrict__ qkv, const int* __restrict__ isg,
        const int* __restrict__ glob, const int* __restrict__ amask,
        ushort* __restrict__ ao)
{
    const int n = blockIdx.x, h = blockIdx.y, b = blockIdx.z;
    const int t = threadIdx.x;
    const int lane = t & 63, wv = t >> 6;
    const int R0 = b * Sdim;
    const int l15 = lane & 15, l4 = lane >> 4;

    __shared__ ushort Kb[32 * 64];        // swizzled [key][64]
    __shared__ ushort Vt[64 * 40];        // [d][key] pad 40
    __shared__ ushort Plds[4][32 * 40];   // per-wave P, pad 40
    __shared__ float  maskLDS[416];

    // validity mask (local: inb & amask & !isg ; global: g<17 & amask)
    for (int i = t; i < 416; i += 256) {
        int ok;
        if (i < 384) {
            int pos = n * Cdim + i - Cdim;
            ok = (pos >= 0 && pos < Sdim);
            if (ok) ok = (amask[b * Sdim + pos] != 0) && (isg[pos] == 0);
        } else {
            int g = i - 384;
            ok = (g < Gdim) && (amask[b * Sdim + glob[g]] != 0);
        }
        maskLDS[i] = ok ? 0.f : -1e9f;
    }

    // Q fragments (rows wv*32 + qi*16 + l15, k = kh*32 + l4*8)
    bf16x8 qf[2][2];
    #pragma unroll
    for (int qi = 0; qi < 2; ++qi)
        #pragma unroll
        for (int kh = 0; kh < 2; ++kh)
            qf[qi][kh] = *reinterpret_cast<const bf16x8*>(
                qkv + (size_t)(R0 + n * Cdim + wv * 32 + qi * 16 + l15) * QKVS
                    + h * DHdim + kh * 32 + l4 * 8);

    f32x4 accO[2][4] = {};
    float mrow[2][4], lrow[2][4];
    #pragma unroll
    for (int qi = 0; qi < 2; ++qi)
        #pragma unroll
        for (int j = 0; j < 4; ++j) { mrow[qi][j] = -1e30f; lrow[qi][j] = 0.f; }

    const int jj = t >> 3, c16 = t & 7;
    auto ldkv = [&](int kt, ushort8v& kr, ushort8v& vr) {
        int j = kt * 32 + jj;
        int pos = 0; bool ok;
        if (j < 384) { pos = n * Cdim + j - Cdim; ok = (pos >= 0 && pos < Sdim); }
        else { int g = j - 384; ok = (g < Gdim); if (ok) pos = glob[g]; }
        ushort8v z = {};
        if (ok) {
            const ushort* kp = qkv + (size_t)(R0 + pos) * QKVS + Ddim + h * DHdim + c16 * 8;
            kr = *reinterpret_cast<const ushort8v*>(kp);
            vr = *reinterpret_cast<const ushort8v*>(kp + Ddim);
        } else { kr = z; vr = z; }
    };

    ushort8v kreg, vreg, kreg2, vreg2;
    ldkv(0, kreg, vreg);

    for (int kt = 0; kt < 13; ++kt) {
        __syncthreads();   // all waves done reading previous tile
        // stage K (swizzled) + V^T
        *reinterpret_cast<ushort8v*>(&Kb[jj * 64 + ((c16 ^ (jj & 7)) * 8)]) = kreg;
        #pragma unroll
        for (int e = 0; e < 8; ++e) Vt[(c16 * 8 + e) * 40 + jj] = vreg[e];
        if (kt < 12) ldkv(kt + 1, kreg2, vreg2);
        __syncthreads();   // staged tile visible

        // K fragments
        bf16x8 kf[2][2];
        #pragma unroll
        for (int kj = 0; kj < 2; ++kj) {
            int key = kj * 16 + l15;
            #pragma unroll
            for (int kh = 0; kh < 2; ++kh) {
                int cc = (kh * 4 + l4) ^ (key & 7);
                kf[kj][kh] = *reinterpret_cast<const bf16x8*>(&Kb[key * 64 + cc * 8]);
            }
        }
        float ma[2];
        ma[0] = maskLDS[kt * 32 + l15];
        ma[1] = maskLDS[kt * 32 + 16 + l15];

        #pragma unroll
        for (int qi = 0; qi < 2; ++qi) {
            f32x4 s0 = {}, s1 = {};
            #pragma unroll
            for (int kh = 0; kh < 2; ++kh) {
                s0 = __builtin_amdgcn_mfma_f32_16x16x32_bf16(qf[qi][kh], kf[0][kh], s0, 0, 0, 0);
                s1 = __builtin_amdgcn_mfma_f32_16x16x32_bf16(qf[qi][kh], kf[1][kh], s1, 0, 0, 0);
            }
            float sf[2][4];
            #pragma unroll
            for (int kj = 0; kj < 2; ++kj) {
                int key = kt * 32 + kj * 16 + l15;
                #pragma unroll
                for (int j = 0; j < 4; ++j) {
                    int cq = wv * 32 + qi * 16 + l4 * 4 + j;
                    float s = (kj ? s1[j] : s0[j]) * 0.125f + ma[kj];
                    bool band = (key >= 384) || ((unsigned)(key - cq) <= 256u);
                    sf[kj][j] = band ? s : s - 1e9f;
                }
            }
            float mnew[4], corr[4];
            #pragma unroll
            for (int j = 0; j < 4; ++j) {
                float v = fmaxf(sf[0][j], sf[1][j]);
                v = fmaxf(v, __shfl_xor(v, 1, 64));
                v = fmaxf(v, __shfl_xor(v, 2, 64));
                v = fmaxf(v, __shfl_xor(v, 4, 64));
                v = fmaxf(v, __shfl_xor(v, 8, 64));
                mnew[j] = fmaxf(mrow[qi][j], v);
                corr[j] = __expf(mrow[qi][j] - mnew[j]);
                mrow[qi][j] = mnew[j];
            }
            float ps[2][4];
            #pragma unroll
            for (int kj = 0; kj < 2; ++kj)
                #pragma unroll
                for (int j = 0; j < 4; ++j)
                    ps[kj][j] = __expf(sf[kj][j] - mnew[j]);
            #pragma unroll
            for (int j = 0; j < 4; ++j) {
                float r = ps[0][j] + ps[1][j];
                r += __shfl_xor(r, 1, 64);
                r += __shfl_xor(r, 2, 64);
                r += __shfl_xor(r, 4, 64);
                r += __shfl_xor(r, 8, 64);
                lrow[qi][j] = lrow[qi][j] * corr[j] + r;
            }
            #pragma unroll
            for (int dt = 0; dt < 4; ++dt)
                #pragma unroll
                for (int j = 0; j < 4; ++j)
                    accO[qi][dt][j] *= corr[j];
            #pragma unroll
            for (int kj = 0; kj < 2; ++kj)
                #pragma unroll
                for (int j = 0; j < 4; ++j)
                    Plds[wv][(qi * 16 + l4 * 4 + j) * 40 + kj * 16 + l15] = f2bf(ps[kj][j]);
        }
        // PV
        #pragma unroll
        for (int qi = 0; qi < 2; ++qi) {
            bf16x8 af = *reinterpret_cast<const bf16x8*>(&Plds[wv][(qi * 16 + l15) * 40 + l4 * 8]);
            #pragma unroll
            for (int dt = 0; dt < 4; ++dt) {
                bf16x8 vf = *reinterpret_cast<const bf16x8*>(&Vt[(dt * 16 + l15) * 40 + l4 * 8]);
                accO[qi][dt] = __builtin_amdgcn_mfma_f32_16x16x32_bf16(af, vf, accO[qi][dt], 0, 0, 0);
            }
        }
        kreg = kreg2; vreg = vreg2;
    }

    // epilogue
    #pragma unroll
    for (int qi = 0; qi < 2; ++qi) {
        float inv[4];
        #pragma unroll
        for (int j = 0; j < 4; ++j) inv[j] = 1.f / lrow[qi][j];
        #pragma unroll
        for (int dt = 0; dt < 4; ++dt) {
            #pragma unroll
            for (int j = 0; j < 4; ++j) {
                int crow = n * Cdim + wv * 32 + qi * 16 + l4 * 4 + j;
                ao[(size_t)(R0 + crow) * Ddim + h * DHdim + dt * 16 + l15] =
                    f2bf(accO[qi][dt][j] * inv[j]);
            }
        }
    }
}

// ---------------- global token rows attend to all S keys ----------------
__global__ __launch_bounds__(256) void k_attn_glob(const ushort* __restrict__ qkv,
        const int* __restrict__ glob, const int* __restrict__ amask,
        ushort* __restrict__ ao) {
    int g = blockIdx.x, h = blockIdx.y, b = blockIdx.z;
    __shared__ float sc[Sdim];
    __shared__ float qs[DHdim];
    __shared__ float redm[4], reds[4];
    __shared__ float part[32][DHdim];
    int t = threadIdx.x;
    int qr = glob[g];
    const int R0 = b * Sdim;
    if (t < DHdim)
        qs[t] = bf2f(qkv[(size_t)(R0 + qr) * QKVS + h * DHdim + t]) * 0.125f;
    __syncthreads();
    float lm = -1e30f;
    for (int s0 = t; s0 < Sdim; s0 += 256) {
        const ushort8v* kr = (const ushort8v*)(qkv + (size_t)(R0 + s0) * QKVS + Ddim + h * DHdim);
        float s = 0.f;
        #pragma unroll
        for (int cc = 0; cc < 8; ++cc) {
            ushort8v kv = kr[cc];
            #pragma unroll
            for (int e = 0; e < 8; ++e) s += qs[cc * 8 + e] * bf2f(kv[e]);
        }
        if (amask[b * Sdim + s0] == 0) s = -1e30f;
        sc[s0] = s;
        lm = fmaxf(lm, s);
    }
    #pragma unroll
    for (int o = 32; o; o >>= 1) lm = fmaxf(lm, __shfl_xor(lm, o, 64));
    if ((t & 63) == 0) redm[t >> 6] = lm;
    __syncthreads();
    float mx = fmaxf(fmaxf(redm[0], redm[1]), fmaxf(redm[2], redm[3]));
    float lsum = 0.f;
    for (int s0 = t; s0 < Sdim; s0 += 256) {
        float p = __expf(sc[s0] - mx);
        sc[s0] = p; lsum += p;
    }
    #pragma unroll
    for (int o = 32; o; o >>= 1) lsum += __shfl_xor(lsum, o, 64);
    if ((t & 63) == 0) reds[t >> 6] = lsum;
    __syncthreads();
    float l = reds[0] + reds[1] + reds[2] + reds[3];
    // V pass: thread = (chunk of 64 rows) x (8 d), vectorized row reads
    int chunk = t >> 3, dg = t & 7;
    float a[8] = {};
    for (int r = chunk * 64; r < chunk * 64 + 64; ++r) {
        float p = sc[r];
        ushort8v vv = *(const ushort8v*)(qkv + (size_t)(R0 + r) * QKVS + 2 * Ddim + h * DHdim + dg * 8);
        #pragma unroll
        for (int e = 0; e < 8; ++e) a[e] += p * bf2f(vv[e]);
    }
    #pragma unroll
    for (int e = 0; e < 8; ++e) part[chunk][dg * 8 + e] = a[e];
    __syncthreads();
    if (t < DHdim) {
        float o = 0.f;
        #pragma unroll
        for (int c = 0; c < 32; ++c) o += part[c][t];
        ao[(size_t)(R0 + qr) * Ddim + h * DHdim + t] = f2bf(o / l);
    }
}

// ---------------- classification head ----------------
__global__ __launch_bounds__(128) void k_head(const float* __restrict__ x,
        const int* __restrict__ glob, const float* __restrict__ Wh,
        const float* __restrict__ bh, const float* __restrict__ Wout,
        const float* __restrict__ bout, float* __restrict__ out) {
    int i = blockIdx.x;
    int b = i / 14, j = i % 14;
    __shared__ float emb[2 * Ddim];
    __shared__ float hid[HIDd];
    int t = threadIdx.x;
    int p = glob[j + 2];
    for (int d = t; d < Ddim; d += 128) {
        emb[d] = x[(long)b * Sdim * Ddim + d];
        emb[Ddim + d] = x[((long)b * Sdim + p) * Ddim + d];
    }
    __syncthreads();
    if (t < HIDd) {
        float s = bh[t];
        for (int k1 = 0; k1 < 2 * Ddim; ++k1) s += emb[k1] * Wh[k1 * HIDd + t];
        hid[t] = fmaxf(s, 0.f);
    }
    __syncthreads();
    if (t < NCLSd) {
        float s = bout[t];
        for (int o = 0; o < HIDd; ++o) s += hid[o] * Wout[o * NCLSd + t];
        out[i * NCLSd + t] = s;
    }
}

extern "C" void kernel_launch(void* const* d_in, const int* in_sizes, int n_in,
                              void* d_out, int out_size, void* d_ws, size_t ws_size,
                              hipStream_t stream) {
    const int*   ids   = (const int*)d_in[0];
    const int*   am    = (const int*)d_in[1];
    const float* tok   = (const float*)d_in[2];
    const float* pos   = (const float*)d_in[3];
    const float* lneg  = (const float*)d_in[4];
    const float* lneb  = (const float*)d_in[5];
    const float* Wq    = (const float*)d_in[6];
    const float* bq    = (const float*)d_in[7];
    const float* Wk    = (const float*)d_in[8];
    const float* bk    = (const float*)d_in[9];
    const float* Wv    = (const float*)d_in[10];
    const float* bv    = (const float*)d_in[11];
    const float* Wo    = (const float*)d_in[12];
    const float* bo    = (const float*)d_in[13];
    const float* ln1g  = (const float*)d_in[14];
    const float* ln1b  = (const float*)d_in[15];
    const float* W1    = (const float*)d_in[16];
    const float* b1    = (const float*)d_in[17];
    const float* W2    = (const float*)d_in[18];
    const float* b2    = (const float*)d_in[19];
    const float* ln2g  = (const float*)d_in[20];
    const float* ln2b  = (const float*)d_in[21];
    const float* Wh    = (const float*)d_in[22];
    const float* bh    = (const float*)d_in[23];
    const float* Wout  = (const float*)d_in[24];
    const float* bout  = (const float*)d_in[25];
    float* out = (float*)d_out;

    char* ws = (char*)d_ws;
    const size_t SZ = (size_t)MROWS * Ddim * sizeof(float);
    const size_t HB = SZ / 2;
    size_t off = 0;
    float*  x    = (float*)(ws + off);  off += SZ;
    float*  pr   = (float*)(ws + off);  off += SZ;
    ushort* xb   = (ushort*)(ws + off); off += HB;
    ushort* qkvB = (ushort*)(ws + off); off += (size_t)MROWS * QKVS * 2;
    ushort* aoB  = (ushort*)(ws + off); off += HB;
    ushort* hh   = (ushort*)(ws + off); off += (size_t)MROWS * FFdim * 2;
    const size_t WSMALL = (size_t)Ddim * Ddim;
    const size_t WBIG   = (size_t)Ddim * FFdim;
    const size_t WL     = 4 * WSMALL + 2 * WBIG;
    ushort* wts = (ushort*)(ws + off); off += WL * Ldim * 2;
    float* bqkv = (float*)(ws + off);  off += Ldim * QKVS * sizeof(float);
    int* glob = (int*)(ws + off); off += 256;
    int* isg  = (int*)(ws + off);

    k_findsep<<<1, 256, 0, stream>>>(ids, glob, isg);
    k_biascat<<<Ldim, 256, 0, stream>>>(bq, bk, bv, bqkv);

    for (int l = 0; l < Ldim; ++l) {
        ushort* base = wts + l * WL;
        dim3 t768(Ddim / 32, Ddim / 32);
        k_w2bt<<<t768, 256, 0, stream>>>(Wq + (size_t)l * WSMALL, base, Ddim, Ddim);
        k_w2bt<<<t768, 256, 0, stream>>>(Wk + (size_t)l * WSMALL, base + WSMALL, Ddim, Ddim);
        k_w2bt<<<t768, 256, 0, stream>>>(Wv + (size_t)l * WSMALL, base + 2 * WSMALL, Ddim, Ddim);
        k_w2bt<<<t768, 256, 0, stream>>>(Wo + (size_t)l * WSMALL, base + 3 * WSMALL, Ddim, Ddim);
        k_w2bt<<<dim3(FFdim / 32, Ddim / 32), 256, 0, stream>>>(W1 + (size_t)l * WBIG, base + 4 * WSMALL, Ddim, FFdim);
        k_w2bt<<<dim3(Ddim / 32, FFdim / 32), 256, 0, stream>>>(W2 + (size_t)l * WBIG, base + 4 * WSMALL + WBIG, FFdim, Ddim);
    }

    k_embed<<<MROWS, 256, 0, stream>>>(ids, tok, pos, lneg, lneb, x, xb);

    dim3 g768(Ddim / 128, MROWS / 128);
    dim3 gQKV(QKVS / 128, MROWS / 128);
    dim3 gFF(FFdim / 128, MROWS / 128);
    dim3 gloc(NCdim, Hdim, Bdim);
    dim3 gglb(Gdim, Hdim, Bdim);

    for (int l = 0; l < Ldim; ++l) {
        ushort* base = wts + l * WL;
        ushort* Wqkvt = base;                       // rows 0..767 Q, 768..1535 K, 1536..2303 V
        ushort* Wot = base + 3 * WSMALL;
        ushort* W1t = base + 4 * WSMALL;
        ushort* W2t = base + 4 * WSMALL + WBIG;
        k_gemm_bf16<0,1><<<gQKV, 256, 0, stream>>>(xb, Wqkvt, bqkv + l * QKVS, qkvB, MROWS, QKVS, Ddim);
        k_attn_mfma<<<gloc, 256, 0, stream>>>(qkvB, isg, glob, am, aoB);
        k_attn_glob<<<gglb, 256, 0, stream>>>(qkvB, glob, am, aoB);
        k_gemm_bf16<0,0><<<g768, 256, 0, stream>>>(aoB, Wot, bo + l * Ddim, pr, MROWS, Ddim, Ddim);
        k_ln_res<<<MROWS, 256, 0, stream>>>(x, pr, ln1g + l * Ddim, ln1b + l * Ddim, xb);
        k_gemm_bf16<1,1><<<gFF, 256, 0, stream>>>(xb, W1t, b1 + l * FFdim, hh, MROWS, FFdim, Ddim);
        k_gemm_bf16<0,0><<<g768, 256, 0, stream>>>(hh, W2t, b2 + l * Ddim, pr, MROWS, Ddim, FFdim);
        k_ln_res<<<MROWS, 256, 0, stream>>>(x, pr, ln2g + l * Ddim, ln2b + l * Ddim, xb);
    }
    k_head<<<Bdim * (NSEPd - 2), 128, 0, stream>>>(x, glob, Wh, bh, Wout, bout, out);
}

// Round 4
// 595.173 us; speedup vs baseline: 5.7630x; 1.2829x over previous
//
#include <hip/hip_runtime.h>
#include <hip/hip_bf16.h>
#include <math.h>

#define Sdim 2048
#define Bdim 2
#define Ddim 768
#define Hdim 12
#define DHdim 64
#define Ldim 2
#define Cdim 128
#define NCdim 16
#define FFdim 3072
#define Gdim 17
#define NSEPd 16
#define HIDd 100
#define NCLSd 7
#define SEPID 2
#define MROWS (Bdim*Sdim)
#define QKVS 2304

typedef __bf16 bf16_t;
typedef bf16_t bf16x8 __attribute__((ext_vector_type(8)));
typedef float f32x4 __attribute__((ext_vector_type(4)));
typedef ushort ushort8v __attribute__((ext_vector_type(8)));

__device__ __forceinline__ ushort f2bf(float f) {
    union { float f; unsigned u; } a; a.f = f;
    unsigned u = a.u;
    unsigned r = (u + 0x7fffu + ((u >> 16) & 1u)) >> 16;
    return (ushort)r;
}
__device__ __forceinline__ float bf2f(ushort h) {
    union { unsigned u; float f; } a; a.u = ((unsigned)h) << 16;
    return a.f;
}
__device__ __forceinline__ void gload16(const ushort* g, ushort* l) {
    __builtin_amdgcn_global_load_lds(
        (const __attribute__((address_space(1))) void*)g,
        (__attribute__((address_space(3))) void*)l, 16, 0, 0);
}

// ---------------- sep finding (ballot + prefix popcount) ----------------
__global__ __launch_bounds__(1024) void k_findsep(const int* __restrict__ ids,
        int* __restrict__ glob, int* __restrict__ isg) {
    __shared__ unsigned long long mw[32];
    __shared__ int pfx[32];
    int t = threadIdx.x;
    int flg[2];
    #pragma unroll
    for (int pass = 0; pass < 2; ++pass) {
        int p = pass * 1024 + t;
        int f = (ids[p] == SEPID);
        flg[pass] = f;
        unsigned long long m = __ballot(f);
        if ((t & 63) == 0) mw[pass * 16 + (t >> 6)] = m;
    }
    __syncthreads();
    if (t == 0) {
        int c = 0;
        #pragma unroll
        for (int i = 0; i < 32; ++i) { pfx[i] = c; c += __popcll(mw[i]); }
        glob[0] = 0;
    }
    __syncthreads();
    #pragma unroll
    for (int pass = 0; pass < 2; ++pass) {
        int p = pass * 1024 + t;
        int w = pass * 16 + (t >> 6);
        int lane = t & 63;
        int rank = pfx[w] + __popcll(mw[w] & ((1ull << lane) - 1ull));
        int ig = 0;
        if (flg[pass] && rank < NSEPd) { glob[rank + 1] = p; ig = 1; }
        if (p == 0) ig = 1;
        isg[p] = ig;
    }
}

// ---------------- ALL weight transposes in ONE kernel ----------------
// 64x64 tiles, f32 [K][N] -> bf16 [N][K]
__global__ __launch_bounds__(256) void k_w2bt_all(
        const float* __restrict__ Wq, const float* __restrict__ Wk,
        const float* __restrict__ Wv, const float* __restrict__ Wo,
        const float* __restrict__ W1, const float* __restrict__ W2,
        ushort* __restrict__ wts) {
    const size_t WSMALL = (size_t)Ddim * Ddim;
    const size_t WBIG   = (size_t)Ddim * FFdim;
    const size_t WL     = 4 * WSMALL + 2 * WBIG;
    int bid = blockIdx.x;
    int l = bid / 1728, r = bid % 1728;
    const float* src; ushort* dst; int K, N, tile;
    ushort* base = wts + (size_t)l * WL;
    if (r < 576) {
        int w = r / 144; tile = r % 144; K = Ddim; N = Ddim;
        src = (w == 0 ? Wq : w == 1 ? Wk : w == 2 ? Wv : Wo) + (size_t)l * WSMALL;
        dst = base + (size_t)w * WSMALL;
    } else if (r < 1152) {
        tile = r - 576; K = Ddim; N = FFdim;
        src = W1 + (size_t)l * WBIG; dst = base + 4 * WSMALL;
    } else {
        tile = r - 1152; K = FFdim; N = Ddim;
        src = W2 + (size_t)l * WBIG; dst = base + 4 * WSMALL + WBIG;
    }
    int ntn = N / 64;
    int bn = (tile % ntn) * 64, bk = (tile / ntn) * 64;

    __shared__ float ts[64][65];
    int t = threadIdx.x;
    int rx = t & 63, ry = t >> 6;
    #pragma unroll
    for (int i = 0; i < 16; ++i) {
        int row = ry * 16 + i;
        ts[row][rx] = src[(size_t)(bk + row) * N + bn + rx];
    }
    __syncthreads();
    int wr = t >> 4;          // 0..15
    int k0 = (t & 15) * 4;
    #pragma unroll
    for (int pass = 0; pass < 4; ++pass) {
        int row = pass * 16 + wr;
        ushort4 val;
        val.x = f2bf(ts[k0 + 0][row]);
        val.y = f2bf(ts[k0 + 1][row]);
        val.z = f2bf(ts[k0 + 2][row]);
        val.w = f2bf(ts[k0 + 3][row]);
        *(ushort4*)(&dst[(size_t)(bn + row) * K + bk + k0]) = val;
    }
}

// ---------------- concat q/k/v biases -> [L][2304] ----------------
__global__ void k_biascat(const float* __restrict__ bq, const float* __restrict__ bk,
                          const float* __restrict__ bv, float* __restrict__ bqkv) {
    int l = blockIdx.x, t = threadIdx.x;
    for (int i = t; i < QKVS; i += 256) {
        float v = (i < Ddim) ? bq[l * Ddim + i]
                : (i < 2 * Ddim) ? bk[l * Ddim + i - Ddim]
                : bv[l * Ddim + i - 2 * Ddim];
        bqkv[l * QKVS + i] = v;
    }
}

// ---------------- embedding + LN (1 wave/row, float4) ----------------
__global__ __launch_bounds__(64) void k_embed(const int* __restrict__ ids,
        const float* __restrict__ tok, const float* __restrict__ pos,
        const float* __restrict__ g, const float* __restrict__ b,
        float* __restrict__ x, ushort* __restrict__ xb) {
    int row = blockIdx.x;
    int s = row & (Sdim - 1);
    long id = ids[row];
    const float4* te = (const float4*)(tok + id * (long)Ddim);
    const float4* pe = (const float4*)(pos + (long)s * Ddim);
    int t = threadIdx.x;
    float4 v[3];
    float ls = 0.f, lq = 0.f;
    #pragma unroll
    for (int i = 0; i < 3; ++i) {
        float4 a = te[i * 64 + t], p = pe[i * 64 + t];
        v[i].x = a.x + p.x; v[i].y = a.y + p.y; v[i].z = a.z + p.z; v[i].w = a.w + p.w;
        ls += v[i].x + v[i].y + v[i].z + v[i].w;
        lq += v[i].x * v[i].x + v[i].y * v[i].y + v[i].z * v[i].z + v[i].w * v[i].w;
    }
    #pragma unroll
    for (int o = 32; o; o >>= 1) { ls += __shfl_xor(ls, o, 64); lq += __shfl_xor(lq, o, 64); }
    float mu = ls / Ddim;
    float var = lq / Ddim - mu * mu;
    float rs = rsqrtf(var + 1e-5f);
    const float4* g4 = (const float4*)g;
    const float4* b4 = (const float4*)b;
    float4* xr = (float4*)(x + (long)row * Ddim);
    ushort4* xbr = (ushort4*)(xb + (long)row * Ddim);
    #pragma unroll
    for (int i = 0; i < 3; ++i) {
        float4 gg = g4[i * 64 + t], bb = b4[i * 64 + t];
        float4 o;
        o.x = (v[i].x - mu) * rs * gg.x + bb.x;
        o.y = (v[i].y - mu) * rs * gg.y + bb.y;
        o.z = (v[i].z - mu) * rs * gg.z + bb.z;
        o.w = (v[i].w - mu) * rs * gg.w + bb.w;
        xr[i * 64 + t] = o;
        ushort4 ob; ob.x = f2bf(o.x); ob.y = f2bf(o.y); ob.z = f2bf(o.z); ob.w = f2bf(o.w);
        xbr[i * 64 + t] = ob;
    }
}

// ---------------- residual add + LN (1 wave/row, float4) ----------------
__global__ __launch_bounds__(64) void k_ln_res(float* __restrict__ x,
        const float* __restrict__ a, const float* __restrict__ g,
        const float* __restrict__ b, ushort* __restrict__ xb) {
    long row = blockIdx.x;
    int t = threadIdx.x;
    const float4* xr = (const float4*)(x + row * Ddim);
    const float4* ar = (const float4*)(a + row * Ddim);
    float4 v[3];
    float ls = 0.f, lq = 0.f;
    #pragma unroll
    for (int i = 0; i < 3; ++i) {
        float4 xa = xr[i * 64 + t], aa = ar[i * 64 + t];
        v[i].x = xa.x + aa.x; v[i].y = xa.y + aa.y; v[i].z = xa.z + aa.z; v[i].w = xa.w + aa.w;
        ls += v[i].x + v[i].y + v[i].z + v[i].w;
        lq += v[i].x * v[i].x + v[i].y * v[i].y + v[i].z * v[i].z + v[i].w * v[i].w;
    }
    #pragma unroll
    for (int o = 32; o; o >>= 1) { ls += __shfl_xor(ls, o, 64); lq += __shfl_xor(lq, o, 64); }
    float mu = ls / Ddim;
    float var = lq / Ddim - mu * mu;
    float rs = rsqrtf(var + 1e-5f);
    const float4* g4 = (const float4*)g;
    const float4* b4 = (const float4*)b;
    float4* xw = (float4*)(x + row * Ddim);
    ushort4* xbr = (ushort4*)(xb + row * Ddim);
    #pragma unroll
    for (int i = 0; i < 3; ++i) {
        float4 gg = g4[i * 64 + t], bb = b4[i * 64 + t];
        float4 o;
        o.x = (v[i].x - mu) * rs * gg.x + bb.x;
        o.y = (v[i].y - mu) * rs * gg.y + bb.y;
        o.z = (v[i].z - mu) * rs * gg.z + bb.z;
        o.w = (v[i].w - mu) * rs * gg.w + bb.w;
        xw[i * 64 + t] = o;
        ushort4 ob; ob.x = f2bf(o.x); ob.y = f2bf(o.y); ob.z = f2bf(o.z); ob.w = f2bf(o.w);
        xbr[i * 64 + t] = ob;
    }
}

// ---------------- bf16 MFMA GEMM (m97 structure): C = A[MxK] @ Wt[NxK]^T + bias ----------------
template<int ACT, int OUTBF16>
__global__ __launch_bounds__(256) void k_gemm_bf16(
        const ushort* __restrict__ A, const ushort* __restrict__ Wt,
        const float* __restrict__ bias, void* __restrict__ Cout,
        int M, int N, int K)
{
    __shared__ ushort As[128 * 32];
    __shared__ ushort Bs[128 * 32];
    const int t = threadIdx.x;
    const int bm = blockIdx.y * 128;
    const int bn = blockIdx.x * 128;
    const int lane = t & 63;
    const int wv = t >> 6;
    const int wm = (wv >> 1) * 64;
    const int wn = (wv & 1) * 64;

    const int srow = t >> 2;
    const int scol = (t & 3) * 8;
    const ushort* gA0 = A + (size_t)(bm + srow) * K + scol;
    const ushort* gA1 = A + (size_t)(bm + 64 + srow) * K + scol;
    const ushort* gB0 = Wt + (size_t)(bn + srow) * K + scol;
    const ushort* gB1 = Wt + (size_t)(bn + 64 + srow) * K + scol;
    ushort* lA0 = As + t * 8;
    ushort* lA1 = As + 2048 + t * 8;
    ushort* lB0 = Bs + t * 8;
    ushort* lB1 = Bs + 2048 + t * 8;

    f32x4 acc[4][4] = {};

    const int frow = lane & 15;
    const int koff = (lane >> 4) * 8;

    for (int k0 = 0; k0 < K; k0 += 32) {
        gload16(gA0 + k0, lA0);
        gload16(gA1 + k0, lA1);
        gload16(gB0 + k0, lB0);
        gload16(gB1 + k0, lB1);
        __syncthreads();
        bf16x8 af[4], bfv[4];
        #pragma unroll
        for (int mi = 0; mi < 4; ++mi)
            af[mi] = *reinterpret_cast<const bf16x8*>(As + (wm + mi * 16 + frow) * 32 + koff);
        #pragma unroll
        for (int ni = 0; ni < 4; ++ni)
            bfv[ni] = *reinterpret_cast<const bf16x8*>(Bs + (wn + ni * 16 + frow) * 32 + koff);
        #pragma unroll
        for (int mi = 0; mi < 4; ++mi)
            #pragma unroll
            for (int ni = 0; ni < 4; ++ni)
                acc[mi][ni] = __builtin_amdgcn_mfma_f32_16x16x32_bf16(af[mi], bfv[ni], acc[mi][ni], 0, 0, 0);
        __syncthreads();
    }
    const int crow0 = (lane >> 4) * 4;
    const int ccol = lane & 15;
    #pragma unroll
    for (int mi = 0; mi < 4; ++mi) {
        #pragma unroll
        for (int ni = 0; ni < 4; ++ni) {
            int gc = bn + wn + ni * 16 + ccol;
            float bv = bias[gc];
            #pragma unroll
            for (int j = 0; j < 4; ++j) {
                int gr = bm + wm + mi * 16 + crow0 + j;
                float v = acc[mi][ni][j] + bv;
                if (ACT == 1) {
                    float y = 0.7978845608f * (v + 0.044715f * v * v * v);
                    float e = __expf(2.f * y);
                    v = v * (1.f - 1.f / (e + 1.f));
                }
                if (OUTBF16) ((ushort*)Cout)[(size_t)gr * N + gc] = f2bf(v);
                else         ((float*)Cout)[(size_t)gr * N + gc] = v;
            }
        }
    }
}

// ---------------- MFMA flash local attention ----------------
__global__ __launch_bounds__(256) void k_attn_mfma(
        const ushort* __restrict__ qkv, const int* __restrict__ isg,
        const int* __restrict__ glob, const int* __restrict__ amask,
        ushort* __restrict__ ao)
{
    const int n = blockIdx.x, h = blockIdx.y, b = blockIdx.z;
    const int t = threadIdx.x;
    const int lane = t & 63, wv = t >> 6;
    const int R0 = b * Sdim;
    const int l15 = lane & 15, l4 = lane >> 4;

    __shared__ ushort Kb[32 * 64];        // swizzled [key][64]
    __shared__ ushort Vt[64 * 40];        // [d][key] pad 40
    __shared__ ushort Plds[4][32 * 40];   // per-wave P, pad 40
    __shared__ float  maskLDS[416];

    for (int i = t; i < 416; i += 256) {
        int ok;
        if (i < 384) {
            int pos = n * Cdim + i - Cdim;
            ok = (pos >= 0 && pos < Sdim);
            if (ok) ok = (amask[b * Sdim + pos] != 0) && (isg[pos] == 0);
        } else {
            int g = i - 384;
            ok = (g < Gdim) && (amask[b * Sdim + glob[g]] != 0);
        }
        maskLDS[i] = ok ? 0.f : -1e9f;
    }

    bf16x8 qf[2][2];
    #pragma unroll
    for (int qi = 0; qi < 2; ++qi)
        #pragma unroll
        for (int kh = 0; kh < 2; ++kh)
            qf[qi][kh] = *reinterpret_cast<const bf16x8*>(
                qkv + (size_t)(R0 + n * Cdim + wv * 32 + qi * 16 + l15) * QKVS
                    + h * DHdim + kh * 32 + l4 * 8);

    f32x4 accO[2][4] = {};
    float mrow[2][4], lrow[2][4];
    #pragma unroll
    for (int qi = 0; qi < 2; ++qi)
        #pragma unroll
        for (int j = 0; j < 4; ++j) { mrow[qi][j] = -1e30f; lrow[qi][j] = 0.f; }

    const int jj = t >> 3, c16 = t & 7;
    auto ldkv = [&](int kt, ushort8v& kr, ushort8v& vr) {
        int j = kt * 32 + jj;
        int pos = 0; bool ok;
        if (j < 384) { pos = n * Cdim + j - Cdim; ok = (pos >= 0 && pos < Sdim); }
        else { int g = j - 384; ok = (g < Gdim); if (ok) pos = glob[g]; }
        ushort8v z = {};
        if (ok) {
            const ushort* kp = qkv + (size_t)(R0 + pos) * QKVS + Ddim + h * DHdim + c16 * 8;
            kr = *reinterpret_cast<const ushort8v*>(kp);
            vr = *reinterpret_cast<const ushort8v*>(kp + Ddim);
        } else { kr = z; vr = z; }
    };

    ushort8v kreg, vreg, kreg2, vreg2;
    ldkv(0, kreg, vreg);

    for (int kt = 0; kt < 13; ++kt) {
        __syncthreads();
        *reinterpret_cast<ushort8v*>(&Kb[jj * 64 + ((c16 ^ (jj & 7)) * 8)]) = kreg;
        #pragma unroll
        for (int e = 0; e < 8; ++e) Vt[(c16 * 8 + e) * 40 + jj] = vreg[e];
        if (kt < 12) ldkv(kt + 1, kreg2, vreg2);
        __syncthreads();

        bf16x8 kf[2][2];
        #pragma unroll
        for (int kj = 0; kj < 2; ++kj) {
            int key = kj * 16 + l15;
            #pragma unroll
            for (int kh = 0; kh < 2; ++kh) {
                int cc = (kh * 4 + l4) ^ (key & 7);
                kf[kj][kh] = *reinterpret_cast<const bf16x8*>(&Kb[key * 64 + cc * 8]);
            }
        }
        float ma[2];
        ma[0] = maskLDS[kt * 32 + l15];
        ma[1] = maskLDS[kt * 32 + 16 + l15];

        #pragma unroll
        for (int qi = 0; qi < 2; ++qi) {
            f32x4 s0 = {}, s1 = {};
            #pragma unroll
            for (int kh = 0; kh < 2; ++kh) {
                s0 = __builtin_amdgcn_mfma_f32_16x16x32_bf16(qf[qi][kh], kf[0][kh], s0, 0, 0, 0);
                s1 = __builtin_amdgcn_mfma_f32_16x16x32_bf16(qf[qi][kh], kf[1][kh], s1, 0, 0, 0);
            }
            float sf[2][4];
            #pragma unroll
            for (int kj = 0; kj < 2; ++kj) {
                int key = kt * 32 + kj * 16 + l15;
                #pragma unroll
                for (int j = 0; j < 4; ++j) {
                    int cq = wv * 32 + qi * 16 + l4 * 4 + j;
                    float s = (kj ? s1[j] : s0[j]) * 0.125f + ma[kj];
                    bool band = (key >= 384) || ((unsigned)(key - cq) <= 256u);
                    sf[kj][j] = band ? s : s - 1e9f;
                }
            }
            float mnew[4], corr[4];
            #pragma unroll
            for (int j = 0; j < 4; ++j) {
                float v = fmaxf(sf[0][j], sf[1][j]);
                v = fmaxf(v, __shfl_xor(v, 1, 64));
                v = fmaxf(v, __shfl_xor(v, 2, 64));
                v = fmaxf(v, __shfl_xor(v, 4, 64));
                v = fmaxf(v, __shfl_xor(v, 8, 64));
                mnew[j] = fmaxf(mrow[qi][j], v);
                corr[j] = __expf(mrow[qi][j] - mnew[j]);
                mrow[qi][j] = mnew[j];
            }
            float ps[2][4];
            #pragma unroll
            for (int kj = 0; kj < 2; ++kj)
                #pragma unroll
                for (int j = 0; j < 4; ++j)
                    ps[kj][j] = __expf(sf[kj][j] - mnew[j]);
            #pragma unroll
            for (int j = 0; j < 4; ++j) {
                float r = ps[0][j] + ps[1][j];
                r += __shfl_xor(r, 1, 64);
                r += __shfl_xor(r, 2, 64);
                r += __shfl_xor(r, 4, 64);
                r += __shfl_xor(r, 8, 64);
                lrow[qi][j] = lrow[qi][j] * corr[j] + r;
            }
            #pragma unroll
            for (int dt = 0; dt < 4; ++dt)
                #pragma unroll
                for (int j = 0; j < 4; ++j)
                    accO[qi][dt][j] *= corr[j];
            #pragma unroll
            for (int kj = 0; kj < 2; ++kj)
                #pragma unroll
                for (int j = 0; j < 4; ++j)
                    Plds[wv][(qi * 16 + l4 * 4 + j) * 40 + kj * 16 + l15] = f2bf(ps[kj][j]);
        }
        #pragma unroll
        for (int qi = 0; qi < 2; ++qi) {
            bf16x8 af = *reinterpret_cast<const bf16x8*>(&Plds[wv][(qi * 16 + l15) * 40 + l4 * 8]);
            #pragma unroll
            for (int dt = 0; dt < 4; ++dt) {
                bf16x8 vf = *reinterpret_cast<const bf16x8*>(&Vt[(dt * 16 + l15) * 40 + l4 * 8]);
                accO[qi][dt] = __builtin_amdgcn_mfma_f32_16x16x32_bf16(af, vf, accO[qi][dt], 0, 0, 0);
            }
        }
        kreg = kreg2; vreg = vreg2;
    }

    #pragma unroll
    for (int qi = 0; qi < 2; ++qi) {
        float inv[4];
        #pragma unroll
        for (int j = 0; j < 4; ++j) inv[j] = 1.f / lrow[qi][j];
        #pragma unroll
        for (int dt = 0; dt < 4; ++dt) {
            #pragma unroll
            for (int j = 0; j < 4; ++j) {
                int crow = n * Cdim + wv * 32 + qi * 16 + l4 * 4 + j;
                ao[(size_t)(R0 + crow) * Ddim + h * DHdim + dt * 16 + l15] =
                    f2bf(accO[qi][dt][j] * inv[j]);
            }
        }
    }
}

// ---------------- global token rows attend to all S keys ----------------
__global__ __launch_bounds__(256) void k_attn_glob(const ushort* __restrict__ qkv,
        const int* __restrict__ glob, const int* __restrict__ amask,
        ushort* __restrict__ ao) {
    int g = blockIdx.x, h = blockIdx.y, b = blockIdx.z;
    __shared__ float sc[Sdim];
    __shared__ float qs[DHdim];
    __shared__ float redm[4], reds[4];
    __shared__ float part[32][DHdim];
    int t = threadIdx.x;
    int qr = glob[g];
    const int R0 = b * Sdim;
    if (t < DHdim)
        qs[t] = bf2f(qkv[(size_t)(R0 + qr) * QKVS + h * DHdim + t]) * 0.125f;
    __syncthreads();
    float lm = -1e30f;
    for (int s0 = t; s0 < Sdim; s0 += 256) {
        const ushort8v* kr = (const ushort8v*)(qkv + (size_t)(R0 + s0) * QKVS + Ddim + h * DHdim);
        float s = 0.f;
        #pragma unroll
        for (int cc = 0; cc < 8; ++cc) {
            ushort8v kv = kr[cc];
            #pragma unroll
            for (int e = 0; e < 8; ++e) s += qs[cc * 8 + e] * bf2f(kv[e]);
        }
        if (amask[b * Sdim + s0] == 0) s = -1e30f;
        sc[s0] = s;
        lm = fmaxf(lm, s);
    }
    #pragma unroll
    for (int o = 32; o; o >>= 1) lm = fmaxf(lm, __shfl_xor(lm, o, 64));
    if ((t & 63) == 0) redm[t >> 6] = lm;
    __syncthreads();
    float mx = fmaxf(fmaxf(redm[0], redm[1]), fmaxf(redm[2], redm[3]));
    float lsum = 0.f;
    for (int s0 = t; s0 < Sdim; s0 += 256) {
        float p = __expf(sc[s0] - mx);
        sc[s0] = p; lsum += p;
    }
    #pragma unroll
    for (int o = 32; o; o >>= 1) lsum += __shfl_xor(lsum, o, 64);
    if ((t & 63) == 0) reds[t >> 6] = lsum;
    __syncthreads();
    float l = reds[0] + reds[1] + reds[2] + reds[3];
    int chunk = t >> 3, dg = t & 7;
    float a[8] = {};
    for (int r = chunk * 64; r < chunk * 64 + 64; ++r) {
        float p = sc[r];
        ushort8v vv = *(const ushort8v*)(qkv + (size_t)(R0 + r) * QKVS + 2 * Ddim + h * DHdim + dg * 8);
        #pragma unroll
        for (int e = 0; e < 8; ++e) a[e] += p * bf2f(vv[e]);
    }
    #pragma unroll
    for (int e = 0; e < 8; ++e) part[chunk][dg * 8 + e] = a[e];
    __syncthreads();
    if (t < DHdim) {
        float o = 0.f;
        #pragma unroll
        for (int c = 0; c < 32; ++c) o += part[c][t];
        ao[(size_t)(R0 + qr) * Ddim + h * DHdim + t] = f2bf(o / l);
    }
}

// ---------------- classification head ----------------
__global__ __launch_bounds__(128) void k_head(const float* __restrict__ x,
        const int* __restrict__ glob, const float* __restrict__ Wh,
        const float* __restrict__ bh, const float* __restrict__ Wout,
        const float* __restrict__ bout, float* __restrict__ out) {
    int i = blockIdx.x;
    int b = i / 14, j = i % 14;
    __shared__ float emb[2 * Ddim];
    __shared__ float hid[HIDd];
    int t = threadIdx.x;
    int p = glob[j + 2];
    for (int d = t; d < Ddim; d += 128) {
        emb[d] = x[(long)b * Sdim * Ddim + d];
        emb[Ddim + d] = x[((long)b * Sdim + p) * Ddim + d];
    }
    __syncthreads();
    if (t < HIDd) {
        float s = bh[t];
        for (int k1 = 0; k1 < 2 * Ddim; ++k1) s += emb[k1] * Wh[k1 * HIDd + t];
        hid[t] = fmaxf(s, 0.f);
    }
    __syncthreads();
    if (t < NCLSd) {
        float s = bout[t];
        for (int o = 0; o < HIDd; ++o) s += hid[o] * Wout[o * NCLSd + t];
        out[i * NCLSd + t] = s;
    }
}

extern "C" void kernel_launch(void* const* d_in, const int* in_sizes, int n_in,
                              void* d_out, int out_size, void* d_ws, size_t ws_size,
                              hipStream_t stream) {
    const int*   ids   = (const int*)d_in[0];
    const int*   am    = (const int*)d_in[1];
    const float* tok   = (const float*)d_in[2];
    const float* pos   = (const float*)d_in[3];
    const float* lneg  = (const float*)d_in[4];
    const float* lneb  = (const float*)d_in[5];
    const float* Wq    = (const float*)d_in[6];
    const float* bq    = (const float*)d_in[7];
    const float* Wk    = (const float*)d_in[8];
    const float* bk    = (const float*)d_in[9];
    const float* Wv    = (const float*)d_in[10];
    const float* bv    = (const float*)d_in[11];
    const float* Wo    = (const float*)d_in[12];
    const float* bo    = (const float*)d_in[13];
    const float* ln1g  = (const float*)d_in[14];
    const float* ln1b  = (const float*)d_in[15];
    const float* W1    = (const float*)d_in[16];
    const float* b1    = (const float*)d_in[17];
    const float* W2    = (const float*)d_in[18];
    const float* b2    = (const float*)d_in[19];
    const float* ln2g  = (const float*)d_in[20];
    const float* ln2b  = (const float*)d_in[21];
    const float* Wh    = (const float*)d_in[22];
    const float* bh    = (const float*)d_in[23];
    const float* Wout  = (const float*)d_in[24];
    const float* bout  = (const float*)d_in[25];
    float* out = (float*)d_out;

    char* ws = (char*)d_ws;
    const size_t SZ = (size_t)MROWS * Ddim * sizeof(float);
    const size_t HB = SZ / 2;
    size_t off = 0;
    float*  x    = (float*)(ws + off);  off += SZ;
    float*  pr   = (float*)(ws + off);  off += SZ;
    ushort* xb   = (ushort*)(ws + off); off += HB;
    ushort* qkvB = (ushort*)(ws + off); off += (size_t)MROWS * QKVS * 2;
    ushort* aoB  = (ushort*)(ws + off); off += HB;
    ushort* hh   = (ushort*)(ws + off); off += (size_t)MROWS * FFdim * 2;
    const size_t WSMALL = (size_t)Ddim * Ddim;
    const size_t WBIG   = (size_t)Ddim * FFdim;
    const size_t WL     = 4 * WSMALL + 2 * WBIG;
    ushort* wts = (ushort*)(ws + off); off += WL * Ldim * 2;
    float* bqkv = (float*)(ws + off);  off += Ldim * QKVS * sizeof(float);
    int* glob = (int*)(ws + off); off += 256;
    int* isg  = (int*)(ws + off);

    k_findsep<<<1, 1024, 0, stream>>>(ids, glob, isg);
    k_biascat<<<Ldim, 256, 0, stream>>>(bq, bk, bv, bqkv);
    k_w2bt_all<<<3456, 256, 0, stream>>>(Wq, Wk, Wv, Wo, W1, W2, wts);
    k_embed<<<MROWS, 64, 0, stream>>>(ids, tok, pos, lneg, lneb, x, xb);

    dim3 g768(Ddim / 128, MROWS / 128);
    dim3 gQKV(QKVS / 128, MROWS / 128);
    dim3 gFF(FFdim / 128, MROWS / 128);
    dim3 gloc(NCdim, Hdim, Bdim);
    dim3 gglb(Gdim, Hdim, Bdim);

    for (int l = 0; l < Ldim; ++l) {
        ushort* base = wts + l * WL;
        ushort* Wqkvt = base;
        ushort* Wot = base + 3 * WSMALL;
        ushort* W1t = base + 4 * WSMALL;
        ushort* W2t = base + 4 * WSMALL + WBIG;
        k_gemm_bf16<0,1><<<gQKV, 256, 0, stream>>>(xb, Wqkvt, bqkv + l * QKVS, qkvB, MROWS, QKVS, Ddim);
        k_attn_mfma<<<gloc, 256, 0, stream>>>(qkvB, isg, glob, am, aoB);
        k_attn_glob<<<gglb, 256, 0, stream>>>(qkvB, glob, am, aoB);
        k_gemm_bf16<0,0><<<g768, 256, 0, stream>>>(aoB, Wot, bo + l * Ddim, pr, MROWS, Ddim, Ddim);
        k_ln_res<<<MROWS, 64, 0, stream>>>(x, pr, ln1g + l * Ddim, ln1b + l * Ddim, xb);
        k_gemm_bf16<1,1><<<gFF, 256, 0, stream>>>(xb, W1t, b1 + l * FFdim, hh, MROWS, FFdim, Ddim);
        k_gemm_bf16<0,0><<<g768, 256, 0, stream>>>(hh, W2t, b2 + l * Ddim, pr, MROWS, Ddim, FFdim);
        k_ln_res<<<MROWS, 64, 0, stream>>>(x, pr, ln2g + l * Ddim, ln2b + l * Ddim, xb);
    }
    k_head<<<Bdim * (NSEPd - 2), 128, 0, stream>>>(x, glob, Wh, bh, Wout, bout, out);
}

// Round 6
// 546.049 us; speedup vs baseline: 6.2814x; 1.0900x over previous
//
#include <hip/hip_runtime.h>
#include <hip/hip_bf16.h>
#include <math.h>

#define Sdim 2048
#define Bdim 2
#define Ddim 768
#define Hdim 12
#define DHdim 64
#define Ldim 2
#define Cdim 128
#define NCdim 16
#define FFdim 3072
#define Gdim 17
#define NSEPd 16
#define HIDd 100
#define NCLSd 7
#define SEPID 2
#define MROWS (Bdim*Sdim)
#define QKVS 2304

typedef __bf16 bf16_t;
typedef bf16_t bf16x8 __attribute__((ext_vector_type(8)));
typedef float f32x4 __attribute__((ext_vector_type(4)));
typedef ushort ushort8v __attribute__((ext_vector_type(8)));

__device__ __forceinline__ ushort f2bf(float f) {
    union { float f; unsigned u; } a; a.f = f;
    unsigned u = a.u;
    unsigned r = (u + 0x7fffu + ((u >> 16) & 1u)) >> 16;
    return (ushort)r;
}
__device__ __forceinline__ float bf2f(ushort h) {
    union { unsigned u; float f; } a; a.u = ((unsigned)h) << 16;
    return a.f;
}
__device__ __forceinline__ void gload16(const ushort* g, ushort* l) {
    __builtin_amdgcn_global_load_lds(
        (const __attribute__((address_space(1))) void*)g,
        (__attribute__((address_space(3))) void*)l, 16, 0, 0);
}

// ---------------- sep finding (ballot + prefix popcount) ----------------
__global__ __launch_bounds__(1024) void k_findsep(const int* __restrict__ ids,
        int* __restrict__ glob, int* __restrict__ isg) {
    __shared__ unsigned long long mw[32];
    __shared__ int pfx[32];
    int t = threadIdx.x;
    int flg[2];
    #pragma unroll
    for (int pass = 0; pass < 2; ++pass) {
        int p = pass * 1024 + t;
        int f = (ids[p] == SEPID);
        flg[pass] = f;
        unsigned long long m = __ballot(f);
        if ((t & 63) == 0) mw[pass * 16 + (t >> 6)] = m;
    }
    __syncthreads();
    if (t == 0) {
        int c = 0;
        #pragma unroll
        for (int i = 0; i < 32; ++i) { pfx[i] = c; c += __popcll(mw[i]); }
        glob[0] = 0;
    }
    __syncthreads();
    #pragma unroll
    for (int pass = 0; pass < 2; ++pass) {
        int p = pass * 1024 + t;
        int w = pass * 16 + (t >> 6);
        int lane = t & 63;
        int rank = pfx[w] + __popcll(mw[w] & ((1ull << lane) - 1ull));
        int ig = 0;
        if (flg[pass] && rank < NSEPd) { glob[rank + 1] = p; ig = 1; }
        if (p == 0) ig = 1;
        isg[p] = ig;
    }
}

// ---------------- ALL weight transposes in ONE kernel ----------------
__global__ __launch_bounds__(256) void k_w2bt_all(
        const float* __restrict__ Wq, const float* __restrict__ Wk,
        const float* __restrict__ Wv, const float* __restrict__ Wo,
        const float* __restrict__ W1, const float* __restrict__ W2,
        ushort* __restrict__ wts) {
    const size_t WSMALL = (size_t)Ddim * Ddim;
    const size_t WBIG   = (size_t)Ddim * FFdim;
    const size_t WL     = 4 * WSMALL + 2 * WBIG;
    int bid = blockIdx.x;
    int l = bid / 1728, r = bid % 1728;
    const float* src; ushort* dst; int K, N, tile;
    ushort* base = wts + (size_t)l * WL;
    if (r < 576) {
        int w = r / 144; tile = r % 144; K = Ddim; N = Ddim;
        src = (w == 0 ? Wq : w == 1 ? Wk : w == 2 ? Wv : Wo) + (size_t)l * WSMALL;
        dst = base + (size_t)w * WSMALL;
    } else if (r < 1152) {
        tile = r - 576; K = Ddim; N = FFdim;
        src = W1 + (size_t)l * WBIG; dst = base + 4 * WSMALL;
    } else {
        tile = r - 1152; K = FFdim; N = Ddim;
        src = W2 + (size_t)l * WBIG; dst = base + 4 * WSMALL + WBIG;
    }
    int ntn = N / 64;
    int bn = (tile % ntn) * 64, bk = (tile / ntn) * 64;

    __shared__ float ts[64][65];
    int t = threadIdx.x;
    int rx = t & 63, ry = t >> 6;
    #pragma unroll
    for (int i = 0; i < 16; ++i) {
        int row = ry * 16 + i;
        ts[row][rx] = src[(size_t)(bk + row) * N + bn + rx];
    }
    __syncthreads();
    int wr = t >> 4;
    int k0 = (t & 15) * 4;
    #pragma unroll
    for (int pass = 0; pass < 4; ++pass) {
        int row = pass * 16 + wr;
        ushort4 val;
        val.x = f2bf(ts[k0 + 0][row]);
        val.y = f2bf(ts[k0 + 1][row]);
        val.z = f2bf(ts[k0 + 2][row]);
        val.w = f2bf(ts[k0 + 3][row]);
        *(ushort4*)(&dst[(size_t)(bn + row) * K + bk + k0]) = val;
    }
}

// ---------------- concat q/k/v biases -> [L][2304] ----------------
__global__ void k_biascat(const float* __restrict__ bq, const float* __restrict__ bk,
                          const float* __restrict__ bv, float* __restrict__ bqkv) {
    int l = blockIdx.x, t = threadIdx.x;
    for (int i = t; i < QKVS; i += 256) {
        float v = (i < Ddim) ? bq[l * Ddim + i]
                : (i < 2 * Ddim) ? bk[l * Ddim + i - Ddim]
                : bv[l * Ddim + i - 2 * Ddim];
        bqkv[l * QKVS + i] = v;
    }
}

// ---------------- embedding + LN (1 wave/row, float4) ----------------
__global__ __launch_bounds__(64) void k_embed(const int* __restrict__ ids,
        const float* __restrict__ tok, const float* __restrict__ pos,
        const float* __restrict__ g, const float* __restrict__ b,
        float* __restrict__ x, ushort* __restrict__ xb) {
    int row = blockIdx.x;
    int s = row & (Sdim - 1);
    long id = ids[row];
    const float4* te = (const float4*)(tok + id * (long)Ddim);
    const float4* pe = (const float4*)(pos + (long)s * Ddim);
    int t = threadIdx.x;
    float4 v[3];
    float ls = 0.f, lq = 0.f;
    #pragma unroll
    for (int i = 0; i < 3; ++i) {
        float4 a = te[i * 64 + t], p = pe[i * 64 + t];
        v[i].x = a.x + p.x; v[i].y = a.y + p.y; v[i].z = a.z + p.z; v[i].w = a.w + p.w;
        ls += v[i].x + v[i].y + v[i].z + v[i].w;
        lq += v[i].x * v[i].x + v[i].y * v[i].y + v[i].z * v[i].z + v[i].w * v[i].w;
    }
    #pragma unroll
    for (int o = 32; o; o >>= 1) { ls += __shfl_xor(ls, o, 64); lq += __shfl_xor(lq, o, 64); }
    float mu = ls / Ddim;
    float var = lq / Ddim - mu * mu;
    float rs = rsqrtf(var + 1e-5f);
    const float4* g4 = (const float4*)g;
    const float4* b4 = (const float4*)b;
    float4* xr = (float4*)(x + (long)row * Ddim);
    ushort4* xbr = (ushort4*)(xb + (long)row * Ddim);
    #pragma unroll
    for (int i = 0; i < 3; ++i) {
        float4 gg = g4[i * 64 + t], bb = b4[i * 64 + t];
        float4 o;
        o.x = (v[i].x - mu) * rs * gg.x + bb.x;
        o.y = (v[i].y - mu) * rs * gg.y + bb.y;
        o.z = (v[i].z - mu) * rs * gg.z + bb.z;
        o.w = (v[i].w - mu) * rs * gg.w + bb.w;
        xr[i * 64 + t] = o;
        ushort4 ob; ob.x = f2bf(o.x); ob.y = f2bf(o.y); ob.z = f2bf(o.z); ob.w = f2bf(o.w);
        xbr[i * 64 + t] = ob;
    }
}

// ---------------- residual add + LN (1 wave/row, float4) ----------------
__global__ __launch_bounds__(64) void k_ln_res(float* __restrict__ x,
        const float* __restrict__ a, const float* __restrict__ g,
        const float* __restrict__ b, ushort* __restrict__ xb) {
    long row = blockIdx.x;
    int t = threadIdx.x;
    const float4* xr = (const float4*)(x + row * Ddim);
    const float4* ar = (const float4*)(a + row * Ddim);
    float4 v[3];
    float ls = 0.f, lq = 0.f;
    #pragma unroll
    for (int i = 0; i < 3; ++i) {
        float4 xa = xr[i * 64 + t], aa = ar[i * 64 + t];
        v[i].x = xa.x + aa.x; v[i].y = xa.y + aa.y; v[i].z = xa.z + aa.z; v[i].w = xa.w + aa.w;
        ls += v[i].x + v[i].y + v[i].z + v[i].w;
        lq += v[i].x * v[i].x + v[i].y * v[i].y + v[i].z * v[i].z + v[i].w * v[i].w;
    }
    #pragma unroll
    for (int o = 32; o; o >>= 1) { ls += __shfl_xor(ls, o, 64); lq += __shfl_xor(lq, o, 64); }
    float mu = ls / Ddim;
    float var = lq / Ddim - mu * mu;
    float rs = rsqrtf(var + 1e-5f);
    const float4* g4 = (const float4*)g;
    const float4* b4 = (const float4*)b;
    float4* xw = (float4*)(x + row * Ddim);
    ushort4* xbr = (ushort4*)(xb + row * Ddim);
    #pragma unroll
    for (int i = 0; i < 3; ++i) {
        float4 gg = g4[i * 64 + t], bb = b4[i * 64 + t];
        float4 o;
        o.x = (v[i].x - mu) * rs * gg.x + bb.x;
        o.y = (v[i].y - mu) * rs * gg.y + bb.y;
        o.z = (v[i].z - mu) * rs * gg.z + bb.z;
        o.w = (v[i].w - mu) * rs * gg.w + bb.w;
        xw[i * 64 + t] = o;
        ushort4 ob; ob.x = f2bf(o.x); ob.y = f2bf(o.y); ob.z = f2bf(o.z); ob.w = f2bf(o.w);
        xbr[i * 64 + t] = ob;
    }
}

// ---------------- bf16 MFMA GEMM (m97 structure + XCD chunked swizzle) ----------------
template<int ACT, int OUTBF16>
__global__ __launch_bounds__(256) void k_gemm_bf16(
        const ushort* __restrict__ A, const ushort* __restrict__ Wt,
        const float* __restrict__ bias, void* __restrict__ Cout,
        int M, int N, int K)
{
    __shared__ ushort As[128 * 32];
    __shared__ ushort Bs[128 * 32];
    const int t = threadIdx.x;
    // bijective XCD-chunked swizzle (m204): consecutive tiles -> same XCD L2
    const int nwg = gridDim.x * gridDim.y;
    const int wgid = blockIdx.y * gridDim.x + blockIdx.x;
    const int q8 = nwg >> 3, r8 = nwg & 7;
    const int xcd = wgid & 7, idx = wgid >> 3;
    const int swz = (xcd < r8 ? xcd * (q8 + 1) : r8 * (q8 + 1) + (xcd - r8) * q8) + idx;
    const int bm = (swz / gridDim.x) * 128;
    const int bn = (swz % gridDim.x) * 128;
    const int lane = t & 63;
    const int wv = t >> 6;
    const int wm = (wv >> 1) * 64;
    const int wn = (wv & 1) * 64;

    const int srow = t >> 2;
    const int scol = (t & 3) * 8;
    const ushort* gA0 = A + (size_t)(bm + srow) * K + scol;
    const ushort* gA1 = A + (size_t)(bm + 64 + srow) * K + scol;
    const ushort* gB0 = Wt + (size_t)(bn + srow) * K + scol;
    const ushort* gB1 = Wt + (size_t)(bn + 64 + srow) * K + scol;
    ushort* lA0 = As + t * 8;
    ushort* lA1 = As + 2048 + t * 8;
    ushort* lB0 = Bs + t * 8;
    ushort* lB1 = Bs + 2048 + t * 8;

    f32x4 acc[4][4] = {};

    const int frow = lane & 15;
    const int koff = (lane >> 4) * 8;

    for (int k0 = 0; k0 < K; k0 += 32) {
        gload16(gA0 + k0, lA0);
        gload16(gA1 + k0, lA1);
        gload16(gB0 + k0, lB0);
        gload16(gB1 + k0, lB1);
        __syncthreads();
        bf16x8 af[4], bfv[4];
        #pragma unroll
        for (int mi = 0; mi < 4; ++mi)
            af[mi] = *reinterpret_cast<const bf16x8*>(As + (wm + mi * 16 + frow) * 32 + koff);
        #pragma unroll
        for (int ni = 0; ni < 4; ++ni)
            bfv[ni] = *reinterpret_cast<const bf16x8*>(Bs + (wn + ni * 16 + frow) * 32 + koff);
        #pragma unroll
        for (int mi = 0; mi < 4; ++mi)
            #pragma unroll
            for (int ni = 0; ni < 4; ++ni)
                acc[mi][ni] = __builtin_amdgcn_mfma_f32_16x16x32_bf16(af[mi], bfv[ni], acc[mi][ni], 0, 0, 0);
        __syncthreads();
    }
    const int crow0 = (lane >> 4) * 4;
    const int ccol = lane & 15;
    #pragma unroll
    for (int mi = 0; mi < 4; ++mi) {
        #pragma unroll
        for (int ni = 0; ni < 4; ++ni) {
            int gc = bn + wn + ni * 16 + ccol;
            float bv = bias[gc];
            #pragma unroll
            for (int j = 0; j < 4; ++j) {
                int gr = bm + wm + mi * 16 + crow0 + j;
                float v = acc[mi][ni][j] + bv;
                if (ACT == 1) {
                    float y = 0.7978845608f * (v + 0.044715f * v * v * v);
                    float e = __expf(2.f * y);
                    v = v * (1.f - 1.f / (e + 1.f));
                }
                if (OUTBF16) ((ushort*)Cout)[(size_t)gr * N + gc] = f2bf(v);
                else         ((float*)Cout)[(size_t)gr * N + gc] = v;
            }
        }
    }
}

// ---------------- MFMA flash local attention, 64-key tiles ----------------
// grid (NC, H, B), block 256 (4 waves); wave wv owns q rows wv*32..+31
// key slots: 0..383 banded local (pos = n*128 + j - 128), 384..447 = 17 globals + pad
__global__ __launch_bounds__(256) void k_attn_mfma(
        const ushort* __restrict__ qkv, const int* __restrict__ isg,
        const int* __restrict__ glob, const int* __restrict__ amask,
        ushort* __restrict__ ao)
{
    const int n = blockIdx.x, h = blockIdx.y, b = blockIdx.z;
    const int t = threadIdx.x;
    const int lane = t & 63, wv = t >> 6;
    const int R0 = b * Sdim;
    const int l15 = lane & 15, l4 = lane >> 4;

    __shared__ ushort Kb[64 * 64];        // swizzled [key][64]
    __shared__ ushort Vt[64 * 72];        // [d][key] pad 72
    __shared__ ushort Plds[4][32 * 72];   // per-wave P, pad 72
    __shared__ float  maskLDS[448];

    for (int i = t; i < 448; i += 256) {
        int ok;
        if (i < 384) {
            int pos = n * Cdim + i - Cdim;
            ok = (pos >= 0 && pos < Sdim);
            if (ok) ok = (amask[b * Sdim + pos] != 0) && (isg[pos] == 0);
        } else {
            int g = i - 384;
            int gp = (g < Gdim) ? glob[g] : 0;
            ok = (g < Gdim) && (amask[b * Sdim + gp] != 0);
        }
        maskLDS[i] = ok ? 0.f : -1e9f;
    }

    bf16x8 qf[2][2];
    #pragma unroll
    for (int qi = 0; qi < 2; ++qi)
        #pragma unroll
        for (int kh = 0; kh < 2; ++kh)
            qf[qi][kh] = *reinterpret_cast<const bf16x8*>(
                qkv + (size_t)(R0 + n * Cdim + wv * 32 + qi * 16 + l15) * QKVS
                    + h * DHdim + kh * 32 + l4 * 8);

    f32x4 accO[2][4] = {};
    float mrow[2][4], lrow[2][4];
    #pragma unroll
    for (int qi = 0; qi < 2; ++qi)
        #pragma unroll
        for (int j = 0; j < 4; ++j) { mrow[qi][j] = -1e30f; lrow[qi][j] = 0.f; }

    const int jj = t >> 3;   // 0..31
    const int c16 = t & 7;   // 0..7

    auto ldone = [&](int j, ushort8v& kr, ushort8v& vr) {
        int pos = 0; bool ok;
        if (j < 384) { pos = n * Cdim + j - Cdim; ok = (pos >= 0 && pos < Sdim); }
        else { int g = j - 384; ok = (g < Gdim); if (ok) pos = glob[g]; }
        ushort8v z = {};
        if (ok) {
            const ushort* kp = qkv + (size_t)(R0 + pos) * QKVS + Ddim + h * DHdim + c16 * 8;
            kr = *reinterpret_cast<const ushort8v*>(kp);
            vr = *reinterpret_cast<const ushort8v*>(kp + Ddim);
        } else { kr = z; vr = z; }
    };

    ushort8v kr0, kr1, vr0, vr1, nk0 = {}, nk1 = {}, nv0 = {}, nv1 = {};
    ldone(jj, kr0, vr0);
    ldone(jj + 32, kr1, vr1);

    for (int kt = 0; kt < 7; ++kt) {
        __syncthreads();
        *reinterpret_cast<ushort8v*>(&Kb[jj * 64 + ((c16 ^ (jj & 7)) * 8)]) = kr0;
        *reinterpret_cast<ushort8v*>(&Kb[(jj + 32) * 64 + ((c16 ^ (jj & 7)) * 8)]) = kr1;
        #pragma unroll
        for (int e = 0; e < 8; ++e) {
            Vt[(c16 * 8 + e) * 72 + jj] = vr0[e];
            Vt[(c16 * 8 + e) * 72 + 32 + jj] = vr1[e];
        }
        if (kt < 6) {
            int base_j = (kt + 1) * 64 + jj;
            ldone(base_j, nk0, nv0);
            ldone(base_j + 32, nk1, nv1);
        }
        __syncthreads();

        // per-wave dead-tile skip: wave's band union = [wv*32, wv*32+287]
        bool active = (kt == 6) || ((kt * 64 + 63 >= wv * 32) && (kt * 64 <= wv * 32 + 287));
        if (active) {
            bf16x8 kf[4][2];
            #pragma unroll
            for (int kj = 0; kj < 4; ++kj) {
                int key = kj * 16 + l15;
                #pragma unroll
                for (int kh = 0; kh < 2; ++kh) {
                    int cc = (kh * 4 + l4) ^ (key & 7);
                    kf[kj][kh] = *reinterpret_cast<const bf16x8*>(&Kb[key * 64 + cc * 8]);
                }
            }
            float ma[4];
            #pragma unroll
            for (int kj = 0; kj < 4; ++kj) ma[kj] = maskLDS[kt * 64 + kj * 16 + l15];

            #pragma unroll
            for (int qi = 0; qi < 2; ++qi) {
                f32x4 s[4] = {};
                #pragma unroll
                for (int kj = 0; kj < 4; ++kj)
                    #pragma unroll
                    for (int kh = 0; kh < 2; ++kh)
                        s[kj] = __builtin_amdgcn_mfma_f32_16x16x32_bf16(qf[qi][kh], kf[kj][kh], s[kj], 0, 0, 0);

                float sf[4][4];
                #pragma unroll
                for (int kj = 0; kj < 4; ++kj) {
                    int key = kt * 64 + kj * 16 + l15;
                    #pragma unroll
                    for (int j = 0; j < 4; ++j) {
                        int cq = wv * 32 + qi * 16 + l4 * 4 + j;
                        float sv = s[kj][j] * 0.125f + ma[kj];
                        bool band = (key >= 384) || ((unsigned)(key - cq) <= 256u);
                        sf[kj][j] = band ? sv : sv - 1e9f;
                    }
                }
                float mnew[4], corr[4];
                #pragma unroll
                for (int j = 0; j < 4; ++j) {
                    float v = fmaxf(fmaxf(sf[0][j], sf[1][j]), fmaxf(sf[2][j], sf[3][j]));
                    v = fmaxf(v, __shfl_xor(v, 1, 64));
                    v = fmaxf(v, __shfl_xor(v, 2, 64));
                    v = fmaxf(v, __shfl_xor(v, 4, 64));
                    v = fmaxf(v, __shfl_xor(v, 8, 64));
                    mnew[j] = fmaxf(mrow[qi][j], v);
                    corr[j] = __expf(mrow[qi][j] - mnew[j]);
                    mrow[qi][j] = mnew[j];
                }
                float ps[4][4];
                #pragma unroll
                for (int kj = 0; kj < 4; ++kj)
                    #pragma unroll
                    for (int j = 0; j < 4; ++j)
                        ps[kj][j] = __expf(sf[kj][j] - mnew[j]);
                #pragma unroll
                for (int j = 0; j < 4; ++j) {
                    float r = (ps[0][j] + ps[1][j]) + (ps[2][j] + ps[3][j]);
                    r += __shfl_xor(r, 1, 64);
                    r += __shfl_xor(r, 2, 64);
                    r += __shfl_xor(r, 4, 64);
                    r += __shfl_xor(r, 8, 64);
                    lrow[qi][j] = lrow[qi][j] * corr[j] + r;
                }
                bool need = (corr[0] < 1.f) || (corr[1] < 1.f) || (corr[2] < 1.f) || (corr[3] < 1.f);
                if (__any((int)need)) {
                    #pragma unroll
                    for (int dt = 0; dt < 4; ++dt)
                        #pragma unroll
                        for (int j = 0; j < 4; ++j)
                            accO[qi][dt][j] *= corr[j];
                }
                #pragma unroll
                for (int kj = 0; kj < 4; ++kj)
                    #pragma unroll
                    for (int j = 0; j < 4; ++j)
                        Plds[wv][(qi * 16 + l4 * 4 + j) * 72 + kj * 16 + l15] = f2bf(ps[kj][j]);
            }
            // PV: contraction over 64 keys = 2 mfma per (qi,dt)
            #pragma unroll
            for (int qi = 0; qi < 2; ++qi) {
                #pragma unroll
                for (int ks = 0; ks < 2; ++ks) {
                    bf16x8 af = *reinterpret_cast<const bf16x8*>(
                        &Plds[wv][(qi * 16 + l15) * 72 + ks * 32 + l4 * 8]);
                    #pragma unroll
                    for (int dt = 0; dt < 4; ++dt) {
                        bf16x8 vf = *reinterpret_cast<const bf16x8*>(
                            &Vt[(dt * 16 + l15) * 72 + ks * 32 + l4 * 8]);
                        accO[qi][dt] = __builtin_amdgcn_mfma_f32_16x16x32_bf16(af, vf, accO[qi][dt], 0, 0, 0);
                    }
                }
            }
        }
        kr0 = nk0; kr1 = nk1; vr0 = nv0; vr1 = nv1;
    }

    #pragma unroll
    for (int qi = 0; qi < 2; ++qi) {
        float inv[4];
        #pragma unroll
        for (int j = 0; j < 4; ++j) inv[j] = 1.f / lrow[qi][j];
        #pragma unroll
        for (int dt = 0; dt < 4; ++dt) {
            #pragma unroll
            for (int j = 0; j < 4; ++j) {
                int crow = n * Cdim + wv * 32 + qi * 16 + l4 * 4 + j;
                ao[(size_t)(R0 + crow) * Ddim + h * DHdim + dt * 16 + l15] =
                    f2bf(accO[qi][dt][j] * inv[j]);
            }
        }
    }
}

// ---------------- global token rows attend to all S keys ----------------
__global__ __launch_bounds__(256) void k_attn_glob(const ushort* __restrict__ qkv,
        const int* __restrict__ glob, const int* __restrict__ amask,
        ushort* __restrict__ ao) {
    int g = blockIdx.x, h = blockIdx.y, b = blockIdx.z;
    __shared__ float sc[Sdim];
    __shared__ float qs[DHdim];
    __shared__ float redm[4], reds[4];
    __shared__ float part[32][DHdim];
    int t = threadIdx.x;
    int qr = glob[g];
    const int R0 = b * Sdim;
    if (t < DHdim)
        qs[t] = bf2f(qkv[(size_t)(R0 + qr) * QKVS + h * DHdim + t]) * 0.125f;
    __syncthreads();
    float lm = -1e30f;
    for (int s0 = t; s0 < Sdim; s0 += 256) {
        const ushort8v* kr = (const ushort8v*)(qkv + (size_t)(R0 + s0) * QKVS + Ddim + h * DHdim);
        float s = 0.f;
        #pragma unroll
        for (int cc = 0; cc < 8; ++cc) {
            ushort8v kv = kr[cc];
            #pragma unroll
            for (int e = 0; e < 8; ++e) s += qs[cc * 8 + e] * bf2f(kv[e]);
        }
        if (amask[b * Sdim + s0] == 0) s = -1e30f;
        sc[s0] = s;
        lm = fmaxf(lm, s);
    }
    #pragma unroll
    for (int o = 32; o; o >>= 1) lm = fmaxf(lm, __shfl_xor(lm, o, 64));
    if ((t & 63) == 0) redm[t >> 6] = lm;
    __syncthreads();
    float mx = fmaxf(fmaxf(redm[0], redm[1]), fmaxf(redm[2], redm[3]));
    float lsum = 0.f;
    for (int s0 = t; s0 < Sdim; s0 += 256) {
        float p = __expf(sc[s0] - mx);
        sc[s0] = p; lsum += p;
    }
    #pragma unroll
    for (int o = 32; o; o >>= 1) lsum += __shfl_xor(lsum, o, 64);
    if ((t & 63) == 0) reds[t >> 6] = lsum;
    __syncthreads();
    float l = reds[0] + reds[1] + reds[2] + reds[3];
    int chunk = t >> 3, dg = t & 7;
    float a[8] = {};
    for (int r = chunk * 64; r < chunk * 64 + 64; ++r) {
        float p = sc[r];
        ushort8v vv = *(const ushort8v*)(qkv + (size_t)(R0 + r) * QKVS + 2 * Ddim + h * DHdim + dg * 8);
        #pragma unroll
        for (int e = 0; e < 8; ++e) a[e] += p * bf2f(vv[e]);
    }
    #pragma unroll
    for (int e = 0; e < 8; ++e) part[chunk][dg * 8 + e] = a[e];
    __syncthreads();
    if (t < DHdim) {
        float o = 0.f;
        #pragma unroll
        for (int c = 0; c < 32; ++c) o += part[c][t];
        ao[(size_t)(R0 + qr) * Ddim + h * DHdim + t] = f2bf(o / l);
    }
}

// ---------------- classification head (256 thr, 2-way k-split) ----------------
__global__ __launch_bounds__(256) void k_head(const float* __restrict__ x,
        const int* __restrict__ glob, const float* __restrict__ Wh,
        const float* __restrict__ bh, const float* __restrict__ Wout,
        const float* __restrict__ bout, float* __restrict__ out) {
    int i = blockIdx.x;
    int b = i / 14, j = i % 14;
    __shared__ float emb[2 * Ddim];
    __shared__ float hp[2][128];
    __shared__ float hid[HIDd];
    int t = threadIdx.x;
    int p = glob[j + 2];
    for (int d = t; d < Ddim; d += 256) {
        emb[d] = x[(long)b * Sdim * Ddim + d];
        emb[Ddim + d] = x[((long)b * Sdim + p) * Ddim + d];
    }
    __syncthreads();
    int nn = t & 127, half = t >> 7;
    float s = 0.f;
    if (nn < HIDd) {
        int k0 = half * Ddim;
        for (int k1 = 0; k1 < Ddim; ++k1) s += emb[k0 + k1] * Wh[(k0 + k1) * HIDd + nn];
    }
    hp[half][nn] = s;
    __syncthreads();
    if (t < HIDd) hid[t] = fmaxf(hp[0][t] + hp[1][t] + bh[t], 0.f);
    __syncthreads();
    if (t < NCLSd) {
        float s2 = bout[t];
        for (int o = 0; o < HIDd; ++o) s2 += hid[o] * Wout[o * NCLSd + t];
        out[i * NCLSd + t] = s2;
    }
}

extern "C" void kernel_launch(void* const* d_in, const int* in_sizes, int n_in,
                              void* d_out, int out_size, void* d_ws, size_t ws_size,
                              hipStream_t stream) {
    const int*   ids   = (const int*)d_in[0];
    const int*   am    = (const int*)d_in[1];
    const float* tok   = (const float*)d_in[2];
    const float* pos   = (const float*)d_in[3];
    const float* lneg  = (const float*)d_in[4];
    const float* lneb  = (const float*)d_in[5];
    const float* Wq    = (const float*)d_in[6];
    const float* bq    = (const float*)d_in[7];
    const float* Wk    = (const float*)d_in[8];
    const float* bk    = (const float*)d_in[9];
    const float* Wv    = (const float*)d_in[10];
    const float* bv    = (const float*)d_in[11];
    const float* Wo    = (const float*)d_in[12];
    const float* bo    = (const float*)d_in[13];
    const float* ln1g  = (const float*)d_in[14];
    const float* ln1b  = (const float*)d_in[15];
    const float* W1    = (const float*)d_in[16];
    const float* b1    = (const float*)d_in[17];
    const float* W2    = (const float*)d_in[18];
    const float* b2    = (const float*)d_in[19];
    const float* ln2g  = (const float*)d_in[20];
    const float* ln2b  = (const float*)d_in[21];
    const float* Wh    = (const float*)d_in[22];
    const float* bh    = (const float*)d_in[23];
    const float* Wout  = (const float*)d_in[24];
    const float* bout  = (const float*)d_in[25];
    float* out = (float*)d_out;

    char* ws = (char*)d_ws;
    const size_t SZ = (size_t)MROWS * Ddim * sizeof(float);
    const size_t HB = SZ / 2;
    size_t off = 0;
    float*  x    = (float*)(ws + off);  off += SZ;
    float*  pr   = (float*)(ws + off);  off += SZ;
    ushort* xb   = (ushort*)(ws + off); off += HB;
    ushort* qkvB = (ushort*)(ws + off); off += (size_t)MROWS * QKVS * 2;
    ushort* aoB  = (ushort*)(ws + off); off += HB;
    ushort* hh   = (ushort*)(ws + off); off += (size_t)MROWS * FFdim * 2;
    const size_t WSMALL = (size_t)Ddim * Ddim;
    const size_t WBIG   = (size_t)Ddim * FFdim;
    const size_t WL     = 4 * WSMALL + 2 * WBIG;
    ushort* wts = (ushort*)(ws + off); off += WL * Ldim * 2;
    float* bqkv = (float*)(ws + off);  off += Ldim * QKVS * sizeof(float);
    int* glob = (int*)(ws + off); off += 256;
    int* isg  = (int*)(ws + off);

    k_findsep<<<1, 1024, 0, stream>>>(ids, glob, isg);
    k_biascat<<<Ldim, 256, 0, stream>>>(bq, bk, bv, bqkv);
    k_w2bt_all<<<3456, 256, 0, stream>>>(Wq, Wk, Wv, Wo, W1, W2, wts);
    k_embed<<<MROWS, 64, 0, stream>>>(ids, tok, pos, lneg, lneb, x, xb);

    dim3 g768(Ddim / 128, MROWS / 128);
    dim3 gQKV(QKVS / 128, MROWS / 128);
    dim3 gFF(FFdim / 128, MROWS / 128);
    dim3 gloc(NCdim, Hdim, Bdim);
    dim3 gglb(Gdim, Hdim, Bdim);

    for (int l = 0; l < Ldim; ++l) {
        ushort* base = wts + l * WL;
        ushort* Wqkvt = base;
        ushort* Wot = base + 3 * WSMALL;
        ushort* W1t = base + 4 * WSMALL;
        ushort* W2t = base + 4 * WSMALL + WBIG;
        k_gemm_bf16<0,1><<<gQKV, 256, 0, stream>>>(xb, Wqkvt, bqkv + l * QKVS, qkvB, MROWS, QKVS, Ddim);
        k_attn_mfma<<<gloc, 256, 0, stream>>>(qkvB, isg, glob, am, aoB);
        k_attn_glob<<<gglb, 256, 0, stream>>>(qkvB, glob, am, aoB);
        k_gemm_bf16<0,0><<<g768, 256, 0, stream>>>(aoB, Wot, bo + l * Ddim, pr, MROWS, Ddim, Ddim);
        k_ln_res<<<MROWS, 64, 0, stream>>>(x, pr, ln1g + l * Ddim, ln1b + l * Ddim, xb);
        k_gemm_bf16<1,1><<<gFF, 256, 0, stream>>>(xb, W1t, b1 + l * FFdim, hh, MROWS, FFdim, Ddim);
        k_gemm_bf16<0,0><<<g768, 256, 0, stream>>>(hh, W2t, b2 + l * Ddim, pr, MROWS, Ddim, FFdim);
        k_ln_res<<<MROWS, 64, 0, stream>>>(x, pr, ln2g + l * Ddim, ln2b + l * Ddim, xb);
    }
    k_head<<<Bdim * (NSEPd - 2), 256, 0, stream>>>(x, glob, Wh, bh, Wout, bout, out);
}

// Round 7
// 486.004 us; speedup vs baseline: 7.0575x; 1.1235x over previous
//
#include <hip/hip_runtime.h>
#include <hip/hip_bf16.h>
#include <math.h>

#define Sdim 2048
#define Bdim 2
#define Ddim 768
#define Hdim 12
#define DHdim 64
#define Ldim 2
#define Cdim 128
#define NCdim 16
#define FFdim 3072
#define Gdim 17
#define NSEPd 16
#define HIDd 100
#define NCLSd 7
#define SEPID 2
#define MROWS (Bdim*Sdim)
#define QKVS 2304
#define MNSZ (MROWS*Ddim)

typedef __bf16 bf16_t;
typedef bf16_t bf16x8 __attribute__((ext_vector_type(8)));
typedef float f32x4 __attribute__((ext_vector_type(4)));
typedef ushort ushort8v __attribute__((ext_vector_type(8)));

__device__ __forceinline__ ushort f2bf(float f) {
    union { float f; unsigned u; } a; a.f = f;
    unsigned u = a.u;
    unsigned r = (u + 0x7fffu + ((u >> 16) & 1u)) >> 16;
    return (ushort)r;
}
__device__ __forceinline__ float bf2f(ushort h) {
    union { unsigned u; float f; } a; a.u = ((unsigned)h) << 16;
    return a.f;
}
__device__ __forceinline__ void gload16(const ushort* g, ushort* l) {
    __builtin_amdgcn_global_load_lds(
        (const __attribute__((address_space(1))) void*)g,
        (__attribute__((address_space(3))) void*)l, 16, 0, 0);
}

// ---------------- sep finding (ballot + prefix popcount) + bias concat ----------------
__global__ __launch_bounds__(1024) void k_findsep(const int* __restrict__ ids,
        int* __restrict__ glob, int* __restrict__ isg,
        const float* __restrict__ bq, const float* __restrict__ bk,
        const float* __restrict__ bv, float* __restrict__ bqkv) {
    __shared__ unsigned long long mw[32];
    __shared__ int pfx[32];
    int t = threadIdx.x;
    int flg[2];
    #pragma unroll
    for (int pass = 0; pass < 2; ++pass) {
        int p = pass * 1024 + t;
        int f = (ids[p] == SEPID);
        flg[pass] = f;
        unsigned long long m = __ballot(f);
        if ((t & 63) == 0) mw[pass * 16 + (t >> 6)] = m;
    }
    __syncthreads();
    if (t == 0) {
        int c = 0;
        #pragma unroll
        for (int i = 0; i < 32; ++i) { pfx[i] = c; c += __popcll(mw[i]); }
        glob[0] = 0;
    }
    __syncthreads();
    #pragma unroll
    for (int pass = 0; pass < 2; ++pass) {
        int p = pass * 1024 + t;
        int w = pass * 16 + (t >> 6);
        int lane = t & 63;
        int rank = pfx[w] + __popcll(mw[w] & ((1ull << lane) - 1ull));
        int ig = 0;
        if (flg[pass] && rank < NSEPd) { glob[rank + 1] = p; ig = 1; }
        if (p == 0) ig = 1;
        isg[p] = ig;
    }
    // concat q/k/v biases -> [L][2304]
    for (int idx = t; idx < Ldim * QKVS; idx += 1024) {
        int l = idx / QKVS, i = idx % QKVS;
        float v = (i < Ddim) ? bq[l * Ddim + i]
                : (i < 2 * Ddim) ? bk[l * Ddim + i - Ddim]
                : bv[l * Ddim + i - 2 * Ddim];
        bqkv[idx] = v;
    }
}

// ---------------- ALL weight transposes in ONE kernel ----------------
__global__ __launch_bounds__(256) void k_w2bt_all(
        const float* __restrict__ Wq, const float* __restrict__ Wk,
        const float* __restrict__ Wv, const float* __restrict__ Wo,
        const float* __restrict__ W1, const float* __restrict__ W2,
        ushort* __restrict__ wts) {
    const size_t WSMALL = (size_t)Ddim * Ddim;
    const size_t WBIG   = (size_t)Ddim * FFdim;
    const size_t WL     = 4 * WSMALL + 2 * WBIG;
    int bid = blockIdx.x;
    int l = bid / 1728, r = bid % 1728;
    const float* src; ushort* dst; int K, N, tile;
    ushort* base = wts + (size_t)l * WL;
    if (r < 576) {
        int w = r / 144; tile = r % 144; K = Ddim; N = Ddim;
        src = (w == 0 ? Wq : w == 1 ? Wk : w == 2 ? Wv : Wo) + (size_t)l * WSMALL;
        dst = base + (size_t)w * WSMALL;
    } else if (r < 1152) {
        tile = r - 576; K = Ddim; N = FFdim;
        src = W1 + (size_t)l * WBIG; dst = base + 4 * WSMALL;
    } else {
        tile = r - 1152; K = FFdim; N = Ddim;
        src = W2 + (size_t)l * WBIG; dst = base + 4 * WSMALL + WBIG;
    }
    int ntn = N / 64;
    int bn = (tile % ntn) * 64, bk = (tile / ntn) * 64;

    __shared__ float ts[64][65];
    int t = threadIdx.x;
    int rx = t & 63, ry = t >> 6;
    #pragma unroll
    for (int i = 0; i < 16; ++i) {
        int row = ry * 16 + i;
        ts[row][rx] = src[(size_t)(bk + row) * N + bn + rx];
    }
    __syncthreads();
    int wr = t >> 4;
    int k0 = (t & 15) * 4;
    #pragma unroll
    for (int pass = 0; pass < 4; ++pass) {
        int row = pass * 16 + wr;
        ushort4 val;
        val.x = f2bf(ts[k0 + 0][row]);
        val.y = f2bf(ts[k0 + 1][row]);
        val.z = f2bf(ts[k0 + 2][row]);
        val.w = f2bf(ts[k0 + 3][row]);
        *(ushort4*)(&dst[(size_t)(bn + row) * K + bk + k0]) = val;
    }
}

// ---------------- embedding + LN (1 wave/row, float4) ----------------
__global__ __launch_bounds__(64) void k_embed(const int* __restrict__ ids,
        const float* __restrict__ tok, const float* __restrict__ pos,
        const float* __restrict__ g, const float* __restrict__ b,
        float* __restrict__ x, ushort* __restrict__ xb) {
    int row = blockIdx.x;
    int s = row & (Sdim - 1);
    long id = ids[row];
    const float4* te = (const float4*)(tok + id * (long)Ddim);
    const float4* pe = (const float4*)(pos + (long)s * Ddim);
    int t = threadIdx.x;
    float4 v[3];
    float ls = 0.f, lq = 0.f;
    #pragma unroll
    for (int i = 0; i < 3; ++i) {
        float4 a = te[i * 64 + t], p = pe[i * 64 + t];
        v[i].x = a.x + p.x; v[i].y = a.y + p.y; v[i].z = a.z + p.z; v[i].w = a.w + p.w;
        ls += v[i].x + v[i].y + v[i].z + v[i].w;
        lq += v[i].x * v[i].x + v[i].y * v[i].y + v[i].z * v[i].z + v[i].w * v[i].w;
    }
    #pragma unroll
    for (int o = 32; o; o >>= 1) { ls += __shfl_xor(ls, o, 64); lq += __shfl_xor(lq, o, 64); }
    float mu = ls / Ddim;
    float var = lq / Ddim - mu * mu;
    float rs = rsqrtf(var + 1e-5f);
    const float4* g4 = (const float4*)g;
    const float4* b4 = (const float4*)b;
    float4* xr = (float4*)(x + (long)row * Ddim);
    ushort4* xbr = (ushort4*)(xb + (long)row * Ddim);
    #pragma unroll
    for (int i = 0; i < 3; ++i) {
        float4 gg = g4[i * 64 + t], bb = b4[i * 64 + t];
        float4 o;
        o.x = (v[i].x - mu) * rs * gg.x + bb.x;
        o.y = (v[i].y - mu) * rs * gg.y + bb.y;
        o.z = (v[i].z - mu) * rs * gg.z + bb.z;
        o.w = (v[i].w - mu) * rs * gg.w + bb.w;
        xr[i * 64 + t] = o;
        ushort4 ob; ob.x = f2bf(o.x); ob.y = f2bf(o.y); ob.z = f2bf(o.z); ob.w = f2bf(o.w);
        xbr[i * 64 + t] = ob;
    }
}

// ---------------- residual add + LN (1 wave/row, float4) ----------------
__global__ __launch_bounds__(64) void k_ln_res(float* __restrict__ x,
        const float* __restrict__ a, const float* __restrict__ g,
        const float* __restrict__ b, ushort* __restrict__ xb) {
    long row = blockIdx.x;
    int t = threadIdx.x;
    const float4* xr = (const float4*)(x + row * Ddim);
    const float4* ar = (const float4*)(a + row * Ddim);
    float4 v[3];
    float ls = 0.f, lq = 0.f;
    #pragma unroll
    for (int i = 0; i < 3; ++i) {
        float4 xa = xr[i * 64 + t], aa = ar[i * 64 + t];
        v[i].x = xa.x + aa.x; v[i].y = xa.y + aa.y; v[i].z = xa.z + aa.z; v[i].w = xa.w + aa.w;
        ls += v[i].x + v[i].y + v[i].z + v[i].w;
        lq += v[i].x * v[i].x + v[i].y * v[i].y + v[i].z * v[i].z + v[i].w * v[i].w;
    }
    #pragma unroll
    for (int o = 32; o; o >>= 1) { ls += __shfl_xor(ls, o, 64); lq += __shfl_xor(lq, o, 64); }
    float mu = ls / Ddim;
    float var = lq / Ddim - mu * mu;
    float rs = rsqrtf(var + 1e-5f);
    const float4* g4 = (const float4*)g;
    const float4* b4 = (const float4*)b;
    float4* xw = (float4*)(x + row * Ddim);
    ushort4* xbr = (ushort4*)(xb + row * Ddim);
    #pragma unroll
    for (int i = 0; i < 3; ++i) {
        float4 gg = g4[i * 64 + t], bb = b4[i * 64 + t];
        float4 o;
        o.x = (v[i].x - mu) * rs * gg.x + bb.x;
        o.y = (v[i].y - mu) * rs * gg.y + bb.y;
        o.z = (v[i].z - mu) * rs * gg.z + bb.z;
        o.w = (v[i].w - mu) * rs * gg.w + bb.w;
        xw[i * 64 + t] = o;
        ushort4 ob; ob.x = f2bf(o.x); ob.y = f2bf(o.y); ob.z = f2bf(o.z); ob.w = f2bf(o.w);
        xbr[i * 64 + t] = ob;
    }
}

// ---------------- residual + 4-slice splitK reduce + col-bias + LN ----------------
__global__ __launch_bounds__(64) void k_ln_res4(float* __restrict__ x,
        const float* __restrict__ pr4, const float* __restrict__ bias,
        const float* __restrict__ g, const float* __restrict__ b,
        ushort* __restrict__ xb) {
    long row = blockIdx.x;
    int t = threadIdx.x;
    const float4* xr = (const float4*)(x + row * Ddim);
    const float4* p0 = (const float4*)(pr4 + row * Ddim);
    const float4* p1 = (const float4*)(pr4 + (size_t)MNSZ + row * Ddim);
    const float4* p2 = (const float4*)(pr4 + 2 * (size_t)MNSZ + row * Ddim);
    const float4* p3 = (const float4*)(pr4 + 3 * (size_t)MNSZ + row * Ddim);
    const float4* bi = (const float4*)bias;
    float4 v[3];
    float ls = 0.f, lq = 0.f;
    #pragma unroll
    for (int i = 0; i < 3; ++i) {
        int ii = i * 64 + t;
        float4 xa = xr[ii], a0 = p0[ii], a1 = p1[ii], a2 = p2[ii], a3 = p3[ii], bb = bi[ii];
        v[i].x = xa.x + ((a0.x + a1.x) + (a2.x + a3.x)) + bb.x;
        v[i].y = xa.y + ((a0.y + a1.y) + (a2.y + a3.y)) + bb.y;
        v[i].z = xa.z + ((a0.z + a1.z) + (a2.z + a3.z)) + bb.z;
        v[i].w = xa.w + ((a0.w + a1.w) + (a2.w + a3.w)) + bb.w;
        ls += v[i].x + v[i].y + v[i].z + v[i].w;
        lq += v[i].x * v[i].x + v[i].y * v[i].y + v[i].z * v[i].z + v[i].w * v[i].w;
    }
    #pragma unroll
    for (int o = 32; o; o >>= 1) { ls += __shfl_xor(ls, o, 64); lq += __shfl_xor(lq, o, 64); }
    float mu = ls / Ddim;
    float var = lq / Ddim - mu * mu;
    float rs = rsqrtf(var + 1e-5f);
    const float4* g4 = (const float4*)g;
    const float4* b4 = (const float4*)b;
    float4* xw = (float4*)(x + row * Ddim);
    ushort4* xbr = (ushort4*)(xb + row * Ddim);
    #pragma unroll
    for (int i = 0; i < 3; ++i) {
        float4 gg = g4[i * 64 + t], bb = b4[i * 64 + t];
        float4 o;
        o.x = (v[i].x - mu) * rs * gg.x + bb.x;
        o.y = (v[i].y - mu) * rs * gg.y + bb.y;
        o.z = (v[i].z - mu) * rs * gg.z + bb.z;
        o.w = (v[i].w - mu) * rs * gg.w + bb.w;
        xw[i * 64 + t] = o;
        ushort4 ob; ob.x = f2bf(o.x); ob.y = f2bf(o.y); ob.z = f2bf(o.z); ob.w = f2bf(o.w);
        xbr[i * 64 + t] = ob;
    }
}

// ---------------- bf16 MFMA GEMM (m97 structure + XCD chunked swizzle) ----------------
template<int ACT, int OUTBF16>
__global__ __launch_bounds__(256) void k_gemm_bf16(
        const ushort* __restrict__ A, const ushort* __restrict__ Wt,
        const float* __restrict__ bias, void* __restrict__ Cout,
        int M, int N, int K)
{
    __shared__ ushort As[128 * 32];
    __shared__ ushort Bs[128 * 32];
    const int t = threadIdx.x;
    const int nwg = gridDim.x * gridDim.y;
    const int wgid = blockIdx.y * gridDim.x + blockIdx.x;
    const int q8 = nwg >> 3, r8 = nwg & 7;
    const int xcd = wgid & 7, idx = wgid >> 3;
    const int swz = (xcd < r8 ? xcd * (q8 + 1) : r8 * (q8 + 1) + (xcd - r8) * q8) + idx;
    const int bm = (swz / gridDim.x) * 128;
    const int bn = (swz % gridDim.x) * 128;
    const int lane = t & 63;
    const int wv = t >> 6;
    const int wm = (wv >> 1) * 64;
    const int wn = (wv & 1) * 64;

    const int srow = t >> 2;
    const int scol = (t & 3) * 8;
    const ushort* gA0 = A + (size_t)(bm + srow) * K + scol;
    const ushort* gA1 = A + (size_t)(bm + 64 + srow) * K + scol;
    const ushort* gB0 = Wt + (size_t)(bn + srow) * K + scol;
    const ushort* gB1 = Wt + (size_t)(bn + 64 + srow) * K + scol;
    ushort* lA0 = As + t * 8;
    ushort* lA1 = As + 2048 + t * 8;
    ushort* lB0 = Bs + t * 8;
    ushort* lB1 = Bs + 2048 + t * 8;

    f32x4 acc[4][4] = {};

    const int frow = lane & 15;
    const int koff = (lane >> 4) * 8;

    for (int k0 = 0; k0 < K; k0 += 32) {
        gload16(gA0 + k0, lA0);
        gload16(gA1 + k0, lA1);
        gload16(gB0 + k0, lB0);
        gload16(gB1 + k0, lB1);
        __syncthreads();
        bf16x8 af[4], bfv[4];
        #pragma unroll
        for (int mi = 0; mi < 4; ++mi)
            af[mi] = *reinterpret_cast<const bf16x8*>(As + (wm + mi * 16 + frow) * 32 + koff);
        #pragma unroll
        for (int ni = 0; ni < 4; ++ni)
            bfv[ni] = *reinterpret_cast<const bf16x8*>(Bs + (wn + ni * 16 + frow) * 32 + koff);
        #pragma unroll
        for (int mi = 0; mi < 4; ++mi)
            #pragma unroll
            for (int ni = 0; ni < 4; ++ni)
                acc[mi][ni] = __builtin_amdgcn_mfma_f32_16x16x32_bf16(af[mi], bfv[ni], acc[mi][ni], 0, 0, 0);
        __syncthreads();
    }
    const int crow0 = (lane >> 4) * 4;
    const int ccol = lane & 15;
    #pragma unroll
    for (int mi = 0; mi < 4; ++mi) {
        #pragma unroll
        for (int ni = 0; ni < 4; ++ni) {
            int gc = bn + wn + ni * 16 + ccol;
            float bv = bias[gc];
            #pragma unroll
            for (int j = 0; j < 4; ++j) {
                int gr = bm + wm + mi * 16 + crow0 + j;
                float v = acc[mi][ni][j] + bv;
                if (ACT == 1) {
                    float y = 0.7978845608f * (v + 0.044715f * v * v * v);
                    float e = __expf(2.f * y);
                    v = v * (1.f - 1.f / (e + 1.f));
                }
                if (OUTBF16) ((ushort*)Cout)[(size_t)gr * N + gc] = f2bf(v);
                else         ((float*)Cout)[(size_t)gr * N + gc] = v;
            }
        }
    }
}

// ---------------- splitK bf16 MFMA GEMM: partial f32, no bias ----------------
// grid (N/128, M/128, NSPLIT); slice ks covers k in [ks*Kper, (ks+1)*Kper)
__global__ __launch_bounds__(256) void k_gemm_splitk(
        const ushort* __restrict__ A, const ushort* __restrict__ Wt,
        float* __restrict__ Cpart, int M, int N, int K, int Kper)
{
    __shared__ ushort As[128 * 32];
    __shared__ ushort Bs[128 * 32];
    const int t = threadIdx.x;
    const int ks = blockIdx.z;
    const int nwg = gridDim.x * gridDim.y;
    const int wgid = blockIdx.y * gridDim.x + blockIdx.x;
    const int q8 = nwg >> 3, r8 = nwg & 7;
    const int xcd = wgid & 7, idx = wgid >> 3;
    const int swz = (xcd < r8 ? xcd * (q8 + 1) : r8 * (q8 + 1) + (xcd - r8) * q8) + idx;
    const int bm = (swz / gridDim.x) * 128;
    const int bn = (swz % gridDim.x) * 128;
    const int lane = t & 63;
    const int wv = t >> 6;
    const int wm = (wv >> 1) * 64;
    const int wn = (wv & 1) * 64;

    const int srow = t >> 2;
    const int scol = (t & 3) * 8;
    const int kbase = ks * Kper;
    const ushort* gA0 = A + (size_t)(bm + srow) * K + kbase + scol;
    const ushort* gA1 = A + (size_t)(bm + 64 + srow) * K + kbase + scol;
    const ushort* gB0 = Wt + (size_t)(bn + srow) * K + kbase + scol;
    const ushort* gB1 = Wt + (size_t)(bn + 64 + srow) * K + kbase + scol;
    ushort* lA0 = As + t * 8;
    ushort* lA1 = As + 2048 + t * 8;
    ushort* lB0 = Bs + t * 8;
    ushort* lB1 = Bs + 2048 + t * 8;

    f32x4 acc[4][4] = {};

    const int frow = lane & 15;
    const int koff = (lane >> 4) * 8;

    for (int k0 = 0; k0 < Kper; k0 += 32) {
        gload16(gA0 + k0, lA0);
        gload16(gA1 + k0, lA1);
        gload16(gB0 + k0, lB0);
        gload16(gB1 + k0, lB1);
        __syncthreads();
        bf16x8 af[4], bfv[4];
        #pragma unroll
        for (int mi = 0; mi < 4; ++mi)
            af[mi] = *reinterpret_cast<const bf16x8*>(As + (wm + mi * 16 + frow) * 32 + koff);
        #pragma unroll
        for (int ni = 0; ni < 4; ++ni)
            bfv[ni] = *reinterpret_cast<const bf16x8*>(Bs + (wn + ni * 16 + frow) * 32 + koff);
        #pragma unroll
        for (int mi = 0; mi < 4; ++mi)
            #pragma unroll
            for (int ni = 0; ni < 4; ++ni)
                acc[mi][ni] = __builtin_amdgcn_mfma_f32_16x16x32_bf16(af[mi], bfv[ni], acc[mi][ni], 0, 0, 0);
        __syncthreads();
    }
    float* outp = Cpart + (size_t)ks * M * N;
    const int crow0 = (lane >> 4) * 4;
    const int ccol = lane & 15;
    #pragma unroll
    for (int mi = 0; mi < 4; ++mi) {
        #pragma unroll
        for (int ni = 0; ni < 4; ++ni) {
            int gc = bn + wn + ni * 16 + ccol;
            #pragma unroll
            for (int j = 0; j < 4; ++j) {
                int gr = bm + wm + mi * 16 + crow0 + j;
                outp[(size_t)gr * N + gc] = acc[mi][ni][j];
            }
        }
    }
}

// ---------------- MFMA flash local attention, 64-key tiles ----------------
__global__ __launch_bounds__(256) void k_attn_mfma(
        const ushort* __restrict__ qkv, const int* __restrict__ isg,
        const int* __restrict__ glob, const int* __restrict__ amask,
        ushort* __restrict__ ao)
{
    const int n = blockIdx.x, h = blockIdx.y, b = blockIdx.z;
    const int t = threadIdx.x;
    const int lane = t & 63, wv = t >> 6;
    const int R0 = b * Sdim;
    const int l15 = lane & 15, l4 = lane >> 4;

    __shared__ ushort Kb[64 * 64];        // swizzled [key][64]
    __shared__ ushort Vt[64 * 72];        // [d][key] pad 72
    __shared__ ushort Plds[4][32 * 72];   // per-wave P, pad 72
    __shared__ float  maskLDS[448];

    for (int i = t; i < 448; i += 256) {
        int ok;
        if (i < 384) {
            int pos = n * Cdim + i - Cdim;
            ok = (pos >= 0 && pos < Sdim);
            if (ok) ok = (amask[b * Sdim + pos] != 0) && (isg[pos] == 0);
        } else {
            int g = i - 384;
            int gp = (g < Gdim) ? glob[g] : 0;
            ok = (g < Gdim) && (amask[b * Sdim + gp] != 0);
        }
        maskLDS[i] = ok ? 0.f : -1e9f;
    }

    bf16x8 qf[2][2];
    #pragma unroll
    for (int qi = 0; qi < 2; ++qi)
        #pragma unroll
        for (int kh = 0; kh < 2; ++kh)
            qf[qi][kh] = *reinterpret_cast<const bf16x8*>(
                qkv + (size_t)(R0 + n * Cdim + wv * 32 + qi * 16 + l15) * QKVS
                    + h * DHdim + kh * 32 + l4 * 8);

    f32x4 accO[2][4] = {};
    float mrow[2][4], lrow[2][4];
    #pragma unroll
    for (int qi = 0; qi < 2; ++qi)
        #pragma unroll
        for (int j = 0; j < 4; ++j) { mrow[qi][j] = -1e30f; lrow[qi][j] = 0.f; }

    const int jj = t >> 3;   // 0..31
    const int c16 = t & 7;   // 0..7

    auto ldone = [&](int j, ushort8v& kr, ushort8v& vr) {
        int pos = 0; bool ok;
        if (j < 384) { pos = n * Cdim + j - Cdim; ok = (pos >= 0 && pos < Sdim); }
        else { int g = j - 384; ok = (g < Gdim); if (ok) pos = glob[g]; }
        ushort8v z = {};
        if (ok) {
            const ushort* kp = qkv + (size_t)(R0 + pos) * QKVS + Ddim + h * DHdim + c16 * 8;
            kr = *reinterpret_cast<const ushort8v*>(kp);
            vr = *reinterpret_cast<const ushort8v*>(kp + Ddim);
        } else { kr = z; vr = z; }
    };

    ushort8v kr0, kr1, vr0, vr1, nk0 = {}, nk1 = {}, nv0 = {}, nv1 = {};
    ldone(jj, kr0, vr0);
    ldone(jj + 32, kr1, vr1);

    for (int kt = 0; kt < 7; ++kt) {
        __syncthreads();
        *reinterpret_cast<ushort8v*>(&Kb[jj * 64 + ((c16 ^ (jj & 7)) * 8)]) = kr0;
        *reinterpret_cast<ushort8v*>(&Kb[(jj + 32) * 64 + ((c16 ^ (jj & 7)) * 8)]) = kr1;
        #pragma unroll
        for (int e = 0; e < 8; ++e) {
            Vt[(c16 * 8 + e) * 72 + jj] = vr0[e];
            Vt[(c16 * 8 + e) * 72 + 32 + jj] = vr1[e];
        }
        if (kt < 6) {
            int base_j = (kt + 1) * 64 + jj;
            ldone(base_j, nk0, nv0);
            ldone(base_j + 32, nk1, nv1);
        }
        __syncthreads();

        bool active = (kt == 6) || ((kt * 64 + 63 >= wv * 32) && (kt * 64 <= wv * 32 + 287));
        if (active) {
            bf16x8 kf[4][2];
            #pragma unroll
            for (int kj = 0; kj < 4; ++kj) {
                int key = kj * 16 + l15;
                #pragma unroll
                for (int kh = 0; kh < 2; ++kh) {
                    int cc = (kh * 4 + l4) ^ (key & 7);
                    kf[kj][kh] = *reinterpret_cast<const bf16x8*>(&Kb[key * 64 + cc * 8]);
                }
            }
            float ma[4];
            #pragma unroll
            for (int kj = 0; kj < 4; ++kj) ma[kj] = maskLDS[kt * 64 + kj * 16 + l15];

            #pragma unroll
            for (int qi = 0; qi < 2; ++qi) {
                f32x4 s[4] = {};
                #pragma unroll
                for (int kj = 0; kj < 4; ++kj)
                    #pragma unroll
                    for (int kh = 0; kh < 2; ++kh)
                        s[kj] = __builtin_amdgcn_mfma_f32_16x16x32_bf16(qf[qi][kh], kf[kj][kh], s[kj], 0, 0, 0);

                float sf[4][4];
                #pragma unroll
                for (int kj = 0; kj < 4; ++kj) {
                    int key = kt * 64 + kj * 16 + l15;
                    #pragma unroll
                    for (int j = 0; j < 4; ++j) {
                        int cq = wv * 32 + qi * 16 + l4 * 4 + j;
                        float sv = s[kj][j] * 0.125f + ma[kj];
                        bool band = (key >= 384) || ((unsigned)(key - cq) <= 256u);
                        sf[kj][j] = band ? sv : sv - 1e9f;
                    }
                }
                float mnew[4], corr[4];
                #pragma unroll
                for (int j = 0; j < 4; ++j) {
                    float v = fmaxf(fmaxf(sf[0][j], sf[1][j]), fmaxf(sf[2][j], sf[3][j]));
                    v = fmaxf(v, __shfl_xor(v, 1, 64));
                    v = fmaxf(v, __shfl_xor(v, 2, 64));
                    v = fmaxf(v, __shfl_xor(v, 4, 64));
                    v = fmaxf(v, __shfl_xor(v, 8, 64));
                    mnew[j] = fmaxf(mrow[qi][j], v);
                    corr[j] = __expf(mrow[qi][j] - mnew[j]);
                    mrow[qi][j] = mnew[j];
                }
                float ps[4][4];
                #pragma unroll
                for (int kj = 0; kj < 4; ++kj)
                    #pragma unroll
                    for (int j = 0; j < 4; ++j)
                        ps[kj][j] = __expf(sf[kj][j] - mnew[j]);
                #pragma unroll
                for (int j = 0; j < 4; ++j) {
                    float r = (ps[0][j] + ps[1][j]) + (ps[2][j] + ps[3][j]);
                    r += __shfl_xor(r, 1, 64);
                    r += __shfl_xor(r, 2, 64);
                    r += __shfl_xor(r, 4, 64);
                    r += __shfl_xor(r, 8, 64);
                    lrow[qi][j] = lrow[qi][j] * corr[j] + r;
                }
                bool need = (corr[0] < 1.f) || (corr[1] < 1.f) || (corr[2] < 1.f) || (corr[3] < 1.f);
                if (__any((int)need)) {
                    #pragma unroll
                    for (int dt = 0; dt < 4; ++dt)
                        #pragma unroll
                        for (int j = 0; j < 4; ++j)
                            accO[qi][dt][j] *= corr[j];
                }
                #pragma unroll
                for (int kj = 0; kj < 4; ++kj)
                    #pragma unroll
                    for (int j = 0; j < 4; ++j)
                        Plds[wv][(qi * 16 + l4 * 4 + j) * 72 + kj * 16 + l15] = f2bf(ps[kj][j]);
            }
            #pragma unroll
            for (int qi = 0; qi < 2; ++qi) {
                #pragma unroll
                for (int ks = 0; ks < 2; ++ks) {
                    bf16x8 af = *reinterpret_cast<const bf16x8*>(
                        &Plds[wv][(qi * 16 + l15) * 72 + ks * 32 + l4 * 8]);
                    #pragma unroll
                    for (int dt = 0; dt < 4; ++dt) {
                        bf16x8 vf = *reinterpret_cast<const bf16x8*>(
                            &Vt[(dt * 16 + l15) * 72 + ks * 32 + l4 * 8]);
                        accO[qi][dt] = __builtin_amdgcn_mfma_f32_16x16x32_bf16(af, vf, accO[qi][dt], 0, 0, 0);
                    }
                }
            }
        }
        kr0 = nk0; kr1 = nk1; vr0 = nv0; vr1 = nv1;
    }

    #pragma unroll
    for (int qi = 0; qi < 2; ++qi) {
        float inv[4];
        #pragma unroll
        for (int j = 0; j < 4; ++j) inv[j] = 1.f / lrow[qi][j];
        #pragma unroll
        for (int dt = 0; dt < 4; ++dt) {
            #pragma unroll
            for (int j = 0; j < 4; ++j) {
                int crow = n * Cdim + wv * 32 + qi * 16 + l4 * 4 + j;
                ao[(size_t)(R0 + crow) * Ddim + h * DHdim + dt * 16 + l15] =
                    f2bf(accO[qi][dt][j] * inv[j]);
            }
        }
    }
}

// ---------------- global token rows attend to all S keys ----------------
__global__ __launch_bounds__(256) void k_attn_glob(const ushort* __restrict__ qkv,
        const int* __restrict__ glob, const int* __restrict__ amask,
        ushort* __restrict__ ao) {
    int g = blockIdx.x, h = blockIdx.y, b = blockIdx.z;
    __shared__ float sc[Sdim];
    __shared__ float qs[DHdim];
    __shared__ float redm[4], reds[4];
    __shared__ float part[32][DHdim];
    int t = threadIdx.x;
    int qr = glob[g];
    const int R0 = b * Sdim;
    if (t < DHdim)
        qs[t] = bf2f(qkv[(size_t)(R0 + qr) * QKVS + h * DHdim + t]) * 0.125f;
    __syncthreads();
    float lm = -1e30f;
    for (int s0 = t; s0 < Sdim; s0 += 256) {
        const ushort8v* kr = (const ushort8v*)(qkv + (size_t)(R0 + s0) * QKVS + Ddim + h * DHdim);
        float s = 0.f;
        #pragma unroll
        for (int cc = 0; cc < 8; ++cc) {
            ushort8v kv = kr[cc];
            #pragma unroll
            for (int e = 0; e < 8; ++e) s += qs[cc * 8 + e] * bf2f(kv[e]);
        }
        if (amask[b * Sdim + s0] == 0) s = -1e30f;
        sc[s0] = s;
        lm = fmaxf(lm, s);
    }
    #pragma unroll
    for (int o = 32; o; o >>= 1) lm = fmaxf(lm, __shfl_xor(lm, o, 64));
    if ((t & 63) == 0) redm[t >> 6] = lm;
    __syncthreads();
    float mx = fmaxf(fmaxf(redm[0], redm[1]), fmaxf(redm[2], redm[3]));
    float lsum = 0.f;
    for (int s0 = t; s0 < Sdim; s0 += 256) {
        float p = __expf(sc[s0] - mx);
        sc[s0] = p; lsum += p;
    }
    #pragma unroll
    for (int o = 32; o; o >>= 1) lsum += __shfl_xor(lsum, o, 64);
    if ((t & 63) == 0) reds[t >> 6] = lsum;
    __syncthreads();
    float l = reds[0] + reds[1] + reds[2] + reds[3];
    int chunk = t >> 3, dg = t & 7;
    float a[8] = {};
    for (int r = chunk * 64; r < chunk * 64 + 64; ++r) {
        float p = sc[r];
        ushort8v vv = *(const ushort8v*)(qkv + (size_t)(R0 + r) * QKVS + 2 * Ddim + h * DHdim + dg * 8);
        #pragma unroll
        for (int e = 0; e < 8; ++e) a[e] += p * bf2f(vv[e]);
    }
    #pragma unroll
    for (int e = 0; e < 8; ++e) part[chunk][dg * 8 + e] = a[e];
    __syncthreads();
    if (t < DHdim) {
        float o = 0.f;
        #pragma unroll
        for (int c = 0; c < 32; ++c) o += part[c][t];
        ao[(size_t)(R0 + qr) * Ddim + h * DHdim + t] = f2bf(o / l);
    }
}

// ---------------- classification head (256 thr, 2-way k-split) ----------------
__global__ __launch_bounds__(256) void k_head(const float* __restrict__ x,
        const int* __restrict__ glob, const float* __restrict__ Wh,
        const float* __restrict__ bh, const float* __restrict__ Wout,
        const float* __restrict__ bout, float* __restrict__ out) {
    int i = blockIdx.x;
    int b = i / 14, j = i % 14;
    __shared__ float emb[2 * Ddim];
    __shared__ float hp[2][128];
    __shared__ float hid[HIDd];
    int t = threadIdx.x;
    int p = glob[j + 2];
    for (int d = t; d < Ddim; d += 256) {
        emb[d] = x[(long)b * Sdim * Ddim + d];
        emb[Ddim + d] = x[((long)b * Sdim + p) * Ddim + d];
    }
    __syncthreads();
    int nn = t & 127, half = t >> 7;
    float s = 0.f;
    if (nn < HIDd) {
        int k0 = half * Ddim;
        for (int k1 = 0; k1 < Ddim; ++k1) s += emb[k0 + k1] * Wh[(k0 + k1) * HIDd + nn];
    }
    hp[half][nn] = s;
    __syncthreads();
    if (t < HIDd) hid[t] = fmaxf(hp[0][t] + hp[1][t] + bh[t], 0.f);
    __syncthreads();
    if (t < NCLSd) {
        float s2 = bout[t];
        for (int o = 0; o < HIDd; ++o) s2 += hid[o] * Wout[o * NCLSd + t];
        out[i * NCLSd + t] = s2;
    }
}

extern "C" void kernel_launch(void* const* d_in, const int* in_sizes, int n_in,
                              void* d_out, int out_size, void* d_ws, size_t ws_size,
                              hipStream_t stream) {
    const int*   ids   = (const int*)d_in[0];
    const int*   am    = (const int*)d_in[1];
    const float* tok   = (const float*)d_in[2];
    const float* pos   = (const float*)d_in[3];
    const float* lneg  = (const float*)d_in[4];
    const float* lneb  = (const float*)d_in[5];
    const float* Wq    = (const float*)d_in[6];
    const float* bq    = (const float*)d_in[7];
    const float* Wk    = (const float*)d_in[8];
    const float* bk    = (const float*)d_in[9];
    const float* Wv    = (const float*)d_in[10];
    const float* bv    = (const float*)d_in[11];
    const float* Wo    = (const float*)d_in[12];
    const float* bo    = (const float*)d_in[13];
    const float* ln1g  = (const float*)d_in[14];
    const float* ln1b  = (const float*)d_in[15];
    const float* W1    = (const float*)d_in[16];
    const float* b1    = (const float*)d_in[17];
    const float* W2    = (const float*)d_in[18];
    const float* b2    = (const float*)d_in[19];
    const float* ln2g  = (const float*)d_in[20];
    const float* ln2b  = (const float*)d_in[21];
    const float* Wh    = (const float*)d_in[22];
    const float* bh    = (const float*)d_in[23];
    const float* Wout  = (const float*)d_in[24];
    const float* bout  = (const float*)d_in[25];
    float* out = (float*)d_out;

    char* ws = (char*)d_ws;
    const size_t SZ = (size_t)MROWS * Ddim * sizeof(float);
    const size_t HB = SZ / 2;
    size_t off = 0;
    float*  x    = (float*)(ws + off);  off += SZ;
    float*  pr4  = (float*)(ws + off);  off += 4 * SZ;   // splitK partials / Wo out
    ushort* xb   = (ushort*)(ws + off); off += HB;
    ushort* qkvB = (ushort*)(ws + off); off += (size_t)MROWS * QKVS * 2;
    ushort* aoB  = (ushort*)(ws + off); off += HB;
    ushort* hh   = (ushort*)(ws + off); off += (size_t)MROWS * FFdim * 2;
    const size_t WSMALL = (size_t)Ddim * Ddim;
    const size_t WBIG   = (size_t)Ddim * FFdim;
    const size_t WL     = 4 * WSMALL + 2 * WBIG;
    ushort* wts = (ushort*)(ws + off); off += WL * Ldim * 2;
    float* bqkv = (float*)(ws + off);  off += Ldim * QKVS * sizeof(float);
    int* glob = (int*)(ws + off); off += 256;
    int* isg  = (int*)(ws + off);

    k_findsep<<<1, 1024, 0, stream>>>(ids, glob, isg, bq, bk, bv, bqkv);
    k_w2bt_all<<<3456, 256, 0, stream>>>(Wq, Wk, Wv, Wo, W1, W2, wts);
    k_embed<<<MROWS, 64, 0, stream>>>(ids, tok, pos, lneg, lneb, x, xb);

    dim3 g768(Ddim / 128, MROWS / 128);
    dim3 gQKV(QKVS / 128, MROWS / 128);
    dim3 gFF(FFdim / 128, MROWS / 128);
    dim3 gW2(Ddim / 128, MROWS / 128, 4);   // 6 x 32 x 4 = 768 blocks, balanced 3/CU
    dim3 gloc(NCdim, Hdim, Bdim);
    dim3 gglb(Gdim, Hdim, Bdim);

    for (int l = 0; l < Ldim; ++l) {
        ushort* base = wts + l * WL;
        ushort* Wqkvt = base;
        ushort* Wot = base + 3 * WSMALL;
        ushort* W1t = base + 4 * WSMALL;
        ushort* W2t = base + 4 * WSMALL + WBIG;
        k_gemm_bf16<0,1><<<gQKV, 256, 0, stream>>>(xb, Wqkvt, bqkv + l * QKVS, qkvB, MROWS, QKVS, Ddim);
        k_attn_mfma<<<gloc, 256, 0, stream>>>(qkvB, isg, glob, am, aoB);
        k_attn_glob<<<gglb, 256, 0, stream>>>(qkvB, glob, am, aoB);
        k_gemm_bf16<0,0><<<g768, 256, 0, stream>>>(aoB, Wot, bo + l * Ddim, pr4, MROWS, Ddim, Ddim);
        k_ln_res<<<MROWS, 64, 0, stream>>>(x, pr4, ln1g + l * Ddim, ln1b + l * Ddim, xb);
        k_gemm_bf16<1,1><<<gFF, 256, 0, stream>>>(xb, W1t, b1 + l * FFdim, hh, MROWS, FFdim, Ddim);
        k_gemm_splitk<<<gW2, 256, 0, stream>>>(hh, W2t, pr4, MROWS, Ddim, FFdim, FFdim / 4);
        k_ln_res4<<<MROWS, 64, 0, stream>>>(x, pr4, b2 + l * Ddim, ln2g + l * Ddim, ln2b + l * Ddim, xb);
    }
    k_head<<<Bdim * (NSEPd - 2), 256, 0, stream>>>(x, glob, Wh, bh, Wout, bout, out);
}

// Round 8
// 473.954 us; speedup vs baseline: 7.2369x; 1.0254x over previous
//
#include <hip/hip_runtime.h>
#include <hip/hip_bf16.h>
#include <math.h>

#define Sdim 2048
#define Bdim 2
#define Ddim 768
#define Hdim 12
#define DHdim 64
#define Ldim 2
#define Cdim 128
#define NCdim 16
#define FFdim 3072
#define Gdim 17
#define NSEPd 16
#define HIDd 100
#define NCLSd 7
#define SEPID 2
#define MROWS (Bdim*Sdim)
#define QKVS 2304
#define MNSZ (MROWS*Ddim)

typedef __bf16 bf16_t;
typedef bf16_t bf16x8 __attribute__((ext_vector_type(8)));
typedef float f32x4 __attribute__((ext_vector_type(4)));
typedef ushort ushort8v __attribute__((ext_vector_type(8)));

__device__ __forceinline__ ushort f2bf(float f) {
    union { float f; unsigned u; } a; a.f = f;
    unsigned u = a.u;
    unsigned r = (u + 0x7fffu + ((u >> 16) & 1u)) >> 16;
    return (ushort)r;
}
__device__ __forceinline__ float bf2f(ushort h) {
    union { unsigned u; float f; } a; a.u = ((unsigned)h) << 16;
    return a.f;
}
__device__ __forceinline__ void gload16(const ushort* g, ushort* l) {
    __builtin_amdgcn_global_load_lds(
        (const __attribute__((address_space(1))) void*)g,
        (__attribute__((address_space(3))) void*)l, 16, 0, 0);
}

// ---------------- sep finding (ballot + prefix popcount) + bias concat ----------------
__global__ __launch_bounds__(1024) void k_findsep(const int* __restrict__ ids,
        int* __restrict__ glob, int* __restrict__ isg,
        const float* __restrict__ bq, const float* __restrict__ bk,
        const float* __restrict__ bv, float* __restrict__ bqkv) {
    __shared__ unsigned long long mw[32];
    __shared__ int pfx[32];
    int t = threadIdx.x;
    int flg[2];
    #pragma unroll
    for (int pass = 0; pass < 2; ++pass) {
        int p = pass * 1024 + t;
        int f = (ids[p] == SEPID);
        flg[pass] = f;
        unsigned long long m = __ballot(f);
        if ((t & 63) == 0) mw[pass * 16 + (t >> 6)] = m;
    }
    __syncthreads();
    if (t == 0) {
        int c = 0;
        #pragma unroll
        for (int i = 0; i < 32; ++i) { pfx[i] = c; c += __popcll(mw[i]); }
        glob[0] = 0;
    }
    __syncthreads();
    #pragma unroll
    for (int pass = 0; pass < 2; ++pass) {
        int p = pass * 1024 + t;
        int w = pass * 16 + (t >> 6);
        int lane = t & 63;
        int rank = pfx[w] + __popcll(mw[w] & ((1ull << lane) - 1ull));
        int ig = 0;
        if (flg[pass] && rank < NSEPd) { glob[rank + 1] = p; ig = 1; }
        if (p == 0) ig = 1;
        isg[p] = ig;
    }
    for (int idx = t; idx < Ldim * QKVS; idx += 1024) {
        int l = idx / QKVS, i = idx % QKVS;
        float v = (i < Ddim) ? bq[l * Ddim + i]
                : (i < 2 * Ddim) ? bk[l * Ddim + i - Ddim]
                : bv[l * Ddim + i - 2 * Ddim];
        bqkv[idx] = v;
    }
}

// ---------------- ALL weight transposes in ONE kernel ----------------
__global__ __launch_bounds__(256) void k_w2bt_all(
        const float* __restrict__ Wq, const float* __restrict__ Wk,
        const float* __restrict__ Wv, const float* __restrict__ Wo,
        const float* __restrict__ W1, const float* __restrict__ W2,
        ushort* __restrict__ wts) {
    const size_t WSMALL = (size_t)Ddim * Ddim;
    const size_t WBIG   = (size_t)Ddim * FFdim;
    const size_t WL     = 4 * WSMALL + 2 * WBIG;
    int bid = blockIdx.x;
    int l = bid / 1728, r = bid % 1728;
    const float* src; ushort* dst; int K, N, tile;
    ushort* base = wts + (size_t)l * WL;
    if (r < 576) {
        int w = r / 144; tile = r % 144; K = Ddim; N = Ddim;
        src = (w == 0 ? Wq : w == 1 ? Wk : w == 2 ? Wv : Wo) + (size_t)l * WSMALL;
        dst = base + (size_t)w * WSMALL;
    } else if (r < 1152) {
        tile = r - 576; K = Ddim; N = FFdim;
        src = W1 + (size_t)l * WBIG; dst = base + 4 * WSMALL;
    } else {
        tile = r - 1152; K = FFdim; N = Ddim;
        src = W2 + (size_t)l * WBIG; dst = base + 4 * WSMALL + WBIG;
    }
    int ntn = N / 64;
    int bn = (tile % ntn) * 64, bk = (tile / ntn) * 64;

    __shared__ float ts[64][65];
    int t = threadIdx.x;
    int rx = t & 63, ry = t >> 6;
    #pragma unroll
    for (int i = 0; i < 16; ++i) {
        int row = ry * 16 + i;
        ts[row][rx] = src[(size_t)(bk + row) * N + bn + rx];
    }
    __syncthreads();
    int wr = t >> 4;
    int k0 = (t & 15) * 4;
    #pragma unroll
    for (int pass = 0; pass < 4; ++pass) {
        int row = pass * 16 + wr;
        ushort4 val;
        val.x = f2bf(ts[k0 + 0][row]);
        val.y = f2bf(ts[k0 + 1][row]);
        val.z = f2bf(ts[k0 + 2][row]);
        val.w = f2bf(ts[k0 + 3][row]);
        *(ushort4*)(&dst[(size_t)(bn + row) * K + bk + k0]) = val;
    }
}

// ---------------- embedding + LN (1 wave/row, float4) ----------------
__global__ __launch_bounds__(64) void k_embed(const int* __restrict__ ids,
        const float* __restrict__ tok, const float* __restrict__ pos,
        const float* __restrict__ g, const float* __restrict__ b,
        float* __restrict__ x, ushort* __restrict__ xb) {
    int row = blockIdx.x;
    int s = row & (Sdim - 1);
    long id = ids[row];
    const float4* te = (const float4*)(tok + id * (long)Ddim);
    const float4* pe = (const float4*)(pos + (long)s * Ddim);
    int t = threadIdx.x;
    float4 v[3];
    float ls = 0.f, lq = 0.f;
    #pragma unroll
    for (int i = 0; i < 3; ++i) {
        float4 a = te[i * 64 + t], p = pe[i * 64 + t];
        v[i].x = a.x + p.x; v[i].y = a.y + p.y; v[i].z = a.z + p.z; v[i].w = a.w + p.w;
        ls += v[i].x + v[i].y + v[i].z + v[i].w;
        lq += v[i].x * v[i].x + v[i].y * v[i].y + v[i].z * v[i].z + v[i].w * v[i].w;
    }
    #pragma unroll
    for (int o = 32; o; o >>= 1) { ls += __shfl_xor(ls, o, 64); lq += __shfl_xor(lq, o, 64); }
    float mu = ls / Ddim;
    float var = lq / Ddim - mu * mu;
    float rs = rsqrtf(var + 1e-5f);
    const float4* g4 = (const float4*)g;
    const float4* b4 = (const float4*)b;
    float4* xr = (float4*)(x + (long)row * Ddim);
    ushort4* xbr = (ushort4*)(xb + (long)row * Ddim);
    #pragma unroll
    for (int i = 0; i < 3; ++i) {
        float4 gg = g4[i * 64 + t], bb = b4[i * 64 + t];
        float4 o;
        o.x = (v[i].x - mu) * rs * gg.x + bb.x;
        o.y = (v[i].y - mu) * rs * gg.y + bb.y;
        o.z = (v[i].z - mu) * rs * gg.z + bb.z;
        o.w = (v[i].w - mu) * rs * gg.w + bb.w;
        xr[i * 64 + t] = o;
        ushort4 ob; ob.x = f2bf(o.x); ob.y = f2bf(o.y); ob.z = f2bf(o.z); ob.w = f2bf(o.w);
        xbr[i * 64 + t] = ob;
    }
}

// ---------------- residual + 4-slice splitK reduce + col-bias + LN ----------------
__global__ __launch_bounds__(64) void k_ln_res4(float* __restrict__ x,
        const float* __restrict__ pr4, const float* __restrict__ bias,
        const float* __restrict__ g, const float* __restrict__ b,
        ushort* __restrict__ xb) {
    long row = blockIdx.x;
    int t = threadIdx.x;
    const float4* xr = (const float4*)(x + row * Ddim);
    const float4* p0 = (const float4*)(pr4 + row * Ddim);
    const float4* p1 = (const float4*)(pr4 + (size_t)MNSZ + row * Ddim);
    const float4* p2 = (const float4*)(pr4 + 2 * (size_t)MNSZ + row * Ddim);
    const float4* p3 = (const float4*)(pr4 + 3 * (size_t)MNSZ + row * Ddim);
    const float4* bi = (const float4*)bias;
    float4 v[3];
    float ls = 0.f, lq = 0.f;
    #pragma unroll
    for (int i = 0; i < 3; ++i) {
        int ii = i * 64 + t;
        float4 xa = xr[ii], a0 = p0[ii], a1 = p1[ii], a2 = p2[ii], a3 = p3[ii], bb = bi[ii];
        v[i].x = xa.x + ((a0.x + a1.x) + (a2.x + a3.x)) + bb.x;
        v[i].y = xa.y + ((a0.y + a1.y) + (a2.y + a3.y)) + bb.y;
        v[i].z = xa.z + ((a0.z + a1.z) + (a2.z + a3.z)) + bb.z;
        v[i].w = xa.w + ((a0.w + a1.w) + (a2.w + a3.w)) + bb.w;
        ls += v[i].x + v[i].y + v[i].z + v[i].w;
        lq += v[i].x * v[i].x + v[i].y * v[i].y + v[i].z * v[i].z + v[i].w * v[i].w;
    }
    #pragma unroll
    for (int o = 32; o; o >>= 1) { ls += __shfl_xor(ls, o, 64); lq += __shfl_xor(lq, o, 64); }
    float mu = ls / Ddim;
    float var = lq / Ddim - mu * mu;
    float rs = rsqrtf(var + 1e-5f);
    const float4* g4 = (const float4*)g;
    const float4* b4 = (const float4*)b;
    float4* xw = (float4*)(x + row * Ddim);
    ushort4* xbr = (ushort4*)(xb + row * Ddim);
    #pragma unroll
    for (int i = 0; i < 3; ++i) {
        float4 gg = g4[i * 64 + t], bb = b4[i * 64 + t];
        float4 o;
        o.x = (v[i].x - mu) * rs * gg.x + bb.x;
        o.y = (v[i].y - mu) * rs * gg.y + bb.y;
        o.z = (v[i].z - mu) * rs * gg.z + bb.z;
        o.w = (v[i].w - mu) * rs * gg.w + bb.w;
        xw[i * 64 + t] = o;
        ushort4 ob; ob.x = f2bf(o.x); ob.y = f2bf(o.y); ob.z = f2bf(o.z); ob.w = f2bf(o.w);
        xbr[i * 64 + t] = ob;
    }
}

// ---------------- bf16 MFMA GEMM (m97 + double-buffered K-loop + XCD swizzle) ----------------
template<int ACT, int OUTBF16>
__global__ __launch_bounds__(256) void k_gemm_bf16(
        const ushort* __restrict__ A, const ushort* __restrict__ Wt,
        const float* __restrict__ bias, void* __restrict__ Cout,
        int M, int N, int K)
{
    __shared__ ushort As[2][128 * 32];
    __shared__ ushort Bs[2][128 * 32];
    const int t = threadIdx.x;
    const int nwg = gridDim.x * gridDim.y;
    const int wgid = blockIdx.y * gridDim.x + blockIdx.x;
    const int q8 = nwg >> 3, r8 = nwg & 7;
    const int xcd = wgid & 7, idx = wgid >> 3;
    const int swz = (xcd < r8 ? xcd * (q8 + 1) : r8 * (q8 + 1) + (xcd - r8) * q8) + idx;
    const int bm = (swz / gridDim.x) * 128;
    const int bn = (swz % gridDim.x) * 128;
    const int lane = t & 63;
    const int wv = t >> 6;
    const int wm = (wv >> 1) * 64;
    const int wn = (wv & 1) * 64;

    const int srow = t >> 2;
    const int scol = (t & 3) * 8;
    const ushort* gA0 = A + (size_t)(bm + srow) * K + scol;
    const ushort* gA1 = A + (size_t)(bm + 64 + srow) * K + scol;
    const ushort* gB0 = Wt + (size_t)(bn + srow) * K + scol;
    const ushort* gB1 = Wt + (size_t)(bn + 64 + srow) * K + scol;

    f32x4 acc[4][4] = {};
    const int frow = lane & 15;
    const int koff = (lane >> 4) * 8;

    auto stage = [&](int d, int k0) {
        gload16(gA0 + k0, &As[d][t * 8]);
        gload16(gA1 + k0, &As[d][2048 + t * 8]);
        gload16(gB0 + k0, &Bs[d][t * 8]);
        gload16(gB1 + k0, &Bs[d][2048 + t * 8]);
    };

    stage(0, 0);
    __syncthreads();
    const int niter = K / 32;
    int cur = 0;
    for (int it = 0; it < niter; ++it) {
        if (it + 1 < niter) stage(cur ^ 1, (it + 1) * 32);
        bf16x8 af[4], bfv[4];
        #pragma unroll
        for (int mi = 0; mi < 4; ++mi)
            af[mi] = *reinterpret_cast<const bf16x8*>(&As[cur][(wm + mi * 16 + frow) * 32 + koff]);
        #pragma unroll
        for (int ni = 0; ni < 4; ++ni)
            bfv[ni] = *reinterpret_cast<const bf16x8*>(&Bs[cur][(wn + ni * 16 + frow) * 32 + koff]);
        #pragma unroll
        for (int mi = 0; mi < 4; ++mi)
            #pragma unroll
            for (int ni = 0; ni < 4; ++ni)
                acc[mi][ni] = __builtin_amdgcn_mfma_f32_16x16x32_bf16(af[mi], bfv[ni], acc[mi][ni], 0, 0, 0);
        __syncthreads();
        cur ^= 1;
    }
    const int crow0 = (lane >> 4) * 4;
    const int ccol = lane & 15;
    #pragma unroll
    for (int mi = 0; mi < 4; ++mi) {
        #pragma unroll
        for (int ni = 0; ni < 4; ++ni) {
            int gc = bn + wn + ni * 16 + ccol;
            float bv = bias[gc];
            #pragma unroll
            for (int j = 0; j < 4; ++j) {
                int gr = bm + wm + mi * 16 + crow0 + j;
                float v = acc[mi][ni][j] + bv;
                if (ACT == 1) {
                    float y = 0.7978845608f * (v + 0.044715f * v * v * v);
                    float e = __expf(2.f * y);
                    v = v * (1.f - 1.f / (e + 1.f));
                }
                if (OUTBF16) ((ushort*)Cout)[(size_t)gr * N + gc] = f2bf(v);
                else         ((float*)Cout)[(size_t)gr * N + gc] = v;
            }
        }
    }
}

// ---------------- splitK bf16 MFMA GEMM (double-buffered): partial f32, no bias ----------------
__global__ __launch_bounds__(256) void k_gemm_splitk(
        const ushort* __restrict__ A, const ushort* __restrict__ Wt,
        float* __restrict__ Cpart, int M, int N, int K, int Kper)
{
    __shared__ ushort As[2][128 * 32];
    __shared__ ushort Bs[2][128 * 32];
    const int t = threadIdx.x;
    const int ks = blockIdx.z;
    const int nwg = gridDim.x * gridDim.y;
    const int wgid = blockIdx.y * gridDim.x + blockIdx.x;
    const int q8 = nwg >> 3, r8 = nwg & 7;
    const int xcd = wgid & 7, idx = wgid >> 3;
    const int swz = (xcd < r8 ? xcd * (q8 + 1) : r8 * (q8 + 1) + (xcd - r8) * q8) + idx;
    const int bm = (swz / gridDim.x) * 128;
    const int bn = (swz % gridDim.x) * 128;
    const int lane = t & 63;
    const int wv = t >> 6;
    const int wm = (wv >> 1) * 64;
    const int wn = (wv & 1) * 64;

    const int srow = t >> 2;
    const int scol = (t & 3) * 8;
    const int kbase = ks * Kper;
    const ushort* gA0 = A + (size_t)(bm + srow) * K + kbase + scol;
    const ushort* gA1 = A + (size_t)(bm + 64 + srow) * K + kbase + scol;
    const ushort* gB0 = Wt + (size_t)(bn + srow) * K + kbase + scol;
    const ushort* gB1 = Wt + (size_t)(bn + 64 + srow) * K + kbase + scol;

    f32x4 acc[4][4] = {};
    const int frow = lane & 15;
    const int koff = (lane >> 4) * 8;

    auto stage = [&](int d, int k0) {
        gload16(gA0 + k0, &As[d][t * 8]);
        gload16(gA1 + k0, &As[d][2048 + t * 8]);
        gload16(gB0 + k0, &Bs[d][t * 8]);
        gload16(gB1 + k0, &Bs[d][2048 + t * 8]);
    };

    stage(0, 0);
    __syncthreads();
    const int niter = Kper / 32;
    int cur = 0;
    for (int it = 0; it < niter; ++it) {
        if (it + 1 < niter) stage(cur ^ 1, (it + 1) * 32);
        bf16x8 af[4], bfv[4];
        #pragma unroll
        for (int mi = 0; mi < 4; ++mi)
            af[mi] = *reinterpret_cast<const bf16x8*>(&As[cur][(wm + mi * 16 + frow) * 32 + koff]);
        #pragma unroll
        for (int ni = 0; ni < 4; ++ni)
            bfv[ni] = *reinterpret_cast<const bf16x8*>(&Bs[cur][(wn + ni * 16 + frow) * 32 + koff]);
        #pragma unroll
        for (int mi = 0; mi < 4; ++mi)
            #pragma unroll
            for (int ni = 0; ni < 4; ++ni)
                acc[mi][ni] = __builtin_amdgcn_mfma_f32_16x16x32_bf16(af[mi], bfv[ni], acc[mi][ni], 0, 0, 0);
        __syncthreads();
        cur ^= 1;
    }
    float* outp = Cpart + (size_t)ks * M * N;
    const int crow0 = (lane >> 4) * 4;
    const int ccol = lane & 15;
    #pragma unroll
    for (int mi = 0; mi < 4; ++mi) {
        #pragma unroll
        for (int ni = 0; ni < 4; ++ni) {
            int gc = bn + wn + ni * 16 + ccol;
            #pragma unroll
            for (int j = 0; j < 4; ++j) {
                int gr = bm + wm + mi * 16 + crow0 + j;
                outp[(size_t)gr * N + gc] = acc[mi][ni][j];
            }
        }
    }
}

// ---------------- MFMA flash local attention, 64-key tiles ----------------
__global__ __launch_bounds__(256) void k_attn_mfma(
        const ushort* __restrict__ qkv, const int* __restrict__ isg,
        const int* __restrict__ glob, const int* __restrict__ amask,
        ushort* __restrict__ ao)
{
    const int n = blockIdx.x, h = blockIdx.y, b = blockIdx.z;
    const int t = threadIdx.x;
    const int lane = t & 63, wv = t >> 6;
    const int R0 = b * Sdim;
    const int l15 = lane & 15, l4 = lane >> 4;

    __shared__ ushort Kb[64 * 64];        // swizzled [key][64]
    __shared__ ushort Vt[64 * 72];        // [d][key] pad 72
    __shared__ ushort Plds[4][32 * 72];   // per-wave P, pad 72
    __shared__ float  maskLDS[448];

    for (int i = t; i < 448; i += 256) {
        int ok;
        if (i < 384) {
            int pos = n * Cdim + i - Cdim;
            ok = (pos >= 0 && pos < Sdim);
            if (ok) ok = (amask[b * Sdim + pos] != 0) && (isg[pos] == 0);
        } else {
            int g = i - 384;
            int gp = (g < Gdim) ? glob[g] : 0;
            ok = (g < Gdim) && (amask[b * Sdim + gp] != 0);
        }
        maskLDS[i] = ok ? 0.f : -1e9f;
    }

    bf16x8 qf[2][2];
    #pragma unroll
    for (int qi = 0; qi < 2; ++qi)
        #pragma unroll
        for (int kh = 0; kh < 2; ++kh)
            qf[qi][kh] = *reinterpret_cast<const bf16x8*>(
                qkv + (size_t)(R0 + n * Cdim + wv * 32 + qi * 16 + l15) * QKVS
                    + h * DHdim + kh * 32 + l4 * 8);

    f32x4 accO[2][4] = {};
    float mrow[2][4], lrow[2][4];
    #pragma unroll
    for (int qi = 0; qi < 2; ++qi)
        #pragma unroll
        for (int j = 0; j < 4; ++j) { mrow[qi][j] = -1e30f; lrow[qi][j] = 0.f; }

    const int jj = t >> 3;   // 0..31
    const int c16 = t & 7;   // 0..7

    auto ldone = [&](int j, ushort8v& kr, ushort8v& vr) {
        int pos = 0; bool ok;
        if (j < 384) { pos = n * Cdim + j - Cdim; ok = (pos >= 0 && pos < Sdim); }
        else { int g = j - 384; ok = (g < Gdim); if (ok) pos = glob[g]; }
        ushort8v z = {};
        if (ok) {
            const ushort* kp = qkv + (size_t)(R0 + pos) * QKVS + Ddim + h * DHdim + c16 * 8;
            kr = *reinterpret_cast<const ushort8v*>(kp);
            vr = *reinterpret_cast<const ushort8v*>(kp + Ddim);
        } else { kr = z; vr = z; }
    };

    ushort8v kr0, kr1, vr0, vr1, nk0 = {}, nk1 = {}, nv0 = {}, nv1 = {};
    ldone(jj, kr0, vr0);
    ldone(jj + 32, kr1, vr1);

    for (int kt = 0; kt < 7; ++kt) {
        __syncthreads();
        *reinterpret_cast<ushort8v*>(&Kb[jj * 64 + ((c16 ^ (jj & 7)) * 8)]) = kr0;
        *reinterpret_cast<ushort8v*>(&Kb[(jj + 32) * 64 + ((c16 ^ (jj & 7)) * 8)]) = kr1;
        #pragma unroll
        for (int e = 0; e < 8; ++e) {
            Vt[(c16 * 8 + e) * 72 + jj] = vr0[e];
            Vt[(c16 * 8 + e) * 72 + 32 + jj] = vr1[e];
        }
        if (kt < 6) {
            int base_j = (kt + 1) * 64 + jj;
            ldone(base_j, nk0, nv0);
            ldone(base_j + 32, nk1, nv1);
        }
        __syncthreads();

        bool active = (kt == 6) || ((kt * 64 + 63 >= wv * 32) && (kt * 64 <= wv * 32 + 287));
        if (active) {
            bf16x8 kf[4][2];
            #pragma unroll
            for (int kj = 0; kj < 4; ++kj) {
                int key = kj * 16 + l15;
                #pragma unroll
                for (int kh = 0; kh < 2; ++kh) {
                    int cc = (kh * 4 + l4) ^ (key & 7);
                    kf[kj][kh] = *reinterpret_cast<const bf16x8*>(&Kb[key * 64 + cc * 8]);
                }
            }
            float ma[4];
            #pragma unroll
            for (int kj = 0; kj < 4; ++kj) ma[kj] = maskLDS[kt * 64 + kj * 16 + l15];

            #pragma unroll
            for (int qi = 0; qi < 2; ++qi) {
                f32x4 s[4] = {};
                #pragma unroll
                for (int kj = 0; kj < 4; ++kj)
                    #pragma unroll
                    for (int kh = 0; kh < 2; ++kh)
                        s[kj] = __builtin_amdgcn_mfma_f32_16x16x32_bf16(qf[qi][kh], kf[kj][kh], s[kj], 0, 0, 0);

                float sf[4][4];
                #pragma unroll
                for (int kj = 0; kj < 4; ++kj) {
                    int key = kt * 64 + kj * 16 + l15;
                    #pragma unroll
                    for (int j = 0; j < 4; ++j) {
                        int cq = wv * 32 + qi * 16 + l4 * 4 + j;
                        float sv = s[kj][j] * 0.125f + ma[kj];
                        bool band = (key >= 384) || ((unsigned)(key - cq) <= 256u);
                        sf[kj][j] = band ? sv : sv - 1e9f;
                    }
                }
                float mnew[4], corr[4];
                #pragma unroll
                for (int j = 0; j < 4; ++j) {
                    float v = fmaxf(fmaxf(sf[0][j], sf[1][j]), fmaxf(sf[2][j], sf[3][j]));
                    v = fmaxf(v, __shfl_xor(v, 1, 64));
                    v = fmaxf(v, __shfl_xor(v, 2, 64));
                    v = fmaxf(v, __shfl_xor(v, 4, 64));
                    v = fmaxf(v, __shfl_xor(v, 8, 64));
                    mnew[j] = fmaxf(mrow[qi][j], v);
                    corr[j] = __expf(mrow[qi][j] - mnew[j]);
                    mrow[qi][j] = mnew[j];
                }
                float ps[4][4];
                #pragma unroll
                for (int kj = 0; kj < 4; ++kj)
                    #pragma unroll
                    for (int j = 0; j < 4; ++j)
                        ps[kj][j] = __expf(sf[kj][j] - mnew[j]);
                #pragma unroll
                for (int j = 0; j < 4; ++j) {
                    float r = (ps[0][j] + ps[1][j]) + (ps[2][j] + ps[3][j]);
                    r += __shfl_xor(r, 1, 64);
                    r += __shfl_xor(r, 2, 64);
                    r += __shfl_xor(r, 4, 64);
                    r += __shfl_xor(r, 8, 64);
                    lrow[qi][j] = lrow[qi][j] * corr[j] + r;
                }
                bool need = (corr[0] < 1.f) || (corr[1] < 1.f) || (corr[2] < 1.f) || (corr[3] < 1.f);
                if (__any((int)need)) {
                    #pragma unroll
                    for (int dt = 0; dt < 4; ++dt)
                        #pragma unroll
                        for (int j = 0; j < 4; ++j)
                            accO[qi][dt][j] *= corr[j];
                }
                #pragma unroll
                for (int kj = 0; kj < 4; ++kj)
                    #pragma unroll
                    for (int j = 0; j < 4; ++j)
                        Plds[wv][(qi * 16 + l4 * 4 + j) * 72 + kj * 16 + l15] = f2bf(ps[kj][j]);
            }
            #pragma unroll
            for (int qi = 0; qi < 2; ++qi) {
                #pragma unroll
                for (int ks = 0; ks < 2; ++ks) {
                    bf16x8 af = *reinterpret_cast<const bf16x8*>(
                        &Plds[wv][(qi * 16 + l15) * 72 + ks * 32 + l4 * 8]);
                    #pragma unroll
                    for (int dt = 0; dt < 4; ++dt) {
                        bf16x8 vf = *reinterpret_cast<const bf16x8*>(
                            &Vt[(dt * 16 + l15) * 72 + ks * 32 + l4 * 8]);
                        accO[qi][dt] = __builtin_amdgcn_mfma_f32_16x16x32_bf16(af, vf, accO[qi][dt], 0, 0, 0);
                    }
                }
            }
        }
        kr0 = nk0; kr1 = nk1; vr0 = nv0; vr1 = nv1;
    }

    #pragma unroll
    for (int qi = 0; qi < 2; ++qi) {
        float inv[4];
        #pragma unroll
        for (int j = 0; j < 4; ++j) inv[j] = 1.f / lrow[qi][j];
        #pragma unroll
        for (int dt = 0; dt < 4; ++dt) {
            #pragma unroll
            for (int j = 0; j < 4; ++j) {
                int crow = n * Cdim + wv * 32 + qi * 16 + l4 * 4 + j;
                ao[(size_t)(R0 + crow) * Ddim + h * DHdim + dt * 16 + l15] =
                    f2bf(accO[qi][dt][j] * inv[j]);
            }
        }
    }
}

// ---------------- global token rows attend to all S keys ----------------
__global__ __launch_bounds__(256) void k_attn_glob(const ushort* __restrict__ qkv,
        const int* __restrict__ glob, const int* __restrict__ amask,
        ushort* __restrict__ ao) {
    int g = blockIdx.x, h = blockIdx.y, b = blockIdx.z;
    __shared__ float sc[Sdim];
    __shared__ float qs[DHdim];
    __shared__ float redm[4], reds[4];
    __shared__ float part[32][DHdim];
    int t = threadIdx.x;
    int qr = glob[g];
    const int R0 = b * Sdim;
    if (t < DHdim)
        qs[t] = bf2f(qkv[(size_t)(R0 + qr) * QKVS + h * DHdim + t]) * 0.125f;
    __syncthreads();
    float lm = -1e30f;
    for (int s0 = t; s0 < Sdim; s0 += 256) {
        const ushort8v* kr = (const ushort8v*)(qkv + (size_t)(R0 + s0) * QKVS + Ddim + h * DHdim);
        float s = 0.f;
        #pragma unroll
        for (int cc = 0; cc < 8; ++cc) {
            ushort8v kv = kr[cc];
            #pragma unroll
            for (int e = 0; e < 8; ++e) s += qs[cc * 8 + e] * bf2f(kv[e]);
        }
        if (amask[b * Sdim + s0] == 0) s = -1e30f;
        sc[s0] = s;
        lm = fmaxf(lm, s);
    }
    #pragma unroll
    for (int o = 32; o; o >>= 1) lm = fmaxf(lm, __shfl_xor(lm, o, 64));
    if ((t & 63) == 0) redm[t >> 6] = lm;
    __syncthreads();
    float mx = fmaxf(fmaxf(redm[0], redm[1]), fmaxf(redm[2], redm[3]));
    float lsum = 0.f;
    for (int s0 = t; s0 < Sdim; s0 += 256) {
        float p = __expf(sc[s0] - mx);
        sc[s0] = p; lsum += p;
    }
    #pragma unroll
    for (int o = 32; o; o >>= 1) lsum += __shfl_xor(lsum, o, 64);
    if ((t & 63) == 0) reds[t >> 6] = lsum;
    __syncthreads();
    float l = reds[0] + reds[1] + reds[2] + reds[3];
    int chunk = t >> 3, dg = t & 7;
    float a[8] = {};
    for (int r = chunk * 64; r < chunk * 64 + 64; ++r) {
        float p = sc[r];
        ushort8v vv = *(const ushort8v*)(qkv + (size_t)(R0 + r) * QKVS + 2 * Ddim + h * DHdim + dg * 8);
        #pragma unroll
        for (int e = 0; e < 8; ++e) a[e] += p * bf2f(vv[e]);
    }
    #pragma unroll
    for (int e = 0; e < 8; ++e) part[chunk][dg * 8 + e] = a[e];
    __syncthreads();
    if (t < DHdim) {
        float o = 0.f;
        #pragma unroll
        for (int c = 0; c < 32; ++c) o += part[c][t];
        ao[(size_t)(R0 + qr) * Ddim + h * DHdim + t] = f2bf(o / l);
    }
}

// ---------------- classification head (256 thr, 2-way k-split) ----------------
__global__ __launch_bounds__(256) void k_head(const float* __restrict__ x,
        const int* __restrict__ glob, const float* __restrict__ Wh,
        const float* __restrict__ bh, const float* __restrict__ Wout,
        const float* __restrict__ bout, float* __restrict__ out) {
    int i = blockIdx.x;
    int b = i / 14, j = i % 14;
    __shared__ float emb[2 * Ddim];
    __shared__ float hp[2][128];
    __shared__ float hid[HIDd];
    int t = threadIdx.x;
    int p = glob[j + 2];
    for (int d = t; d < Ddim; d += 256) {
        emb[d] = x[(long)b * Sdim * Ddim + d];
        emb[Ddim + d] = x[((long)b * Sdim + p) * Ddim + d];
    }
    __syncthreads();
    int nn = t & 127, half = t >> 7;
    float s = 0.f;
    if (nn < HIDd) {
        int k0 = half * Ddim;
        for (int k1 = 0; k1 < Ddim; ++k1) s += emb[k0 + k1] * Wh[(k0 + k1) * HIDd + nn];
    }
    hp[half][nn] = s;
    __syncthreads();
    if (t < HIDd) hid[t] = fmaxf(hp[0][t] + hp[1][t] + bh[t], 0.f);
    __syncthreads();
    if (t < NCLSd) {
        float s2 = bout[t];
        for (int o = 0; o < HIDd; ++o) s2 += hid[o] * Wout[o * NCLSd + t];
        out[i * NCLSd + t] = s2;
    }
}

extern "C" void kernel_launch(void* const* d_in, const int* in_sizes, int n_in,
                              void* d_out, int out_size, void* d_ws, size_t ws_size,
                              hipStream_t stream) {
    const int*   ids   = (const int*)d_in[0];
    const int*   am    = (const int*)d_in[1];
    const float* tok   = (const float*)d_in[2];
    const float* pos   = (const float*)d_in[3];
    const float* lneg  = (const float*)d_in[4];
    const float* lneb  = (const float*)d_in[5];
    const float* Wq    = (const float*)d_in[6];
    const float* bq    = (const float*)d_in[7];
    const float* Wk    = (const float*)d_in[8];
    const float* bk    = (const float*)d_in[9];
    const float* Wv    = (const float*)d_in[10];
    const float* bv    = (const float*)d_in[11];
    const float* Wo    = (const float*)d_in[12];
    const float* bo    = (const float*)d_in[13];
    const float* ln1g  = (const float*)d_in[14];
    const float* ln1b  = (const float*)d_in[15];
    const float* W1    = (const float*)d_in[16];
    const float* b1    = (const float*)d_in[17];
    const float* W2    = (const float*)d_in[18];
    const float* b2    = (const float*)d_in[19];
    const float* ln2g  = (const float*)d_in[20];
    const float* ln2b  = (const float*)d_in[21];
    const float* Wh    = (const float*)d_in[22];
    const float* bh    = (const float*)d_in[23];
    const float* Wout  = (const float*)d_in[24];
    const float* bout  = (const float*)d_in[25];
    float* out = (float*)d_out;

    char* ws = (char*)d_ws;
    const size_t SZ = (size_t)MROWS * Ddim * sizeof(float);
    const size_t HB = SZ / 2;
    size_t off = 0;
    float*  x    = (float*)(ws + off);  off += SZ;
    float*  pr4  = (float*)(ws + off);  off += 4 * SZ;   // splitK partials
    ushort* xb   = (ushort*)(ws + off); off += HB;
    ushort* qkvB = (ushort*)(ws + off); off += (size_t)MROWS * QKVS * 2;
    ushort* aoB  = (ushort*)(ws + off); off += HB;
    ushort* hh   = (ushort*)(ws + off); off += (size_t)MROWS * FFdim * 2;
    const size_t WSMALL = (size_t)Ddim * Ddim;
    const size_t WBIG   = (size_t)Ddim * FFdim;
    const size_t WL     = 4 * WSMALL + 2 * WBIG;
    ushort* wts = (ushort*)(ws + off); off += WL * Ldim * 2;
    float* bqkv = (float*)(ws + off);  off += Ldim * QKVS * sizeof(float);
    int* glob = (int*)(ws + off); off += 256;
    int* isg  = (int*)(ws + off);

    k_findsep<<<1, 1024, 0, stream>>>(ids, glob, isg, bq, bk, bv, bqkv);
    k_w2bt_all<<<3456, 256, 0, stream>>>(Wq, Wk, Wv, Wo, W1, W2, wts);
    k_embed<<<MROWS, 64, 0, stream>>>(ids, tok, pos, lneg, lneb, x, xb);

    dim3 gQKV(QKVS / 128, MROWS / 128);
    dim3 gFF(FFdim / 128, MROWS / 128);
    dim3 gSK(Ddim / 128, MROWS / 128, 4);   // 6 x 32 x 4 = 768 blocks, 3/CU balanced
    dim3 gloc(NCdim, Hdim, Bdim);
    dim3 gglb(Gdim, Hdim, Bdim);

    for (int l = 0; l < Ldim; ++l) {
        ushort* base = wts + l * WL;
        ushort* Wqkvt = base;
        ushort* Wot = base + 3 * WSMALL;
        ushort* W1t = base + 4 * WSMALL;
        ushort* W2t = base + 4 * WSMALL + WBIG;
        k_gemm_bf16<0,1><<<gQKV, 256, 0, stream>>>(xb, Wqkvt, bqkv + l * QKVS, qkvB, MROWS, QKVS, Ddim);
        k_attn_mfma<<<gloc, 256, 0, stream>>>(qkvB, isg, glob, am, aoB);
        k_attn_glob<<<gglb, 256, 0, stream>>>(qkvB, glob, am, aoB);
        k_gemm_splitk<<<gSK, 256, 0, stream>>>(aoB, Wot, pr4, MROWS, Ddim, Ddim, Ddim / 4);
        k_ln_res4<<<MROWS, 64, 0, stream>>>(x, pr4, bo + l * Ddim, ln1g + l * Ddim, ln1b + l * Ddim, xb);
        k_gemm_bf16<1,1><<<gFF, 256, 0, stream>>>(xb, W1t, b1 + l * FFdim, hh, MROWS, FFdim, Ddim);
        k_gemm_splitk<<<gSK, 256, 0, stream>>>(hh, W2t, pr4, MROWS, Ddim, FFdim, FFdim / 4);
        k_ln_res4<<<MROWS, 64, 0, stream>>>(x, pr4, b2 + l * Ddim, ln2g + l * Ddim, ln2b + l * Ddim, xb);
    }
    k_head<<<Bdim * (NSEPd - 2), 256, 0, stream>>>(x, glob, Wh, bh, Wout, bout, out);
}